// Round 9
// baseline (2830.542 us; speedup 1.0000x reference)
//
#include <hip/hip_runtime.h>
#include <hip/hip_fp16.h>
#include <math.h>

#define BLK 128          // fused-fallback block
#define EBLK 256         // encode / utility block
#define NBINS (1 << 18)  // 6 bits per axis, Morton sort bins
#define Q_SCALE 65536.0f
#define Q_DESCALE 0x1p-16f

typedef __attribute__((ext_vector_type(8))) _Float16 half8;
typedef __attribute__((ext_vector_type(4))) float f32x4;
typedef __attribute__((ext_vector_type(2))) float f32x2;

// frag offsets in f16 elements: L1,L2,L3,R1,R2,R3,R4
#define FO_L1 0
#define FO_L2 2048
#define FO_L3 6144
#define FO_R1 7168
#define FO_R2 9216
#define FO_R3 13312
#define FO_R4 17408
#define FRAG_TOTAL 18432

// ---- fp8 table layout ----
#define HOFF0 3764224
#define MOFF0 5861376
#define MOFF1 12939264
#define MOFF2 20017152
#define MOFF3 36794368
#define TABQ_ENTRIES 53571584
#define PAIR_LO 1881687
#define PAIR_H  1048576
#define MTOT 47710208

// ---------------- Morton helpers ----------------
__device__ __forceinline__ unsigned mexp(unsigned v) {
    v &= 0x3FF;
    v = (v | (v << 16)) & 0x030000FF;
    v = (v | (v << 8))  & 0x0300F00F;
    v = (v | (v << 4))  & 0x030C30C3;
    v = (v | (v << 2))  & 0x09249249;
    return v;
}
__device__ __forceinline__ unsigned mcomp(unsigned v) {
    v &= 0x09249249u;
    v = (v | (v >> 2)) & 0x030C30C3u;
    v = (v | (v >> 4)) & 0x0300F00Fu;
    v = (v | (v >> 8)) & 0x030000FFu;
    v = (v | (v >> 16)) & 0x3FFu;
    return v;
}
__device__ __forceinline__ unsigned morton_key(float x, float y, float z) {
    int bx = (int)(x * 64.f); bx = bx < 0 ? 0 : (bx > 63 ? 63 : bx);
    int by = (int)(y * 64.f); by = by < 0 ? 0 : (by > 63 ? 63 : by);
    int bz = (int)(z * 64.f); bz = bz < 0 ? 0 : (bz > 63 ? 63 : bz);
    return (mexp((unsigned)bx) << 2) | (mexp((unsigned)by) << 1) | mexp((unsigned)bz);
}

// ---------------- table conversion kernels ----------------
__device__ __forceinline__ unsigned pk_fp8(float a, float b) {
    const int lo = __builtin_amdgcn_cvt_pk_fp8_f32(a * Q_SCALE, b * Q_SCALE, 0, false);
    return (unsigned)lo & 0xFFFFu;
}

__global__ __launch_bounds__(256) void cvt_lo(const float4* __restrict__ src,
                                              unsigned* __restrict__ dst)
{
    const int i = blockIdx.x * 256 + threadIdx.x;
    if (i >= PAIR_LO) return;
    const float4 v = src[i];
    dst[i] = pk_fp8(v.x, v.y) | (pk_fp8(v.z, v.w) << 16);
}

__global__ __launch_bounds__(256) void cvt_hash(const float4* __restrict__ src,
                                                unsigned* __restrict__ dst)
{
    const int i = blockIdx.x * 256 + threadIdx.x;
    if (i >= PAIR_H) return;
    const float4 v = src[17294596 + i];            // OFF[12]/2 + i
    dst[HOFF0 / 2 + i] = pk_fp8(v.x, v.y) | (pk_fp8(v.z, v.w) << 16);
}

__global__ __launch_bounds__(256) void cvt_morton(const float* __restrict__ srcF,
                                                  unsigned short* __restrict__ dstQ)
{
    const unsigned e = blockIdx.x * 256 + threadIdx.x;
    if (e >= MTOT) return;
    int j, cnt; unsigned base, moff;
    if (e < 14155776u) {
        cnt = 3;
        if (e < 7077888u) { j = 0; base = 0u;        moff = MOFF0; }
        else              { j = 1; base = 7077888u;  moff = MOFF1; }
    } else {
        cnt = 4;
        if (e < 30932992u){ j = 2; base = 14155776u; moff = MOFF2; }
        else              { j = 3; base = 30932992u; moff = MOFF3; }
    }
    const unsigned within = e - base;
    const unsigned blk = within >> 18, lo = within & 0x3FFFFu;
    unsigned bx, by, bz;
    if (cnt == 3) { bx = blk % 3u; const unsigned t = blk / 3u; by = t % 3u; bz = t / 3u; }
    else          { bx = blk & 3u; by = (blk >> 2) & 3u; bz = blk >> 4; }
    const unsigned x = bx * 64u + mcomp(lo);
    const unsigned y = by * 64u + mcomp(lo >> 1);
    const unsigned z = bz * 64u + mcomp(lo >> 2);

    constexpr unsigned RES1[4] = {141u, 169u, 204u, 245u};
    constexpr unsigned SOFF[4] = {3763373u, 6566594u, 11393403u, 19883067u};
    const unsigned r1 = RES1[j];
    unsigned q = 0;
    if (x < r1 && y < r1 && z < r1) {
        const size_t se = (size_t)SOFF[j] + x + (size_t)y * r1 + (size_t)z * r1 * r1;
        const float2 v = *reinterpret_cast<const float2*>(srcF + 2 * se);
        q = pk_fp8(v.x, v.y);
    }
    dstQ[(size_t)moff + within] = (unsigned short)q;
}

// ---------------- weight fragment packing ----------------
__global__ __launch_bounds__(256) void prep_frags(
    const float* __restrict__ fw1, const float* __restrict__ fw2, const float* __restrict__ fw3,
    const float* __restrict__ rw1, const float* __restrict__ rw2, const float* __restrict__ rw3,
    const float* __restrict__ rw4, _Float16* __restrict__ frag)
{
    const int gid = blockIdx.x * 256 + threadIdx.x;
    if (gid >= FRAG_TOTAL) return;
    constexpr int offs[8] = {FO_L1, FO_L2, FO_L3, FO_R1, FO_R2, FO_R3, FO_R4, FRAG_TOTAL};
    constexpr int Ks[7]   = {32, 64, 64, 31, 64, 64, 64};
    constexpr int NO[7]   = {64, 64, 16, 64, 64, 64, 3};
    constexpr int NKs[7]  = {1, 2, 2, 1, 2, 2, 2};
    int layer = 0;
    #pragma unroll
    for (int i = 1; i < 7; ++i) if (gid >= offs[i]) layer = i;
    const float* W = fw1;
    if (layer == 1) W = fw2; else if (layer == 2) W = fw3;
    else if (layer == 3) W = rw1; else if (layer == 4) W = rw2;
    else if (layer == 5) W = rw3; else if (layer == 6) W = rw4;

    const int e = gid - offs[layer];
    const int nk = NKs[layer];
    const int blk = e >> 9, within = e & 511;
    const int t = blk / nk, ks = blk - t * nk;
    const int lane = within >> 3, i = within & 7;
    const int k = ks * 32 + (lane >> 4) * 8 + i;
    // 64-wide layers: col c of tile t holds output feature 4*c + t (paired-store remap)
    const int col = (NO[layer] == 64) ? ((lane & 15) * 4 + t) : (t * 16 + (lane & 15));
    float v = 0.f;
    if (k < Ks[layer] && col < NO[layer]) v = W[k * NO[layer] + col];
    frag[gid] = (_Float16)v;
}

// ---------------- sort: histogram ----------------
__global__ __launch_bounds__(256) void hist_build(const float* __restrict__ coords,
                                                  unsigned* __restrict__ hist, int N)
{
    const int i = blockIdx.x * 256 + threadIdx.x;
    if (i >= N) return;
    const unsigned key = morton_key(coords[3*i+0], coords[3*i+1], coords[3*i+2]);
    atomicAdd(&hist[key], 1u);
}

// ---------------- sort: hierarchical exclusive scan ----------------
__global__ __launch_bounds__(256) void scan1(unsigned* __restrict__ hist, unsigned* __restrict__ bsum)
{
    __shared__ unsigned sa[256], sb[256];
    const int t = threadIdx.x;
    const unsigned base = blockIdx.x * 1024u + (unsigned)t * 4u;
    const unsigned v0 = hist[base+0], v1 = hist[base+1], v2 = hist[base+2], v3 = hist[base+3];
    const unsigned sum = v0 + v1 + v2 + v3;
    sa[t] = sum; __syncthreads();
    unsigned* src = sa; unsigned* dst = sb;
    for (int off = 1; off < 256; off <<= 1) {
        dst[t] = src[t] + (t >= off ? src[t - off] : 0u);
        __syncthreads();
        unsigned* tmp = src; src = dst; dst = tmp;
    }
    const unsigned incl = src[t];
    unsigned run = incl - sum;
    hist[base+0] = run; run += v0;
    hist[base+1] = run; run += v1;
    hist[base+2] = run; run += v2;
    hist[base+3] = run;
    if (t == 255) bsum[blockIdx.x] = incl;
}

__global__ __launch_bounds__(256) void scan2(unsigned* __restrict__ bsum)
{
    __shared__ unsigned sa[256], sb[256];
    const int t = threadIdx.x;
    const unsigned v = bsum[t];
    sa[t] = v; __syncthreads();
    unsigned* src = sa; unsigned* dst = sb;
    for (int off = 1; off < 256; off <<= 1) {
        dst[t] = src[t] + (t >= off ? src[t - off] : 0u);
        __syncthreads();
        unsigned* tmp = src; src = dst; dst = tmp;
    }
    bsum[t] = src[t] - v;
}

__global__ __launch_bounds__(256) void scan3(const unsigned* __restrict__ hist,
                                             const unsigned* __restrict__ bsum,
                                             unsigned* __restrict__ cursor)
{
    const int i = blockIdx.x * 256 + threadIdx.x;
    cursor[i] = hist[i] + bsum[i >> 10];
}

// ---------------- sort: scatter points into bins ----------------
__global__ __launch_bounds__(256) void scatter_pts(const float* __restrict__ coords,
                                                   const float* __restrict__ dirs,
                                                   unsigned* __restrict__ cursor,
                                                   float4* __restrict__ cS,
                                                   float4* __restrict__ dS, int N)
{
    const int i = blockIdx.x * 256 + threadIdx.x;
    if (i >= N) return;
    const float x = coords[3*i+0], y = coords[3*i+1], z = coords[3*i+2];
    const unsigned key = morton_key(x, y, z);
    const unsigned slot = atomicAdd(&cursor[key], 1u);
    cS[slot] = make_float4(x, y, z, __uint_as_float((unsigned)i));
    dS[slot] = make_float4(dirs[3*i+0], dirs[3*i+1], dirs[3*i+2], __uint_as_float((unsigned)i));
}

// ---------------- encode kernel (pair-load gathers) ----------------
__global__ __launch_bounds__(EBLK, 8) void ngp_encode(
    const float4* __restrict__ cS,
    const unsigned short* __restrict__ tableQ,
    uint4* __restrict__ emb_out, int N)
{
    // bijective XCD-contiguous remap of blockIdx (8 XCDs)
    const unsigned nwg = gridDim.x;
    const unsigned bid = blockIdx.x;
    const unsigned qn = nwg >> 3, rn = nwg & 7;
    const unsigned xc = bid & 7, ib = bid >> 3;
    const unsigned nb = (xc < rn ? xc * (qn + 1) : rn * (qn + 1) + (xc - rn) * qn) + ib;

    const int gi = (int)(nb * EBLK + threadIdx.x);
    if (gi >= N) return;

    const float4 cp = cS[gi];
    const float x = cp.x, y = cp.y, z = cp.z;

    float emb[32];

    // ---- dense row-major levels 0-7: x-pair u32 loads when aligned ----
    {
        constexpr int RES[8] = {32,38,46,55,67,80,97,116};
        constexpr int OFF[8] = {0,35937,95256,199079,374695,689127,1220568,2161760};
        #pragma unroll
        for (int lv = 0; lv < 8; ++lv) {
            const int res = RES[lv];
            const float xl = x * (float)res, yl = y * (float)res, zl = z * (float)res;
            int cx = (int)floorf(xl); cx = cx < 0 ? 0 : (cx > res-1 ? res-1 : cx);
            int cy = (int)floorf(yl); cy = cy < 0 ? 0 : (cy > res-1 ? res-1 : cy);
            int cz = (int)floorf(zl); cz = cz < 0 ? 0 : (cz > res-1 ? res-1 : cz);
            const float wx = xl - (float)cx, wy = yl - (float)cy, wz = zl - (float)cz;
            const int res1 = res + 1;
            unsigned qv[8];
            #pragma unroll
            for (int p = 0; p < 4; ++p) {           // p = (dy<<1)|dz
                const int dy = (p >> 1) & 1, dz = p & 1;
                const int i0 = OFF[lv] + cx + (cy+dy)*res1 + (cz+dz)*res1*res1;
                unsigned lo, hi;
                if ((i0 & 1) == 0) {
                    const unsigned w = *reinterpret_cast<const unsigned*>(tableQ + i0);
                    lo = w & 0xFFFFu; hi = w >> 16;
                } else {
                    lo = tableQ[i0]; hi = tableQ[i0 + 1];
                }
                qv[p] = lo; qv[p + 4] = hi;
            }
            float e0 = 0.f, e1 = 0.f;
            #pragma unroll
            for (int c = 0; c < 8; ++c) {
                const int dx = (c >> 2) & 1, dy = (c >> 1) & 1, dz = c & 1;
                const float w = (dx ? wx : 1.f-wx)*(dy ? wy : 1.f-wy)*(dz ? wz : 1.f-wz);
                const f32x2 vf = __builtin_amdgcn_cvt_pk_f32_fp8((int)qv[c], false);
                e0 = fmaf(vf.x, w, e0); e1 = fmaf(vf.y, w, e1);
            }
            emb[2*lv+0] = e0 * Q_DESCALE; emb[2*lv+1] = e1 * Q_DESCALE;
        }
    }

    // ---- Morton-block dense levels 8-11: x-pair u32 when cx even ----
    {
        constexpr int RESM[4] = {140,168,203,244};
        constexpr int CNTM[4] = {3,3,4,4};
        constexpr unsigned MOFF[4] = {MOFF0, MOFF1, MOFF2, MOFF3};
        #pragma unroll
        for (int j = 0; j < 4; ++j) {
            const int res = RESM[j];
            const int cnt = CNTM[j];
            const float xl = x * (float)res, yl = y * (float)res, zl = z * (float)res;
            int cx = (int)floorf(xl); cx = cx < 0 ? 0 : (cx > res-1 ? res-1 : cx);
            int cy = (int)floorf(yl); cy = cy < 0 ? 0 : (cy > res-1 ? res-1 : cy);
            int cz = (int)floorf(zl); cz = cz < 0 ? 0 : (cz > res-1 ? res-1 : cz);
            const float wx = xl - (float)cx, wy = yl - (float)cy, wz = zl - (float)cz;

            const int bx0 = cx >> 6, bx1 = (cx+1) >> 6;
            const int by0 = cy >> 6, by1 = (cy+1) >> 6;
            const int bz0 = cz >> 6, bz1 = (cz+1) >> 6;
            const unsigned mx0 = mexp(cx & 63),      mx1 = mexp((cx+1) & 63);
            const unsigned my0 = mexp(cy & 63) << 1, my1 = mexp((cy+1) & 63) << 1;
            const unsigned mz0 = mexp(cz & 63) << 2, mz1 = mexp((cz+1) & 63) << 2;
            const bool xev = (cx & 1) == 0;

            unsigned qv[8];
            #pragma unroll
            for (int p = 0; p < 4; ++p) {
                const int dy = (p >> 1) & 1, dz = p & 1;
                const int by = dy ? by1 : by0, bz = dz ? bz1 : bz0;
                const unsigned myz = (dy ? my1 : my0) | (dz ? mz1 : mz0);
                if (xev) {
                    // cx even -> cx+1 in same 64-block, Morton codes adjacent (bit0)
                    const unsigned blk = (unsigned)((bz * cnt + by) * cnt + bx0);
                    const unsigned m0 = (blk << 18) | myz | mx0;      // even
                    const unsigned w = *reinterpret_cast<const unsigned*>(
                        tableQ + (size_t)MOFF[j] + m0);
                    qv[p] = w & 0xFFFFu; qv[p + 4] = w >> 16;
                } else {
                    const unsigned blkA = (unsigned)((bz * cnt + by) * cnt + bx0);
                    const unsigned blkB = (unsigned)((bz * cnt + by) * cnt + bx1);
                    qv[p]     = tableQ[(size_t)MOFF[j] + ((blkA << 18) | myz | mx0)];
                    qv[p + 4] = tableQ[(size_t)MOFF[j] + ((blkB << 18) | myz | mx1)];
                }
            }
            float e0 = 0.f, e1 = 0.f;
            #pragma unroll
            for (int c = 0; c < 8; ++c) {
                const int dx = (c >> 2) & 1, dy = (c >> 1) & 1, dz = c & 1;
                const float w = (dx ? wx : 1.f-wx)*(dy ? wy : 1.f-wy)*(dz ? wz : 1.f-wz);
                const f32x2 vf = __builtin_amdgcn_cvt_pk_f32_fp8((int)qv[c], false);
                e0 = fmaf(vf.x, w, e0); e1 = fmaf(vf.y, w, e1);
            }
            emb[16+2*j+0] = e0 * Q_DESCALE; emb[16+2*j+1] = e1 * Q_DESCALE;
        }
    }

    // ---- hashed levels 12-15: h and h^1 adjacent when cx even (PRIMES[0]=1) ----
    {
        constexpr int RESH[4] = {294,353,425,512};
        constexpr unsigned HOFF[4] = {HOFF0, HOFF0+524288, HOFF0+1048576, HOFF0+1572864};
        constexpr unsigned NMASK = (1u << 19) - 1u;
        #pragma unroll
        for (int j = 0; j < 4; ++j) {
            const int res = RESH[j];
            const float xl = x * (float)res, yl = y * (float)res, zl = z * (float)res;
            int cx = (int)floorf(xl); cx = cx < 0 ? 0 : (cx > res-1 ? res-1 : cx);
            int cy = (int)floorf(yl); cy = cy < 0 ? 0 : (cy > res-1 ? res-1 : cy);
            int cz = (int)floorf(zl); cz = cz < 0 ? 0 : (cz > res-1 ? res-1 : cz);
            const float wx = xl - (float)cx, wy = yl - (float)cy, wz = zl - (float)cz;
            const bool xev = (cx & 1) == 0;
            unsigned qv[8];
            #pragma unroll
            for (int p = 0; p < 4; ++p) {
                const int dy = (p >> 1) & 1, dz = p & 1;
                const unsigned hyz = ((unsigned)(cy+dy) * 2654435761u)
                                   ^ ((unsigned)(cz+dz) * 805459861u);
                const unsigned h0 = ((unsigned)cx ^ hyz) & NMASK;
                if (xev) {
                    // h1 = h0 ^ 1 -> same aligned u32
                    const unsigned w = *reinterpret_cast<const unsigned*>(
                        tableQ + HOFF[j] + (h0 & ~1u));
                    const unsigned lo16 = w & 0xFFFFu, hi16 = w >> 16;
                    qv[p]     = (h0 & 1) ? hi16 : lo16;
                    qv[p + 4] = (h0 & 1) ? lo16 : hi16;
                } else {
                    const unsigned h1 = ((unsigned)(cx+1) ^ hyz) & NMASK;
                    qv[p]     = tableQ[HOFF[j] + h0];
                    qv[p + 4] = tableQ[HOFF[j] + h1];
                }
            }
            float e0 = 0.f, e1 = 0.f;
            #pragma unroll
            for (int c = 0; c < 8; ++c) {
                const int dx = (c >> 2) & 1, dy = (c >> 1) & 1, dz = c & 1;
                const float w = (dx ? wx : 1.f-wx)*(dy ? wy : 1.f-wy)*(dz ? wz : 1.f-wz);
                const f32x2 vf = __builtin_amdgcn_cvt_pk_f32_fp8((int)qv[c], false);
                e0 = fmaf(vf.x, w, e0); e1 = fmaf(vf.y, w, e1);
            }
            emb[24+2*j+0] = e0 * Q_DESCALE; emb[24+2*j+1] = e1 * Q_DESCALE;
        }
    }

    unsigned packed[16];
    #pragma unroll
    for (int i = 0; i < 16; ++i) {
        const __half2 h = __floats2half2_rn(emb[2*i+0], emb[2*i+1]);
        packed[i] = *reinterpret_cast<const unsigned*>(&h);
    }
    uint4* dst = emb_out + (size_t)gi * 4;
    #pragma unroll
    for (int k = 0; k < 4; ++k)
        dst[k] = make_uint4(packed[4*k+0], packed[4*k+1], packed[4*k+2], packed[4*k+3]);
}

// ================= MFMA MLP =================
__device__ __forceinline__ half8 ldfrag(const _Float16* __restrict__ frags, int off, int l) {
    return *reinterpret_cast<const half8*>(frags + off + l * 8);
}
__device__ __forceinline__ int swz(int f, int p) {
    return ((((f >> 3) + p) & 7) << 3) | (f & 7);
}
__device__ __forceinline__ half8 loadA(const _Float16* T, int p, int kb) {
    return *reinterpret_cast<const half8*>(T + p * 64 + ((((kb >> 3) + p) & 7) << 3));
}
// paired store: acc[t][r] holds output feature 4*p16+t for point g*4+r
template<bool RELU>
__device__ __forceinline__ void storePair(_Float16* T, const f32x4 (&acc)[4], int p16, int g) {
    #pragma unroll
    for (int r = 0; r < 4; ++r) {
        const int p = g * 4 + r;
        float v0 = acc[0][r], v1 = acc[1][r], v2 = acc[2][r], v3 = acc[3][r];
        if (RELU) { v0 = fmaxf(v0,0.f); v1 = fmaxf(v1,0.f); v2 = fmaxf(v2,0.f); v3 = fmaxf(v3,0.f); }
        const __half2 h01 = __floats2half2_rn(v0, v1);
        const __half2 h23 = __floats2half2_rn(v2, v3);
        const int blkb = ((p16 >> 1) + p) & 7;
        uint2* dst = reinterpret_cast<uint2*>(T + p * 64 + blkb * 8 + 4 * (p16 & 1));
        *dst = make_uint2(*reinterpret_cast<const unsigned*>(&h01),
                          *reinterpret_cast<const unsigned*>(&h23));
    }
}
__device__ __forceinline__ void pe_fill(_Float16* T, int p16, int g, float dx, float dy, float dz) {
    float pv0, pv1, pv2, pv3;
    if (g == 0)      { pv0 = dx;             pv1 = dy;         pv2 = dz;             pv3 = __sinf(dx); }
    else if (g == 1) { pv0 = __sinf(2.f*dx); pv1 = __sinf(dy); pv2 = __sinf(2.f*dy); pv3 = __sinf(dz); }
    else if (g == 2) { pv0 = __sinf(2.f*dz); pv1 = __cosf(dx); pv2 = __cosf(2.f*dx); pv3 = __cosf(dy); }
    else             { pv0 = __cosf(2.f*dy); pv1 = __cosf(dz); pv2 = __cosf(2.f*dz); pv3 = 0.f; }
    const float pv[4] = {pv0, pv1, pv2, pv3};
    #pragma unroll
    for (int j2 = 0; j2 < 4; ++j2) {
        const int f = 16 + g * 4 + j2;
        T[p16 * 64 + swz(f, p16)] = (_Float16)pv[j2];
    }
}
#define MFMA16(a, b, c) __builtin_amdgcn_mfma_f32_16x16x32_f16((a), (b), (c), 0, 0, 0)

__global__ __launch_bounds__(256) void ngp_mlp_mfma(
    const _Float16* __restrict__ embws,      // [N][32] f16
    const float4* __restrict__ dS,
    const _Float16* __restrict__ frags,
    const float* __restrict__ fb1, const float* __restrict__ fb2, const float* __restrict__ fb3,
    const float* __restrict__ rb1, const float* __restrict__ rb2, const float* __restrict__ rb3,
    const float* __restrict__ rb4,
    float* __restrict__ out, int N)
{
    __shared__ _Float16 tbuf[4][2][16 * 64];
    __shared__ float obuf[4][2][64];
    const int tid = threadIdx.x;
    const int wv = tid >> 6, l = tid & 63;
    const int p16 = l & 15, g = l >> 4;
    const int wbase = (blockIdx.x * 4 + wv) * 32;
    _Float16* T0 = tbuf[wv][0];
    _Float16* T1 = tbuf[wv][1];
    float* O0 = obuf[wv][0];
    float* O1 = obuf[wv][1];

    int pi0 = wbase + p16;      if (pi0 >= N) pi0 = N - 1;
    int pi1 = wbase + 16 + p16; if (pi1 >= N) pi1 = N - 1;
    const float4 d0 = dS[pi0];
    const float4 d1 = dS[pi1];

    f32x4 ac0[4], ac1[4];
    half8 x00, x01, x10, x11;

    // ---- L1 (K=32): A straight from packed emb ----
    {
        const half8 a0 = *reinterpret_cast<const half8*>(embws + (size_t)pi0 * 32 + g * 8);
        const half8 a1 = *reinterpret_cast<const half8*>(embws + (size_t)pi1 * 32 + g * 8);
        __builtin_amdgcn_s_setprio(1);
        #pragma unroll
        for (int t = 0; t < 4; ++t) {
            const float b = fb1[(p16 << 2) + t];
            const half8 w = ldfrag(frags, FO_L1 + t * 512, l);
            f32x4 c = {b, b, b, b};
            ac0[t] = MFMA16(a0, w, c);
            ac1[t] = MFMA16(a1, w, c);
        }
        __builtin_amdgcn_s_setprio(0);
    }
    storePair<true>(T0, ac0, p16, g);
    storePair<true>(T1, ac1, p16, g);
    x00 = loadA(T0, p16, g*8); x01 = loadA(T0, p16, 32 + g*8);
    x10 = loadA(T1, p16, g*8); x11 = loadA(T1, p16, 32 + g*8);

    // ---- L2 (K=64) ----
    __builtin_amdgcn_s_setprio(1);
    #pragma unroll
    for (int t = 0; t < 4; ++t) {
        const float b = fb2[(p16 << 2) + t];
        const half8 w0 = ldfrag(frags, FO_L2 + (2*t+0) * 512, l);
        const half8 w1 = ldfrag(frags, FO_L2 + (2*t+1) * 512, l);
        f32x4 c0 = {b, b, b, b}, c1 = {b, b, b, b};
        c0 = MFMA16(x00, w0, c0); ac0[t] = MFMA16(x01, w1, c0);
        c1 = MFMA16(x10, w0, c1); ac1[t] = MFMA16(x11, w1, c1);
    }
    __builtin_amdgcn_s_setprio(0);
    storePair<true>(T0, ac0, p16, g);
    storePair<true>(T1, ac1, p16, g);
    x00 = loadA(T0, p16, g*8); x01 = loadA(T0, p16, 32 + g*8);
    x10 = loadA(T1, p16, g*8); x11 = loadA(T1, p16, 32 + g*8);

    // ---- L3 (feat, 16 cols, natural mapping) ----
    {
        const float b = fb3[p16];
        const half8 wa = ldfrag(frags, FO_L3 + 0, l);
        const half8 wb = ldfrag(frags, FO_L3 + 512, l);
        f32x4 c0 = {b, b, b, b}, c1 = {b, b, b, b};
        __builtin_amdgcn_s_setprio(1);
        c0 = MFMA16(x00, wa, c0); c0 = MFMA16(x01, wb, c0);
        c1 = MFMA16(x10, wa, c1); c1 = MFMA16(x11, wb, c1);
        __builtin_amdgcn_s_setprio(0);
        if (p16 == 0) {
            #pragma unroll
            for (int rr = 0; rr < 4; ++rr) {
                O0[(g*4+rr)*4 + 3] = __expf(c0[rr]);
                O1[(g*4+rr)*4 + 3] = __expf(c1[rr]);
            }
        }
        #pragma unroll
        for (int rr = 0; rr < 4; ++rr) {
            const int p = g*4 + rr;
            T0[p*64 + swz(p16, p)] = (_Float16)c0[rr];
            T1[p*64 + swz(p16, p)] = (_Float16)c1[rr];
        }
    }

    // ---- PE fill: features 16..31 ----
    pe_fill(T0, p16, g, d0.x, d0.y, d0.z);
    pe_fill(T1, p16, g, d1.x, d1.y, d1.z);
    const half8 ar0 = loadA(T0, p16, g*8);
    const half8 ar1 = loadA(T1, p16, g*8);

    // ---- R1 (K=32) ----
    __builtin_amdgcn_s_setprio(1);
    #pragma unroll
    for (int t = 0; t < 4; ++t) {
        const float b = rb1[(p16 << 2) + t];
        const half8 w = ldfrag(frags, FO_R1 + t * 512, l);
        f32x4 c = {b, b, b, b};
        ac0[t] = MFMA16(ar0, w, c);
        ac1[t] = MFMA16(ar1, w, c);
    }
    __builtin_amdgcn_s_setprio(0);
    storePair<true>(T0, ac0, p16, g);
    storePair<true>(T1, ac1, p16, g);
    x00 = loadA(T0, p16, g*8); x01 = loadA(T0, p16, 32 + g*8);
    x10 = loadA(T1, p16, g*8); x11 = loadA(T1, p16, 32 + g*8);

    // ---- R2 (K=64) ----
    __builtin_amdgcn_s_setprio(1);
    #pragma unroll
    for (int t = 0; t < 4; ++t) {
        const float b = rb2[(p16 << 2) + t];
        const half8 w0 = ldfrag(frags, FO_R2 + (2*t+0) * 512, l);
        const half8 w1 = ldfrag(frags, FO_R2 + (2*t+1) * 512, l);
        f32x4 c0 = {b, b, b, b}, c1 = {b, b, b, b};
        c0 = MFMA16(x00, w0, c0); ac0[t] = MFMA16(x01, w1, c0);
        c1 = MFMA16(x10, w0, c1); ac1[t] = MFMA16(x11, w1, c1);
    }
    __builtin_amdgcn_s_setprio(0);
    storePair<true>(T0, ac0, p16, g);
    storePair<true>(T1, ac1, p16, g);
    x00 = loadA(T0, p16, g*8); x01 = loadA(T0, p16, 32 + g*8);
    x10 = loadA(T1, p16, g*8); x11 = loadA(T1, p16, 32 + g*8);

    // ---- R3 (K=64) ----
    __builtin_amdgcn_s_setprio(1);
    #pragma unroll
    for (int t = 0; t < 4; ++t) {
        const float b = rb3[(p16 << 2) + t];
        const half8 w0 = ldfrag(frags, FO_R3 + (2*t+0) * 512, l);
        const half8 w1 = ldfrag(frags, FO_R3 + (2*t+1) * 512, l);
        f32x4 c0 = {b, b, b, b}, c1 = {b, b, b, b};
        c0 = MFMA16(x00, w0, c0); ac0[t] = MFMA16(x01, w1, c0);
        c1 = MFMA16(x10, w0, c1); ac1[t] = MFMA16(x11, w1, c1);
    }
    __builtin_amdgcn_s_setprio(0);
    storePair<true>(T0, ac0, p16, g);
    storePair<true>(T1, ac1, p16, g);
    x00 = loadA(T0, p16, g*8); x01 = loadA(T0, p16, 32 + g*8);
    x10 = loadA(T1, p16, g*8); x11 = loadA(T1, p16, 32 + g*8);

    // ---- R4 (rgb, 3 cols, natural mapping) ----
    {
        const float b = (p16 < 3) ? rb4[p16] : 0.f;
        const half8 wa = ldfrag(frags, FO_R4 + 0, l);
        const half8 wb = ldfrag(frags, FO_R4 + 512, l);
        f32x4 c0 = {b, b, b, b}, c1 = {b, b, b, b};
        __builtin_amdgcn_s_setprio(1);
        c0 = MFMA16(x00, wa, c0); c0 = MFMA16(x01, wb, c0);
        c1 = MFMA16(x10, wa, c1); c1 = MFMA16(x11, wb, c1);
        __builtin_amdgcn_s_setprio(0);
        if (p16 < 3) {
            #pragma unroll
            for (int rr = 0; rr < 4; ++rr) {
                O0[(g*4+rr)*4 + p16] = 1.f / (1.f + __expf(-c0[rr]));
                O1[(g*4+rr)*4 + p16] = 1.f / (1.f + __expf(-c1[rr]));
            }
        }
    }

    // ---- scatter out ----
    if (wbase + p16 < N) {
        const unsigned orig = __float_as_uint(d0.w);
        out[(size_t)orig * 4 + g] = O0[p16 * 4 + g];
    }
    if (wbase + 16 + p16 < N) {
        const unsigned orig = __float_as_uint(d1.w);
        out[(size_t)orig * 4 + g] = O1[p16 * 4 + g];
    }
}

// ---------------- fused fallback (small ws, f32 table) ----------------
template<int NIN, int NOUT, bool RELU>
__device__ __forceinline__ void dense_l(const float* __restrict__ W, const float* __restrict__ Bias,
                                        const float* __restrict__ col, float (&out)[NOUT])
{
    #pragma unroll
    for (int j = 0; j < NOUT; ++j) out[j] = Bias[j];
    #pragma unroll 4
    for (int i = 0; i < NIN; ++i) {
        const float a = col[i * BLK];
        const float* Wr = W + i * NOUT;
        #pragma unroll
        for (int j = 0; j < NOUT; ++j) out[j] = fmaf(a, Wr[j], out[j]);
    }
    if (RELU) {
        #pragma unroll
        for (int j = 0; j < NOUT; ++j) out[j] = fmaxf(out[j], 0.f);
    }
}

__device__ __forceinline__ void encode_point_f(float x, float y, float z,
                                               const float* __restrict__ tableF,
                                               float (&emb)[32])
{
    constexpr int RES[16] = {32,38,46,55,67,80,97,116,140,168,203,244,294,353,425,512};
    constexpr int DN [16] = {1,1,1,1,1,1,1,1,1,1,1,1,0,0,0,0};
    constexpr int OFF[16] = {0,35937,95256,199079,374695,689127,1220568,2161760,
                             3763373,6566594,11393403,19883067,34589192,35113480,
                             35637768,36162056};
    constexpr unsigned NMASK = (1u << 19) - 1u;
    #pragma unroll
    for (int l = 0; l < 16; ++l) {
        const int res = RES[l];
        const float xl = x * (float)res, yl = y * (float)res, zl = z * (float)res;
        int cx = (int)floorf(xl); cx = cx < 0 ? 0 : (cx > res-1 ? res-1 : cx);
        int cy = (int)floorf(yl); cy = cy < 0 ? 0 : (cy > res-1 ? res-1 : cy);
        int cz = (int)floorf(zl); cz = cz < 0 ? 0 : (cz > res-1 ? res-1 : cz);
        const float wx = xl - (float)cx, wy = yl - (float)cy, wz = zl - (float)cz;
        float e0 = 0.f, e1 = 0.f;
        #pragma unroll
        for (int c = 0; c < 8; ++c) {
            const int dx = (c >> 2) & 1, dy = (c >> 1) & 1, dz = c & 1;
            int idx;
            if (DN[l]) {
                idx = (cx+dx) + (cy+dy)*(res+1) + (cz+dz)*(res+1)*(res+1);
            } else {
                const unsigned hh = (unsigned)(cx+dx) ^ ((unsigned)(cy+dy)*2654435761u)
                                  ^ ((unsigned)(cz+dz)*805459861u);
                idx = (int)(hh & NMASK);
            }
            const float w = (dx ? wx : 1.f-wx)*(dy ? wy : 1.f-wy)*(dz ? wz : 1.f-wz);
            const float2 v = *reinterpret_cast<const float2*>(tableF + (size_t)2*(size_t)(OFF[l]+idx));
            e0 = fmaf(v.x, w, e0); e1 = fmaf(v.y, w, e1);
        }
        emb[2*l+0] = e0; emb[2*l+1] = e1;
    }
}

__device__ __forceinline__ float4 mlp_lds(float* col, float dx0, float dy0, float dz0,
    const float* __restrict__ fw1, const float* __restrict__ fb1,
    const float* __restrict__ fw2, const float* __restrict__ fb2,
    const float* __restrict__ fw3, const float* __restrict__ fb3,
    const float* __restrict__ rw1, const float* __restrict__ rb1,
    const float* __restrict__ rw2, const float* __restrict__ rb2,
    const float* __restrict__ rw3, const float* __restrict__ rb3,
    const float* __restrict__ rw4, const float* __restrict__ rb4)
{
    float h[64];
    dense_l<32, 64, true>(fw1, fb1, col, h);
    #pragma unroll
    for (int j = 0; j < 64; ++j) col[j * BLK] = h[j];
    dense_l<64, 64, true>(fw2, fb2, col, h);
    #pragma unroll
    for (int j = 0; j < 64; ++j) col[j * BLK] = h[j];
    float feat16[16];
    dense_l<64, 16, false>(fw3, fb3, col, feat16);
    const float sigma = expf(feat16[0]);
    #pragma unroll
    for (int j = 0; j < 16; ++j) col[j * BLK] = feat16[j];
    col[16 * BLK] = dx0; col[17 * BLK] = dy0; col[18 * BLK] = dz0;
    {
        float s, c;
        sincosf(dx0,     &s, &c); col[19 * BLK] = s; col[25 * BLK] = c;
        sincosf(2.f*dx0, &s, &c); col[20 * BLK] = s; col[26 * BLK] = c;
        sincosf(dy0,     &s, &c); col[21 * BLK] = s; col[27 * BLK] = c;
        sincosf(2.f*dy0, &s, &c); col[22 * BLK] = s; col[28 * BLK] = c;
        sincosf(dz0,     &s, &c); col[23 * BLK] = s; col[29 * BLK] = c;
        sincosf(2.f*dz0, &s, &c); col[24 * BLK] = s; col[30 * BLK] = c;
    }
    dense_l<31, 64, true>(rw1, rb1, col, h);
    #pragma unroll
    for (int j = 0; j < 64; ++j) col[j * BLK] = h[j];
    dense_l<64, 64, true>(rw2, rb2, col, h);
    #pragma unroll
    for (int j = 0; j < 64; ++j) col[j * BLK] = h[j];
    dense_l<64, 64, true>(rw3, rb3, col, h);
    #pragma unroll
    for (int j = 0; j < 64; ++j) col[j * BLK] = h[j];
    float o0 = rb4[0], o1 = rb4[1], o2 = rb4[2];
    #pragma unroll 4
    for (int i = 0; i < 64; ++i) {
        const float a = col[i * BLK];
        o0 = fmaf(a, rw4[i*3 + 0], o0);
        o1 = fmaf(a, rw4[i*3 + 1], o1);
        o2 = fmaf(a, rw4[i*3 + 2], o2);
    }
    o0 = 1.f / (1.f + expf(-o0));
    o1 = 1.f / (1.f + expf(-o1));
    o2 = 1.f / (1.f + expf(-o2));
    return make_float4(o0, o1, o2, sigma);
}

__global__ __launch_bounds__(BLK) void ngp_fused_f32(
    const float* __restrict__ coords,
    const float* __restrict__ dirs,
    const float* __restrict__ tableF,
    const float* __restrict__ fw1, const float* __restrict__ fb1,
    const float* __restrict__ fw2, const float* __restrict__ fb2,
    const float* __restrict__ fw3, const float* __restrict__ fb3,
    const float* __restrict__ rw1, const float* __restrict__ rb1,
    const float* __restrict__ rw2, const float* __restrict__ rb2,
    const float* __restrict__ rw3, const float* __restrict__ rb3,
    const float* __restrict__ rw4, const float* __restrict__ rb4,
    float* __restrict__ out, int N)
{
    __shared__ float sbuf[64 * BLK];
    const int tid = threadIdx.x;
    const int gi  = blockIdx.x * BLK + tid;
    if (gi >= N) return;

    float emb[32];
    encode_point_f(coords[3*gi+0], coords[3*gi+1], coords[3*gi+2], tableF, emb);
    float* col = sbuf + tid;
    #pragma unroll
    for (int j = 0; j < 32; ++j) col[j * BLK] = emb[j];

    const float4 ov = mlp_lds(col, dirs[3*gi+0], dirs[3*gi+1], dirs[3*gi+2],
                              fw1, fb1, fw2, fb2, fw3, fb3,
                              rw1, rb1, rw2, rb2, rw3, rb3, rw4, rb4);
    reinterpret_cast<float4*>(out)[gi] = ov;
}

extern "C" void kernel_launch(void* const* d_in, const int* in_sizes, int n_in,
                              void* d_out, int out_size, void* d_ws, size_t ws_size,
                              hipStream_t stream)
{
    const float* coords = (const float*)d_in[0];
    const float* dirs   = (const float*)d_in[1];
    const float* table  = (const float*)d_in[2];
    const float* fw1 = (const float*)d_in[3];
    const float* fb1 = (const float*)d_in[4];
    const float* fw2 = (const float*)d_in[5];
    const float* fb2 = (const float*)d_in[6];
    const float* fw3 = (const float*)d_in[7];
    const float* fb3 = (const float*)d_in[8];
    const float* rw1 = (const float*)d_in[9];
    const float* rb1 = (const float*)d_in[10];
    const float* rw2 = (const float*)d_in[11];
    const float* rb2 = (const float*)d_in[12];
    const float* rw3 = (const float*)d_in[13];
    const float* rb3 = (const float*)d_in[14];
    const float* rw4 = (const float*)d_in[15];
    const float* rb4 = (const float*)d_in[16];

    const int N = in_sizes[0] / 3;

    // ws layout
    size_t pos = 0;
    auto take = [&](size_t bytes) { size_t p = pos; pos = (pos + bytes + 255) & ~(size_t)255; return p; };
    const size_t o_tableQ = take((size_t)TABQ_ENTRIES * 2);
    const size_t o_emb    = take((size_t)N * 64);
    const size_t o_cS     = take((size_t)N * 16);
    const size_t o_dS     = take((size_t)N * 16);
    const size_t o_hist   = take((size_t)NBINS * 4);
    const size_t o_cursor = take((size_t)NBINS * 4);
    const size_t o_bsum   = take(256 * 4);
    const size_t o_frag   = take((size_t)FRAG_TOTAL * 2);
    const size_t need_full = pos;

    char* ws = (char*)d_ws;

    if (ws_size >= need_full) {
        unsigned short* tableQ = (unsigned short*)(ws + o_tableQ);
        uint4*     embws  = (uint4*)(ws + o_emb);
        float4*    cS     = (float4*)(ws + o_cS);
        float4*    dS     = (float4*)(ws + o_dS);
        unsigned*  hist   = (unsigned*)(ws + o_hist);
        unsigned*  cursor = (unsigned*)(ws + o_cursor);
        unsigned*  bsum   = (unsigned*)(ws + o_bsum);
        _Float16*  frag   = (_Float16*)(ws + o_frag);

        hipLaunchKernelGGL(cvt_lo, dim3((PAIR_LO + 255) / 256), dim3(256), 0, stream,
                           (const float4*)table, (unsigned*)tableQ);
        hipLaunchKernelGGL(cvt_hash, dim3(PAIR_H / 256), dim3(256), 0, stream,
                           (const float4*)table, (unsigned*)tableQ);
        hipLaunchKernelGGL(cvt_morton, dim3(MTOT / 256), dim3(256), 0, stream,
                           table, tableQ);
        hipLaunchKernelGGL(prep_frags, dim3(FRAG_TOTAL / 256), dim3(256), 0, stream,
                           fw1, fw2, fw3, rw1, rw2, rw3, rw4, frag);
        hipMemsetAsync(hist, 0, (size_t)NBINS * 4, stream);
        hipLaunchKernelGGL(hist_build, dim3((N + 255) / 256), dim3(256), 0, stream,
                           coords, hist, N);
        hipLaunchKernelGGL(scan1, dim3(NBINS / 1024), dim3(256), 0, stream, hist, bsum);
        hipLaunchKernelGGL(scan2, dim3(1), dim3(256), 0, stream, bsum);
        hipLaunchKernelGGL(scan3, dim3(NBINS / 256), dim3(256), 0, stream, hist, bsum, cursor);
        hipLaunchKernelGGL(scatter_pts, dim3((N + 255) / 256), dim3(256), 0, stream,
                           coords, dirs, cursor, cS, dS, N);
        hipLaunchKernelGGL(ngp_encode, dim3((N + EBLK - 1) / EBLK), dim3(EBLK), 0, stream,
                           cS, tableQ, embws, N);
        hipLaunchKernelGGL(ngp_mlp_mfma, dim3((N + 127) / 128), dim3(256), 0, stream,
                           (const _Float16*)embws, dS, frag,
                           fb1, fb2, fb3, rb1, rb2, rb3, rb4,
                           (float*)d_out, N);
    } else {
        hipLaunchKernelGGL(ngp_fused_f32, dim3((N + BLK - 1) / BLK), dim3(BLK), 0, stream,
                           coords, dirs, table,
                           fw1, fb1, fw2, fb2, fw3, fb3,
                           rw1, rb1, rw2, rb2, rw3, rb3, rw4, rb4,
                           (float*)d_out, N);
    }
}

// Round 10
// 1597.447 us; speedup vs baseline: 1.7719x; 1.7719x over previous
//
#include <hip/hip_runtime.h>
#include <hip/hip_fp16.h>
#include <math.h>

#define BLK 128          // fused-fallback block
#define EBLK 256         // encode / utility block
#define NBINS (1 << 18)  // 6 bits per axis, Morton sort bins
#define Q_SCALE 65536.0f
#define Q_DESCALE 0x1p-16f

typedef __attribute__((ext_vector_type(8))) _Float16 half8;
typedef __attribute__((ext_vector_type(4))) float f32x4;
typedef __attribute__((ext_vector_type(2))) float f32x2;

// frag offsets in f16 elements: L1,L2,L3,R1,R2,R3,R4
#define FO_L1 0
#define FO_L2 2048
#define FO_L3 6144
#define FO_R1 7168
#define FO_R2 9216
#define FO_R3 13312
#define FO_R4 17408
#define FRAG_TOTAL 18432

// ---- table shapes ----
#define PD_ENTRIES 3763373           // dense levels 0-7, u32 x-pair each
#define MTOT 47710208                // morton levels 8-11, u16 each
#define PH_ENTRIES (4 * 524288)      // hashed levels 12-15, u32 pair each

// ---------------- Morton helpers ----------------
__device__ __forceinline__ unsigned mexp(unsigned v) {
    v &= 0x3FF;
    v = (v | (v << 16)) & 0x030000FF;
    v = (v | (v << 8))  & 0x0300F00F;
    v = (v | (v << 4))  & 0x030C30C3;
    v = (v | (v << 2))  & 0x09249249;
    return v;
}
__device__ __forceinline__ unsigned mcomp(unsigned v) {
    v &= 0x09249249u;
    v = (v | (v >> 2)) & 0x030C30C3u;
    v = (v | (v >> 4)) & 0x0300F00Fu;
    v = (v | (v >> 8)) & 0x030000FFu;
    v = (v | (v >> 16)) & 0x3FFu;
    return v;
}
__device__ __forceinline__ unsigned morton_key(float x, float y, float z) {
    int bx = (int)(x * 64.f); bx = bx < 0 ? 0 : (bx > 63 ? 63 : bx);
    int by = (int)(y * 64.f); by = by < 0 ? 0 : (by > 63 ? 63 : by);
    int bz = (int)(z * 64.f); bz = bz < 0 ? 0 : (bz > 63 ? 63 : bz);
    return (mexp((unsigned)bx) << 2) | (mexp((unsigned)by) << 1) | mexp((unsigned)bz);
}

// ---------------- table conversion kernels ----------------
__device__ __forceinline__ unsigned pk_fp8(float a, float b) {
    const int lo = __builtin_amdgcn_cvt_pk_fp8_f32(a * Q_SCALE, b * Q_SCALE, 0, false);
    return (unsigned)lo & 0xFFFFu;
}

// dense levels 0-7: u32[e] = (q[e], q[e+1])  (x-pair; e+1 overflow value unused)
__global__ __launch_bounds__(256) void cvt_pd(const float* __restrict__ srcF,
                                              unsigned* __restrict__ pd)
{
    const int e = blockIdx.x * 256 + threadIdx.x;
    if (e >= PD_ENTRIES) return;
    const float2 a = *reinterpret_cast<const float2*>(srcF + 2 * (size_t)e);
    const float2 b = *reinterpret_cast<const float2*>(srcF + 2 * ((size_t)e + 1));
    pd[e] = pk_fp8(a.x, a.y) | (pk_fp8(b.x, b.y) << 16);
}

// hashed levels 12-15: u32[(j<<19)+h] = (q[h], q[h^1])
__global__ __launch_bounds__(256) void cvt_ph(const float* __restrict__ srcF,
                                              unsigned* __restrict__ ph)
{
    const int i = blockIdx.x * 256 + threadIdx.x;
    if (i >= PH_ENTRIES) return;
    constexpr unsigned SOFF[4] = {34589192u, 35113480u, 35637768u, 36162056u};
    const int j = i >> 19;
    const unsigned h = (unsigned)i & 524287u;
    const size_t s0 = (size_t)SOFF[j] + h;
    const size_t s1 = (size_t)SOFF[j] + (h ^ 1u);
    const float2 a = *reinterpret_cast<const float2*>(srcF + 2 * s0);
    const float2 b = *reinterpret_cast<const float2*>(srcF + 2 * s1);
    ph[i] = pk_fp8(a.x, a.y) | (pk_fp8(b.x, b.y) << 16);
}

// Morton-block levels 8-11 (verbatim R7 logic, standalone u16 array)
__global__ __launch_bounds__(256) void cvt_mt(const float* __restrict__ srcF,
                                              unsigned short* __restrict__ mt)
{
    const unsigned e = blockIdx.x * 256 + threadIdx.x;
    if (e >= MTOT) return;
    int j, cnt; unsigned base;
    if (e < 14155776u) {
        cnt = 3;
        if (e < 7077888u) { j = 0; base = 0u; }
        else              { j = 1; base = 7077888u; }
    } else {
        cnt = 4;
        if (e < 30932992u){ j = 2; base = 14155776u; }
        else              { j = 3; base = 30932992u; }
    }
    const unsigned within = e - base;
    const unsigned blk = within >> 18, lo = within & 0x3FFFFu;
    unsigned bx, by, bz;
    if (cnt == 3) { bx = blk % 3u; const unsigned t = blk / 3u; by = t % 3u; bz = t / 3u; }
    else          { bx = blk & 3u; by = (blk >> 2) & 3u; bz = blk >> 4; }
    const unsigned x = bx * 64u + mcomp(lo);
    const unsigned y = by * 64u + mcomp(lo >> 1);
    const unsigned z = bz * 64u + mcomp(lo >> 2);

    constexpr unsigned RES1[4] = {141u, 169u, 204u, 245u};
    constexpr unsigned SOFF[4] = {3763373u, 6566594u, 11393403u, 19883067u};
    const unsigned r1 = RES1[j];
    unsigned q = 0;
    if (x < r1 && y < r1 && z < r1) {
        const size_t se = (size_t)SOFF[j] + x + (size_t)y * r1 + (size_t)z * r1 * r1;
        const float2 v = *reinterpret_cast<const float2*>(srcF + 2 * se);
        q = pk_fp8(v.x, v.y);
    }
    mt[e] = (unsigned short)q;
}

// ---------------- weight fragment packing ----------------
__global__ __launch_bounds__(256) void prep_frags(
    const float* __restrict__ fw1, const float* __restrict__ fw2, const float* __restrict__ fw3,
    const float* __restrict__ rw1, const float* __restrict__ rw2, const float* __restrict__ rw3,
    const float* __restrict__ rw4, _Float16* __restrict__ frag)
{
    const int gid = blockIdx.x * 256 + threadIdx.x;
    if (gid >= FRAG_TOTAL) return;
    constexpr int offs[8] = {FO_L1, FO_L2, FO_L3, FO_R1, FO_R2, FO_R3, FO_R4, FRAG_TOTAL};
    constexpr int Ks[7]   = {32, 64, 64, 31, 64, 64, 64};
    constexpr int NO[7]   = {64, 64, 16, 64, 64, 64, 3};
    constexpr int NKs[7]  = {1, 2, 2, 1, 2, 2, 2};
    int layer = 0;
    #pragma unroll
    for (int i = 1; i < 7; ++i) if (gid >= offs[i]) layer = i;
    const float* W = fw1;
    if (layer == 1) W = fw2; else if (layer == 2) W = fw3;
    else if (layer == 3) W = rw1; else if (layer == 4) W = rw2;
    else if (layer == 5) W = rw3; else if (layer == 6) W = rw4;

    const int e = gid - offs[layer];
    const int nk = NKs[layer];
    const int blk = e >> 9, within = e & 511;
    const int t = blk / nk, ks = blk - t * nk;
    const int lane = within >> 3, i = within & 7;
    const int k = ks * 32 + (lane >> 4) * 8 + i;
    // 64-wide layers: col c of tile t holds output feature 4*c + t (paired-store remap)
    const int col = (NO[layer] == 64) ? ((lane & 15) * 4 + t) : (t * 16 + (lane & 15));
    float v = 0.f;
    if (k < Ks[layer] && col < NO[layer]) v = W[k * NO[layer] + col];
    frag[gid] = (_Float16)v;
}

// ---------------- sort: histogram ----------------
__global__ __launch_bounds__(256) void hist_build(const float* __restrict__ coords,
                                                  unsigned* __restrict__ hist, int N)
{
    const int i = blockIdx.x * 256 + threadIdx.x;
    if (i >= N) return;
    const unsigned key = morton_key(coords[3*i+0], coords[3*i+1], coords[3*i+2]);
    atomicAdd(&hist[key], 1u);
}

// ---------------- sort: hierarchical exclusive scan ----------------
__global__ __launch_bounds__(256) void scan1(unsigned* __restrict__ hist, unsigned* __restrict__ bsum)
{
    __shared__ unsigned sa[256], sb[256];
    const int t = threadIdx.x;
    const unsigned base = blockIdx.x * 1024u + (unsigned)t * 4u;
    const unsigned v0 = hist[base+0], v1 = hist[base+1], v2 = hist[base+2], v3 = hist[base+3];
    const unsigned sum = v0 + v1 + v2 + v3;
    sa[t] = sum; __syncthreads();
    unsigned* src = sa; unsigned* dst = sb;
    for (int off = 1; off < 256; off <<= 1) {
        dst[t] = src[t] + (t >= off ? src[t - off] : 0u);
        __syncthreads();
        unsigned* tmp = src; src = dst; dst = tmp;
    }
    const unsigned incl = src[t];
    unsigned run = incl - sum;
    hist[base+0] = run; run += v0;
    hist[base+1] = run; run += v1;
    hist[base+2] = run; run += v2;
    hist[base+3] = run;
    if (t == 255) bsum[blockIdx.x] = incl;
}

__global__ __launch_bounds__(256) void scan2(unsigned* __restrict__ bsum)
{
    __shared__ unsigned sa[256], sb[256];
    const int t = threadIdx.x;
    const unsigned v = bsum[t];
    sa[t] = v; __syncthreads();
    unsigned* src = sa; unsigned* dst = sb;
    for (int off = 1; off < 256; off <<= 1) {
        dst[t] = src[t] + (t >= off ? src[t - off] : 0u);
        __syncthreads();
        unsigned* tmp = src; src = dst; dst = tmp;
    }
    bsum[t] = src[t] - v;
}

__global__ __launch_bounds__(256) void scan3(const unsigned* __restrict__ hist,
                                             const unsigned* __restrict__ bsum,
                                             unsigned* __restrict__ cursor)
{
    const int i = blockIdx.x * 256 + threadIdx.x;
    cursor[i] = hist[i] + bsum[i >> 10];
}

// ---------------- sort: scatter points into bins ----------------
__global__ __launch_bounds__(256) void scatter_pts(const float* __restrict__ coords,
                                                   const float* __restrict__ dirs,
                                                   unsigned* __restrict__ cursor,
                                                   float4* __restrict__ cS,
                                                   float4* __restrict__ dS, int N)
{
    const int i = blockIdx.x * 256 + threadIdx.x;
    if (i >= N) return;
    const float x = coords[3*i+0], y = coords[3*i+1], z = coords[3*i+2];
    const unsigned key = morton_key(x, y, z);
    const unsigned slot = atomicAdd(&cursor[key], 1u);
    cS[slot] = make_float4(x, y, z, __uint_as_float((unsigned)i));
    dS[slot] = make_float4(dirs[3*i+0], dirs[3*i+1], dirs[3*i+2], __uint_as_float((unsigned)i));
}

// ---------------- encode kernel ----------------
__global__ __launch_bounds__(EBLK, 8) void ngp_encode(
    const float4* __restrict__ cS,
    const unsigned* __restrict__ PD,
    const unsigned short* __restrict__ MT,
    const unsigned* __restrict__ PH,
    uint4* __restrict__ emb_out, int N)
{
    // bijective XCD-contiguous remap of blockIdx (8 XCDs)
    const unsigned nwg = gridDim.x;
    const unsigned bid = blockIdx.x;
    const unsigned qn = nwg >> 3, rn = nwg & 7;
    const unsigned xc = bid & 7, ib = bid >> 3;
    const unsigned nb = (xc < rn ? xc * (qn + 1) : rn * (qn + 1) + (xc - rn) * qn) + ib;

    const int gi = (int)(nb * EBLK + threadIdx.x);
    if (gi >= N) return;

    const float4 cp = cS[gi];
    const float x = cp.x, y = cp.y, z = cp.z;

    float emb[32];

    // ---- dense levels 0-7: one u32 pair-load per (dy,dz) corner-row ----
    {
        constexpr int RES[8] = {32,38,46,55,67,80,97,116};
        constexpr int OFF[8] = {0,35937,95256,199079,374695,689127,1220568,2161760};
        #pragma unroll
        for (int lv = 0; lv < 8; ++lv) {
            const int res = RES[lv];
            const float xl = x * (float)res, yl = y * (float)res, zl = z * (float)res;
            int cx = (int)floorf(xl); cx = cx < 0 ? 0 : (cx > res-1 ? res-1 : cx);
            int cy = (int)floorf(yl); cy = cy < 0 ? 0 : (cy > res-1 ? res-1 : cy);
            int cz = (int)floorf(zl); cz = cz < 0 ? 0 : (cz > res-1 ? res-1 : cz);
            const float wx = xl - (float)cx, wy = yl - (float)cy, wz = zl - (float)cz;
            const int res1 = res + 1;
            unsigned qv[8];
            #pragma unroll
            for (int p = 0; p < 4; ++p) {           // p = (dy<<1)|dz
                const int dy = (p >> 1) & 1, dz = p & 1;
                const unsigned w = PD[OFF[lv] + cx + (cy+dy)*res1 + (cz+dz)*res1*res1];
                qv[p] = w & 0xFFFFu; qv[p + 4] = w >> 16;
            }
            float e0 = 0.f, e1 = 0.f;
            #pragma unroll
            for (int c = 0; c < 8; ++c) {
                const int dx = (c >> 2) & 1, dy = (c >> 1) & 1, dz = c & 1;
                const float w = (dx ? wx : 1.f-wx)*(dy ? wy : 1.f-wy)*(dz ? wz : 1.f-wz);
                const f32x2 vf = __builtin_amdgcn_cvt_pk_f32_fp8((int)qv[c], false);
                e0 = fmaf(vf.x, w, e0); e1 = fmaf(vf.y, w, e1);
            }
            emb[2*lv+0] = e0 * Q_DESCALE; emb[2*lv+1] = e1 * Q_DESCALE;
        }
    }

    // ---- Morton-block dense levels 8-11 (verbatim R7 structure) ----
    {
        constexpr int RESM[4] = {140,168,203,244};
        constexpr int CNTM[4] = {3,3,4,4};
        constexpr unsigned MOFF[4] = {0u, 7077888u, 14155776u, 30932992u};
        #pragma unroll
        for (int j = 0; j < 4; ++j) {
            const int res = RESM[j];
            const int cnt = CNTM[j];
            const float xl = x * (float)res, yl = y * (float)res, zl = z * (float)res;
            int cx = (int)floorf(xl); cx = cx < 0 ? 0 : (cx > res-1 ? res-1 : cx);
            int cy = (int)floorf(yl); cy = cy < 0 ? 0 : (cy > res-1 ? res-1 : cy);
            int cz = (int)floorf(zl); cz = cz < 0 ? 0 : (cz > res-1 ? res-1 : cz);
            const float wx = xl - (float)cx, wy = yl - (float)cy, wz = zl - (float)cz;

            const int bx0 = cx >> 6, bx1 = (cx+1) >> 6;
            const int by0 = cy >> 6, by1 = (cy+1) >> 6;
            const int bz0 = cz >> 6, bz1 = (cz+1) >> 6;
            const unsigned mx0 = mexp(cx & 63),      mx1 = mexp((cx+1) & 63);
            const unsigned my0 = mexp(cy & 63) << 1, my1 = mexp((cy+1) & 63) << 1;
            const unsigned mz0 = mexp(cz & 63) << 2, mz1 = mexp((cz+1) & 63) << 2;

            unsigned qv[8];
            #pragma unroll
            for (int c = 0; c < 8; ++c) {
                const int dx = (c >> 2) & 1, dy = (c >> 1) & 1, dz = c & 1;
                const int bx = dx ? bx1 : bx0, by = dy ? by1 : by0, bz = dz ? bz1 : bz0;
                const unsigned mm = (dx ? mx1 : mx0) | (dy ? my1 : my0) | (dz ? mz1 : mz0);
                const unsigned blk = (unsigned)((bz * cnt + by) * cnt + bx);
                qv[c] = MT[(size_t)MOFF[j] + ((blk << 18) | mm)];
            }
            float e0 = 0.f, e1 = 0.f;
            #pragma unroll
            for (int c = 0; c < 8; ++c) {
                const int dx = (c >> 2) & 1, dy = (c >> 1) & 1, dz = c & 1;
                const float w = (dx ? wx : 1.f-wx)*(dy ? wy : 1.f-wy)*(dz ? wz : 1.f-wz);
                const f32x2 vf = __builtin_amdgcn_cvt_pk_f32_fp8((int)qv[c], false);
                e0 = fmaf(vf.x, w, e0); e1 = fmaf(vf.y, w, e1);
            }
            emb[16+2*j+0] = e0 * Q_DESCALE; emb[16+2*j+1] = e1 * Q_DESCALE;
        }
    }

    // ---- hashed levels 12-15: pair u32, extra load only for odd cx ----
    {
        constexpr int RESH[4] = {294,353,425,512};
        constexpr unsigned NMASK = (1u << 19) - 1u;
        #pragma unroll
        for (int j = 0; j < 4; ++j) {
            const int res = RESH[j];
            const float xl = x * (float)res, yl = y * (float)res, zl = z * (float)res;
            int cx = (int)floorf(xl); cx = cx < 0 ? 0 : (cx > res-1 ? res-1 : cx);
            int cy = (int)floorf(yl); cy = cy < 0 ? 0 : (cy > res-1 ? res-1 : cy);
            int cz = (int)floorf(zl); cz = cz < 0 ? 0 : (cz > res-1 ? res-1 : cz);
            const float wx = xl - (float)cx, wy = yl - (float)cy, wz = zl - (float)cz;
            const unsigned lvbase = (unsigned)j << 19;
            const bool xodd = (cx & 1) != 0;
            unsigned qv[8];
            #pragma unroll
            for (int p = 0; p < 4; ++p) {
                const int dy = (p >> 1) & 1, dz = p & 1;
                const unsigned hyz = ((unsigned)(cy+dy) * 2654435761u)
                                   ^ ((unsigned)(cz+dz) * 805459861u);
                const unsigned h0 = ((unsigned)cx ^ hyz) & NMASK;
                const unsigned w0 = PH[lvbase + h0];
                unsigned q0 = w0 & 0xFFFFu;
                unsigned q1 = w0 >> 16;                 // = q[h0^1] (valid when cx even)
                if (xodd) {
                    const unsigned h1 = (((unsigned)cx + 1u) ^ hyz) & NMASK;
                    q1 = PH[lvbase + h1] & 0xFFFFu;
                }
                qv[p] = q0; qv[p + 4] = q1;
            }
            float e0 = 0.f, e1 = 0.f;
            #pragma unroll
            for (int c = 0; c < 8; ++c) {
                const int dx = (c >> 2) & 1, dy = (c >> 1) & 1, dz = c & 1;
                const float w = (dx ? wx : 1.f-wx)*(dy ? wy : 1.f-wy)*(dz ? wz : 1.f-wz);
                const f32x2 vf = __builtin_amdgcn_cvt_pk_f32_fp8((int)qv[c], false);
                e0 = fmaf(vf.x, w, e0); e1 = fmaf(vf.y, w, e1);
            }
            emb[24+2*j+0] = e0 * Q_DESCALE; emb[24+2*j+1] = e1 * Q_DESCALE;
        }
    }

    unsigned packed[16];
    #pragma unroll
    for (int i = 0; i < 16; ++i) {
        const __half2 h = __floats2half2_rn(emb[2*i+0], emb[2*i+1]);
        packed[i] = *reinterpret_cast<const unsigned*>(&h);
    }
    uint4* dst = emb_out + (size_t)gi * 4;
    #pragma unroll
    for (int k = 0; k < 4; ++k)
        dst[k] = make_uint4(packed[4*k+0], packed[4*k+1], packed[4*k+2], packed[4*k+3]);
}

// ================= MFMA MLP (verbatim R7) =================
__device__ __forceinline__ half8 ldfrag(const _Float16* __restrict__ frags, int off, int l) {
    return *reinterpret_cast<const half8*>(frags + off + l * 8);
}
__device__ __forceinline__ int swz(int f, int p) {
    return ((((f >> 3) + p) & 7) << 3) | (f & 7);
}
__device__ __forceinline__ half8 loadA(const _Float16* T, int p, int kb) {
    return *reinterpret_cast<const half8*>(T + p * 64 + ((((kb >> 3) + p) & 7) << 3));
}
// paired store: acc[t][r] holds output feature 4*p16+t for point g*4+r
template<bool RELU>
__device__ __forceinline__ void storePair(_Float16* T, const f32x4 (&acc)[4], int p16, int g) {
    #pragma unroll
    for (int r = 0; r < 4; ++r) {
        const int p = g * 4 + r;
        float v0 = acc[0][r], v1 = acc[1][r], v2 = acc[2][r], v3 = acc[3][r];
        if (RELU) { v0 = fmaxf(v0,0.f); v1 = fmaxf(v1,0.f); v2 = fmaxf(v2,0.f); v3 = fmaxf(v3,0.f); }
        const __half2 h01 = __floats2half2_rn(v0, v1);
        const __half2 h23 = __floats2half2_rn(v2, v3);
        const int blkb = ((p16 >> 1) + p) & 7;
        uint2* dst = reinterpret_cast<uint2*>(T + p * 64 + blkb * 8 + 4 * (p16 & 1));
        *dst = make_uint2(*reinterpret_cast<const unsigned*>(&h01),
                          *reinterpret_cast<const unsigned*>(&h23));
    }
}
__device__ __forceinline__ void pe_fill(_Float16* T, int p16, int g, float dx, float dy, float dz) {
    float pv0, pv1, pv2, pv3;
    if (g == 0)      { pv0 = dx;             pv1 = dy;         pv2 = dz;             pv3 = __sinf(dx); }
    else if (g == 1) { pv0 = __sinf(2.f*dx); pv1 = __sinf(dy); pv2 = __sinf(2.f*dy); pv3 = __sinf(dz); }
    else if (g == 2) { pv0 = __sinf(2.f*dz); pv1 = __cosf(dx); pv2 = __cosf(2.f*dx); pv3 = __cosf(dy); }
    else             { pv0 = __cosf(2.f*dy); pv1 = __cosf(dz); pv2 = __cosf(2.f*dz); pv3 = 0.f; }
    const float pv[4] = {pv0, pv1, pv2, pv3};
    #pragma unroll
    for (int j2 = 0; j2 < 4; ++j2) {
        const int f = 16 + g * 4 + j2;
        T[p16 * 64 + swz(f, p16)] = (_Float16)pv[j2];
    }
}
#define MFMA16(a, b, c) __builtin_amdgcn_mfma_f32_16x16x32_f16((a), (b), (c), 0, 0, 0)

__global__ __launch_bounds__(256) void ngp_mlp_mfma(
    const _Float16* __restrict__ embws,      // [N][32] f16
    const float4* __restrict__ dS,
    const _Float16* __restrict__ frags,
    const float* __restrict__ fb1, const float* __restrict__ fb2, const float* __restrict__ fb3,
    const float* __restrict__ rb1, const float* __restrict__ rb2, const float* __restrict__ rb3,
    const float* __restrict__ rb4,
    float* __restrict__ out, int N)
{
    __shared__ _Float16 tbuf[4][2][16 * 64];
    __shared__ float obuf[4][2][64];
    const int tid = threadIdx.x;
    const int wv = tid >> 6, l = tid & 63;
    const int p16 = l & 15, g = l >> 4;
    const int wbase = (blockIdx.x * 4 + wv) * 32;
    _Float16* T0 = tbuf[wv][0];
    _Float16* T1 = tbuf[wv][1];
    float* O0 = obuf[wv][0];
    float* O1 = obuf[wv][1];

    int pi0 = wbase + p16;      if (pi0 >= N) pi0 = N - 1;
    int pi1 = wbase + 16 + p16; if (pi1 >= N) pi1 = N - 1;
    const float4 d0 = dS[pi0];
    const float4 d1 = dS[pi1];

    f32x4 ac0[4], ac1[4];
    half8 x00, x01, x10, x11;

    // ---- L1 (K=32): A straight from packed emb ----
    {
        const half8 a0 = *reinterpret_cast<const half8*>(embws + (size_t)pi0 * 32 + g * 8);
        const half8 a1 = *reinterpret_cast<const half8*>(embws + (size_t)pi1 * 32 + g * 8);
        __builtin_amdgcn_s_setprio(1);
        #pragma unroll
        for (int t = 0; t < 4; ++t) {
            const float b = fb1[(p16 << 2) + t];
            const half8 w = ldfrag(frags, FO_L1 + t * 512, l);
            f32x4 c = {b, b, b, b};
            ac0[t] = MFMA16(a0, w, c);
            ac1[t] = MFMA16(a1, w, c);
        }
        __builtin_amdgcn_s_setprio(0);
    }
    storePair<true>(T0, ac0, p16, g);
    storePair<true>(T1, ac1, p16, g);
    x00 = loadA(T0, p16, g*8); x01 = loadA(T0, p16, 32 + g*8);
    x10 = loadA(T1, p16, g*8); x11 = loadA(T1, p16, 32 + g*8);

    // ---- L2 (K=64) ----
    __builtin_amdgcn_s_setprio(1);
    #pragma unroll
    for (int t = 0; t < 4; ++t) {
        const float b = fb2[(p16 << 2) + t];
        const half8 w0 = ldfrag(frags, FO_L2 + (2*t+0) * 512, l);
        const half8 w1 = ldfrag(frags, FO_L2 + (2*t+1) * 512, l);
        f32x4 c0 = {b, b, b, b}, c1 = {b, b, b, b};
        c0 = MFMA16(x00, w0, c0); ac0[t] = MFMA16(x01, w1, c0);
        c1 = MFMA16(x10, w0, c1); ac1[t] = MFMA16(x11, w1, c1);
    }
    __builtin_amdgcn_s_setprio(0);
    storePair<true>(T0, ac0, p16, g);
    storePair<true>(T1, ac1, p16, g);
    x00 = loadA(T0, p16, g*8); x01 = loadA(T0, p16, 32 + g*8);
    x10 = loadA(T1, p16, g*8); x11 = loadA(T1, p16, 32 + g*8);

    // ---- L3 (feat, 16 cols, natural mapping) ----
    {
        const float b = fb3[p16];
        const half8 wa = ldfrag(frags, FO_L3 + 0, l);
        const half8 wb = ldfrag(frags, FO_L3 + 512, l);
        f32x4 c0 = {b, b, b, b}, c1 = {b, b, b, b};
        __builtin_amdgcn_s_setprio(1);
        c0 = MFMA16(x00, wa, c0); c0 = MFMA16(x01, wb, c0);
        c1 = MFMA16(x10, wa, c1); c1 = MFMA16(x11, wb, c1);
        __builtin_amdgcn_s_setprio(0);
        if (p16 == 0) {
            #pragma unroll
            for (int rr = 0; rr < 4; ++rr) {
                O0[(g*4+rr)*4 + 3] = __expf(c0[rr]);
                O1[(g*4+rr)*4 + 3] = __expf(c1[rr]);
            }
        }
        #pragma unroll
        for (int rr = 0; rr < 4; ++rr) {
            const int p = g*4 + rr;
            T0[p*64 + swz(p16, p)] = (_Float16)c0[rr];
            T1[p*64 + swz(p16, p)] = (_Float16)c1[rr];
        }
    }

    // ---- PE fill: features 16..31 ----
    pe_fill(T0, p16, g, d0.x, d0.y, d0.z);
    pe_fill(T1, p16, g, d1.x, d1.y, d1.z);
    const half8 ar0 = loadA(T0, p16, g*8);
    const half8 ar1 = loadA(T1, p16, g*8);

    // ---- R1 (K=32) ----
    __builtin_amdgcn_s_setprio(1);
    #pragma unroll
    for (int t = 0; t < 4; ++t) {
        const float b = rb1[(p16 << 2) + t];
        const half8 w = ldfrag(frags, FO_R1 + t * 512, l);
        f32x4 c = {b, b, b, b};
        ac0[t] = MFMA16(ar0, w, c);
        ac1[t] = MFMA16(ar1, w, c);
    }
    __builtin_amdgcn_s_setprio(0);
    storePair<true>(T0, ac0, p16, g);
    storePair<true>(T1, ac1, p16, g);
    x00 = loadA(T0, p16, g*8); x01 = loadA(T0, p16, 32 + g*8);
    x10 = loadA(T1, p16, g*8); x11 = loadA(T1, p16, 32 + g*8);

    // ---- R2 (K=64) ----
    __builtin_amdgcn_s_setprio(1);
    #pragma unroll
    for (int t = 0; t < 4; ++t) {
        const float b = rb2[(p16 << 2) + t];
        const half8 w0 = ldfrag(frags, FO_R2 + (2*t+0) * 512, l);
        const half8 w1 = ldfrag(frags, FO_R2 + (2*t+1) * 512, l);
        f32x4 c0 = {b, b, b, b}, c1 = {b, b, b, b};
        c0 = MFMA16(x00, w0, c0); ac0[t] = MFMA16(x01, w1, c0);
        c1 = MFMA16(x10, w0, c1); ac1[t] = MFMA16(x11, w1, c1);
    }
    __builtin_amdgcn_s_setprio(0);
    storePair<true>(T0, ac0, p16, g);
    storePair<true>(T1, ac1, p16, g);
    x00 = loadA(T0, p16, g*8); x01 = loadA(T0, p16, 32 + g*8);
    x10 = loadA(T1, p16, g*8); x11 = loadA(T1, p16, 32 + g*8);

    // ---- R3 (K=64) ----
    __builtin_amdgcn_s_setprio(1);
    #pragma unroll
    for (int t = 0; t < 4; ++t) {
        const float b = rb3[(p16 << 2) + t];
        const half8 w0 = ldfrag(frags, FO_R3 + (2*t+0) * 512, l);
        const half8 w1 = ldfrag(frags, FO_R3 + (2*t+1) * 512, l);
        f32x4 c0 = {b, b, b, b}, c1 = {b, b, b, b};
        c0 = MFMA16(x00, w0, c0); ac0[t] = MFMA16(x01, w1, c0);
        c1 = MFMA16(x10, w0, c1); ac1[t] = MFMA16(x11, w1, c1);
    }
    __builtin_amdgcn_s_setprio(0);
    storePair<true>(T0, ac0, p16, g);
    storePair<true>(T1, ac1, p16, g);
    x00 = loadA(T0, p16, g*8); x01 = loadA(T0, p16, 32 + g*8);
    x10 = loadA(T1, p16, g*8); x11 = loadA(T1, p16, 32 + g*8);

    // ---- R4 (rgb, 3 cols, natural mapping) ----
    {
        const float b = (p16 < 3) ? rb4[p16] : 0.f;
        const half8 wa = ldfrag(frags, FO_R4 + 0, l);
        const half8 wb = ldfrag(frags, FO_R4 + 512, l);
        f32x4 c0 = {b, b, b, b}, c1 = {b, b, b, b};
        __builtin_amdgcn_s_setprio(1);
        c0 = MFMA16(x00, wa, c0); c0 = MFMA16(x01, wb, c0);
        c1 = MFMA16(x10, wa, c1); c1 = MFMA16(x11, wb, c1);
        __builtin_amdgcn_s_setprio(0);
        if (p16 < 3) {
            #pragma unroll
            for (int rr = 0; rr < 4; ++rr) {
                O0[(g*4+rr)*4 + p16] = 1.f / (1.f + __expf(-c0[rr]));
                O1[(g*4+rr)*4 + p16] = 1.f / (1.f + __expf(-c1[rr]));
            }
        }
    }

    // ---- scatter out ----
    if (wbase + p16 < N) {
        const unsigned orig = __float_as_uint(d0.w);
        out[(size_t)orig * 4 + g] = O0[p16 * 4 + g];
    }
    if (wbase + 16 + p16 < N) {
        const unsigned orig = __float_as_uint(d1.w);
        out[(size_t)orig * 4 + g] = O1[p16 * 4 + g];
    }
}

// ---------------- fused fallback (small ws, f32 table) ----------------
template<int NIN, int NOUT, bool RELU>
__device__ __forceinline__ void dense_l(const float* __restrict__ W, const float* __restrict__ Bias,
                                        const float* __restrict__ col, float (&out)[NOUT])
{
    #pragma unroll
    for (int j = 0; j < NOUT; ++j) out[j] = Bias[j];
    #pragma unroll 4
    for (int i = 0; i < NIN; ++i) {
        const float a = col[i * BLK];
        const float* Wr = W + i * NOUT;
        #pragma unroll
        for (int j = 0; j < NOUT; ++j) out[j] = fmaf(a, Wr[j], out[j]);
    }
    if (RELU) {
        #pragma unroll
        for (int j = 0; j < NOUT; ++j) out[j] = fmaxf(out[j], 0.f);
    }
}

__device__ __forceinline__ void encode_point_f(float x, float y, float z,
                                               const float* __restrict__ tableF,
                                               float (&emb)[32])
{
    constexpr int RES[16] = {32,38,46,55,67,80,97,116,140,168,203,244,294,353,425,512};
    constexpr int DN [16] = {1,1,1,1,1,1,1,1,1,1,1,1,0,0,0,0};
    constexpr int OFF[16] = {0,35937,95256,199079,374695,689127,1220568,2161760,
                             3763373,6566594,11393403,19883067,34589192,35113480,
                             35637768,36162056};
    constexpr unsigned NMASK = (1u << 19) - 1u;
    #pragma unroll
    for (int l = 0; l < 16; ++l) {
        const int res = RES[l];
        const float xl = x * (float)res, yl = y * (float)res, zl = z * (float)res;
        int cx = (int)floorf(xl); cx = cx < 0 ? 0 : (cx > res-1 ? res-1 : cx);
        int cy = (int)floorf(yl); cy = cy < 0 ? 0 : (cy > res-1 ? res-1 : cy);
        int cz = (int)floorf(zl); cz = cz < 0 ? 0 : (cz > res-1 ? res-1 : cz);
        const float wx = xl - (float)cx, wy = yl - (float)cy, wz = zl - (float)cz;
        float e0 = 0.f, e1 = 0.f;
        #pragma unroll
        for (int c = 0; c < 8; ++c) {
            const int dx = (c >> 2) & 1, dy = (c >> 1) & 1, dz = c & 1;
            int idx;
            if (DN[l]) {
                idx = (cx+dx) + (cy+dy)*(res+1) + (cz+dz)*(res+1)*(res+1);
            } else {
                const unsigned hh = (unsigned)(cx+dx) ^ ((unsigned)(cy+dy)*2654435761u)
                                  ^ ((unsigned)(cz+dz)*805459861u);
                idx = (int)(hh & NMASK);
            }
            const float w = (dx ? wx : 1.f-wx)*(dy ? wy : 1.f-wy)*(dz ? wz : 1.f-wz);
            const float2 v = *reinterpret_cast<const float2*>(tableF + (size_t)2*(size_t)(OFF[l]+idx));
            e0 = fmaf(v.x, w, e0); e1 = fmaf(v.y, w, e1);
        }
        emb[2*l+0] = e0; emb[2*l+1] = e1;
    }
}

__device__ __forceinline__ float4 mlp_lds(float* col, float dx0, float dy0, float dz0,
    const float* __restrict__ fw1, const float* __restrict__ fb1,
    const float* __restrict__ fw2, const float* __restrict__ fb2,
    const float* __restrict__ fw3, const float* __restrict__ fb3,
    const float* __restrict__ rw1, const float* __restrict__ rb1,
    const float* __restrict__ rw2, const float* __restrict__ rb2,
    const float* __restrict__ rw3, const float* __restrict__ rb3,
    const float* __restrict__ rw4, const float* __restrict__ rb4)
{
    float h[64];
    dense_l<32, 64, true>(fw1, fb1, col, h);
    #pragma unroll
    for (int j = 0; j < 64; ++j) col[j * BLK] = h[j];
    dense_l<64, 64, true>(fw2, fb2, col, h);
    #pragma unroll
    for (int j = 0; j < 64; ++j) col[j * BLK] = h[j];
    float feat16[16];
    dense_l<64, 16, false>(fw3, fb3, col, feat16);
    const float sigma = expf(feat16[0]);
    #pragma unroll
    for (int j = 0; j < 16; ++j) col[j * BLK] = feat16[j];
    col[16 * BLK] = dx0; col[17 * BLK] = dy0; col[18 * BLK] = dz0;
    {
        float s, c;
        sincosf(dx0,     &s, &c); col[19 * BLK] = s; col[25 * BLK] = c;
        sincosf(2.f*dx0, &s, &c); col[20 * BLK] = s; col[26 * BLK] = c;
        sincosf(dy0,     &s, &c); col[21 * BLK] = s; col[27 * BLK] = c;
        sincosf(2.f*dy0, &s, &c); col[22 * BLK] = s; col[28 * BLK] = c;
        sincosf(dz0,     &s, &c); col[23 * BLK] = s; col[29 * BLK] = c;
        sincosf(2.f*dz0, &s, &c); col[24 * BLK] = s; col[30 * BLK] = c;
    }
    dense_l<31, 64, true>(rw1, rb1, col, h);
    #pragma unroll
    for (int j = 0; j < 64; ++j) col[j * BLK] = h[j];
    dense_l<64, 64, true>(rw2, rb2, col, h);
    #pragma unroll
    for (int j = 0; j < 64; ++j) col[j * BLK] = h[j];
    dense_l<64, 64, true>(rw3, rb3, col, h);
    #pragma unroll
    for (int j = 0; j < 64; ++j) col[j * BLK] = h[j];
    float o0 = rb4[0], o1 = rb4[1], o2 = rb4[2];
    #pragma unroll 4
    for (int i = 0; i < 64; ++i) {
        const float a = col[i * BLK];
        o0 = fmaf(a, rw4[i*3 + 0], o0);
        o1 = fmaf(a, rw4[i*3 + 1], o1);
        o2 = fmaf(a, rw4[i*3 + 2], o2);
    }
    o0 = 1.f / (1.f + expf(-o0));
    o1 = 1.f / (1.f + expf(-o1));
    o2 = 1.f / (1.f + expf(-o2));
    return make_float4(o0, o1, o2, sigma);
}

__global__ __launch_bounds__(BLK) void ngp_fused_f32(
    const float* __restrict__ coords,
    const float* __restrict__ dirs,
    const float* __restrict__ tableF,
    const float* __restrict__ fw1, const float* __restrict__ fb1,
    const float* __restrict__ fw2, const float* __restrict__ fb2,
    const float* __restrict__ fw3, const float* __restrict__ fb3,
    const float* __restrict__ rw1, const float* __restrict__ rb1,
    const float* __restrict__ rw2, const float* __restrict__ rb2,
    const float* __restrict__ rw3, const float* __restrict__ rb3,
    const float* __restrict__ rw4, const float* __restrict__ rb4,
    float* __restrict__ out, int N)
{
    __shared__ float sbuf[64 * BLK];
    const int tid = threadIdx.x;
    const int gi  = blockIdx.x * BLK + tid;
    if (gi >= N) return;

    float emb[32];
    encode_point_f(coords[3*gi+0], coords[3*gi+1], coords[3*gi+2], tableF, emb);
    float* col = sbuf + tid;
    #pragma unroll
    for (int j = 0; j < 32; ++j) col[j * BLK] = emb[j];

    const float4 ov = mlp_lds(col, dirs[3*gi+0], dirs[3*gi+1], dirs[3*gi+2],
                              fw1, fb1, fw2, fb2, fw3, fb3,
                              rw1, rb1, rw2, rb2, rw3, rb3, rw4, rb4);
    reinterpret_cast<float4*>(out)[gi] = ov;
}

extern "C" void kernel_launch(void* const* d_in, const int* in_sizes, int n_in,
                              void* d_out, int out_size, void* d_ws, size_t ws_size,
                              hipStream_t stream)
{
    const float* coords = (const float*)d_in[0];
    const float* dirs   = (const float*)d_in[1];
    const float* table  = (const float*)d_in[2];
    const float* fw1 = (const float*)d_in[3];
    const float* fb1 = (const float*)d_in[4];
    const float* fw2 = (const float*)d_in[5];
    const float* fb2 = (const float*)d_in[6];
    const float* fw3 = (const float*)d_in[7];
    const float* fb3 = (const float*)d_in[8];
    const float* rw1 = (const float*)d_in[9];
    const float* rb1 = (const float*)d_in[10];
    const float* rw2 = (const float*)d_in[11];
    const float* rb2 = (const float*)d_in[12];
    const float* rw3 = (const float*)d_in[13];
    const float* rb3 = (const float*)d_in[14];
    const float* rw4 = (const float*)d_in[15];
    const float* rb4 = (const float*)d_in[16];

    const int N = in_sizes[0] / 3;

    // ws layout
    size_t pos = 0;
    auto take = [&](size_t bytes) { size_t p = pos; pos = (pos + bytes + 255) & ~(size_t)255; return p; };
    const size_t o_pd     = take((size_t)PD_ENTRIES * 4);
    const size_t o_mt     = take((size_t)MTOT * 2);
    const size_t o_ph     = take((size_t)PH_ENTRIES * 4);
    const size_t o_emb    = take((size_t)N * 64);
    const size_t o_cS     = take((size_t)N * 16);
    const size_t o_dS     = take((size_t)N * 16);
    const size_t o_hist   = take((size_t)NBINS * 4);
    const size_t o_cursor = take((size_t)NBINS * 4);
    const size_t o_bsum   = take(256 * 4);
    const size_t o_frag   = take((size_t)FRAG_TOTAL * 2);
    const size_t need_full = pos;

    char* ws = (char*)d_ws;

    if (ws_size >= need_full) {
        unsigned*       PD     = (unsigned*)(ws + o_pd);
        unsigned short* MT     = (unsigned short*)(ws + o_mt);
        unsigned*       PH     = (unsigned*)(ws + o_ph);
        uint4*     embws  = (uint4*)(ws + o_emb);
        float4*    cS     = (float4*)(ws + o_cS);
        float4*    dS     = (float4*)(ws + o_dS);
        unsigned*  hist   = (unsigned*)(ws + o_hist);
        unsigned*  cursor = (unsigned*)(ws + o_cursor);
        unsigned*  bsum   = (unsigned*)(ws + o_bsum);
        _Float16*  frag   = (_Float16*)(ws + o_frag);

        hipLaunchKernelGGL(cvt_pd, dim3((PD_ENTRIES + 255) / 256), dim3(256), 0, stream,
                           table, PD);
        hipLaunchKernelGGL(cvt_ph, dim3(PH_ENTRIES / 256), dim3(256), 0, stream,
                           table, PH);
        hipLaunchKernelGGL(cvt_mt, dim3(MTOT / 256), dim3(256), 0, stream,
                           table, MT);
        hipLaunchKernelGGL(prep_frags, dim3(FRAG_TOTAL / 256), dim3(256), 0, stream,
                           fw1, fw2, fw3, rw1, rw2, rw3, rw4, frag);
        hipMemsetAsync(hist, 0, (size_t)NBINS * 4, stream);
        hipLaunchKernelGGL(hist_build, dim3((N + 255) / 256), dim3(256), 0, stream,
                           coords, hist, N);
        hipLaunchKernelGGL(scan1, dim3(NBINS / 1024), dim3(256), 0, stream, hist, bsum);
        hipLaunchKernelGGL(scan2, dim3(1), dim3(256), 0, stream, bsum);
        hipLaunchKernelGGL(scan3, dim3(NBINS / 256), dim3(256), 0, stream, hist, bsum, cursor);
        hipLaunchKernelGGL(scatter_pts, dim3((N + 255) / 256), dim3(256), 0, stream,
                           coords, dirs, cursor, cS, dS, N);
        hipLaunchKernelGGL(ngp_encode, dim3((N + EBLK - 1) / EBLK), dim3(EBLK), 0, stream,
                           cS, PD, MT, PH, embws, N);
        hipLaunchKernelGGL(ngp_mlp_mfma, dim3((N + 127) / 128), dim3(256), 0, stream,
                           (const _Float16*)embws, dS, frag,
                           fb1, fb2, fb3, rb1, rb2, rb3, rb4,
                           (float*)d_out, N);
    } else {
        hipLaunchKernelGGL(ngp_fused_f32, dim3((N + BLK - 1) / BLK), dim3(BLK), 0, stream,
                           coords, dirs, table,
                           fw1, fb1, fw2, fb2, fw3, fb3,
                           rw1, rb1, rw2, rb2, rw3, rb3, rw4, rb4,
                           (float*)d_out, N);
    }
}

// Round 11
// 1181.166 us; speedup vs baseline: 2.3964x; 1.3524x over previous
//
#include <hip/hip_runtime.h>
#include <hip/hip_fp16.h>
#include <math.h>

#define BLK 128          // fused-fallback block
#define EBLK 256         // encode / utility block
#define NBINS (1 << 18)  // 6 bits per axis, Morton sort bins
#define Q_SCALE 65536.0f
#define Q_DESCALE 0x1p-16f

typedef __attribute__((ext_vector_type(8))) _Float16 half8;
typedef __attribute__((ext_vector_type(4))) float f32x4;
typedef __attribute__((ext_vector_type(2))) float f32x2;

// frag offsets in f16 elements: L1,L2,L3,R1,R2,R3,R4
#define FO_L1 0
#define FO_L2 2048
#define FO_L3 6144
#define FO_R1 7168
#define FO_R2 9216
#define FO_R3 13312
#define FO_R4 17408
#define FRAG_TOTAL 18432

// ---- table shapes ----
#define PD_ENTRIES 3763373           // dense levels 0-7, u32 x-pair each
#define MTOT 47710208                // morton levels 8-11, u16 each
#define PH_ENTRIES (4 * 524288)      // hashed levels 12-15, u32 pair each

// ---------------- Morton helpers ----------------
__device__ __forceinline__ unsigned mexp(unsigned v) {
    v &= 0x3FF;
    v = (v | (v << 16)) & 0x030000FF;
    v = (v | (v << 8))  & 0x0300F00F;
    v = (v | (v << 4))  & 0x030C30C3;
    v = (v | (v << 2))  & 0x09249249;
    return v;
}
__device__ __forceinline__ unsigned mcomp(unsigned v) {
    v &= 0x09249249u;
    v = (v | (v >> 2)) & 0x030C30C3u;
    v = (v | (v >> 4)) & 0x0300F00Fu;
    v = (v | (v >> 8)) & 0x030000FFu;
    v = (v | (v >> 16)) & 0x3FFu;
    return v;
}
__device__ __forceinline__ unsigned morton_key(float x, float y, float z) {
    int bx = (int)(x * 64.f); bx = bx < 0 ? 0 : (bx > 63 ? 63 : bx);
    int by = (int)(y * 64.f); by = by < 0 ? 0 : (by > 63 ? 63 : by);
    int bz = (int)(z * 64.f); bz = bz < 0 ? 0 : (bz > 63 ? 63 : bz);
    return (mexp((unsigned)bx) << 2) | (mexp((unsigned)by) << 1) | mexp((unsigned)bz);
}

// ---------------- table conversion kernels ----------------
__device__ __forceinline__ unsigned pk_fp8(float a, float b) {
    const int lo = __builtin_amdgcn_cvt_pk_fp8_f32(a * Q_SCALE, b * Q_SCALE, 0, false);
    return (unsigned)lo & 0xFFFFu;
}

// dense levels 0-7: u32[e] = (q[e], q[e+1])  (x-pair; e+1 overflow value unused)
__global__ __launch_bounds__(256) void cvt_pd(const float* __restrict__ srcF,
                                              unsigned* __restrict__ pd)
{
    const int e = blockIdx.x * 256 + threadIdx.x;
    if (e >= PD_ENTRIES) return;
    const float2 a = *reinterpret_cast<const float2*>(srcF + 2 * (size_t)e);
    const float2 b = *reinterpret_cast<const float2*>(srcF + 2 * ((size_t)e + 1));
    pd[e] = pk_fp8(a.x, a.y) | (pk_fp8(b.x, b.y) << 16);
}

// hashed levels 12-15: u32[(j<<19)+h] = (q[h], q[h^1])
__global__ __launch_bounds__(256) void cvt_ph(const float* __restrict__ srcF,
                                              unsigned* __restrict__ ph)
{
    const int i = blockIdx.x * 256 + threadIdx.x;
    if (i >= PH_ENTRIES) return;
    constexpr unsigned SOFF[4] = {34589192u, 35113480u, 35637768u, 36162056u};
    const int j = i >> 19;
    const unsigned h = (unsigned)i & 524287u;
    const size_t s0 = (size_t)SOFF[j] + h;
    const size_t s1 = (size_t)SOFF[j] + (h ^ 1u);
    const float2 a = *reinterpret_cast<const float2*>(srcF + 2 * s0);
    const float2 b = *reinterpret_cast<const float2*>(srcF + 2 * s1);
    ph[i] = pk_fp8(a.x, a.y) | (pk_fp8(b.x, b.y) << 16);
}

// Morton-block levels 8-11
__global__ __launch_bounds__(256) void cvt_mt(const float* __restrict__ srcF,
                                              unsigned short* __restrict__ mt)
{
    const unsigned e = blockIdx.x * 256 + threadIdx.x;
    if (e >= MTOT) return;
    int j, cnt; unsigned base;
    if (e < 14155776u) {
        cnt = 3;
        if (e < 7077888u) { j = 0; base = 0u; }
        else              { j = 1; base = 7077888u; }
    } else {
        cnt = 4;
        if (e < 30932992u){ j = 2; base = 14155776u; }
        else              { j = 3; base = 30932992u; }
    }
    const unsigned within = e - base;
    const unsigned blk = within >> 18, lo = within & 0x3FFFFu;
    unsigned bx, by, bz;
    if (cnt == 3) { bx = blk % 3u; const unsigned t = blk / 3u; by = t % 3u; bz = t / 3u; }
    else          { bx = blk & 3u; by = (blk >> 2) & 3u; bz = blk >> 4; }
    const unsigned x = bx * 64u + mcomp(lo);
    const unsigned y = by * 64u + mcomp(lo >> 1);
    const unsigned z = bz * 64u + mcomp(lo >> 2);

    constexpr unsigned RES1[4] = {141u, 169u, 204u, 245u};
    constexpr unsigned SOFF[4] = {3763373u, 6566594u, 11393403u, 19883067u};
    const unsigned r1 = RES1[j];
    unsigned q = 0;
    if (x < r1 && y < r1 && z < r1) {
        const size_t se = (size_t)SOFF[j] + x + (size_t)y * r1 + (size_t)z * r1 * r1;
        const float2 v = *reinterpret_cast<const float2*>(srcF + 2 * se);
        q = pk_fp8(v.x, v.y);
    }
    mt[e] = (unsigned short)q;
}

// ---------------- weight fragment packing ----------------
__global__ __launch_bounds__(256) void prep_frags(
    const float* __restrict__ fw1, const float* __restrict__ fw2, const float* __restrict__ fw3,
    const float* __restrict__ rw1, const float* __restrict__ rw2, const float* __restrict__ rw3,
    const float* __restrict__ rw4, _Float16* __restrict__ frag)
{
    const int gid = blockIdx.x * 256 + threadIdx.x;
    if (gid >= FRAG_TOTAL) return;
    constexpr int offs[8] = {FO_L1, FO_L2, FO_L3, FO_R1, FO_R2, FO_R3, FO_R4, FRAG_TOTAL};
    constexpr int Ks[7]   = {32, 64, 64, 31, 64, 64, 64};
    constexpr int NO[7]   = {64, 64, 16, 64, 64, 64, 3};
    constexpr int NKs[7]  = {1, 2, 2, 1, 2, 2, 2};
    int layer = 0;
    #pragma unroll
    for (int i = 1; i < 7; ++i) if (gid >= offs[i]) layer = i;
    const float* W = fw1;
    if (layer == 1) W = fw2; else if (layer == 2) W = fw3;
    else if (layer == 3) W = rw1; else if (layer == 4) W = rw2;
    else if (layer == 5) W = rw3; else if (layer == 6) W = rw4;

    const int e = gid - offs[layer];
    const int nk = NKs[layer];
    const int blk = e >> 9, within = e & 511;
    const int t = blk / nk, ks = blk - t * nk;
    const int lane = within >> 3, i = within & 7;
    const int k = ks * 32 + (lane >> 4) * 8 + i;
    // 64-wide layers: col c of tile t holds output feature 4*c + t (paired-store remap)
    const int col = (NO[layer] == 64) ? ((lane & 15) * 4 + t) : (t * 16 + (lane & 15));
    float v = 0.f;
    if (k < Ks[layer] && col < NO[layer]) v = W[k * NO[layer] + col];
    frag[gid] = (_Float16)v;
}

// ---------------- sort: histogram ----------------
__global__ __launch_bounds__(256) void hist_build(const float* __restrict__ coords,
                                                  unsigned* __restrict__ hist, int N)
{
    const int i = blockIdx.x * 256 + threadIdx.x;
    if (i >= N) return;
    const unsigned key = morton_key(coords[3*i+0], coords[3*i+1], coords[3*i+2]);
    atomicAdd(&hist[key], 1u);
}

// ---------------- sort: hierarchical exclusive scan ----------------
__global__ __launch_bounds__(256) void scan1(unsigned* __restrict__ hist, unsigned* __restrict__ bsum)
{
    __shared__ unsigned sa[256], sb[256];
    const int t = threadIdx.x;
    const unsigned base = blockIdx.x * 1024u + (unsigned)t * 4u;
    const unsigned v0 = hist[base+0], v1 = hist[base+1], v2 = hist[base+2], v3 = hist[base+3];
    const unsigned sum = v0 + v1 + v2 + v3;
    sa[t] = sum; __syncthreads();
    unsigned* src = sa; unsigned* dst = sb;
    for (int off = 1; off < 256; off <<= 1) {
        dst[t] = src[t] + (t >= off ? src[t - off] : 0u);
        __syncthreads();
        unsigned* tmp = src; src = dst; dst = tmp;
    }
    const unsigned incl = src[t];
    unsigned run = incl - sum;
    hist[base+0] = run; run += v0;
    hist[base+1] = run; run += v1;
    hist[base+2] = run; run += v2;
    hist[base+3] = run;
    if (t == 255) bsum[blockIdx.x] = incl;
}

__global__ __launch_bounds__(256) void scan2(unsigned* __restrict__ bsum)
{
    __shared__ unsigned sa[256], sb[256];
    const int t = threadIdx.x;
    const unsigned v = bsum[t];
    sa[t] = v; __syncthreads();
    unsigned* src = sa; unsigned* dst = sb;
    for (int off = 1; off < 256; off <<= 1) {
        dst[t] = src[t] + (t >= off ? src[t - off] : 0u);
        __syncthreads();
        unsigned* tmp = src; src = dst; dst = tmp;
    }
    bsum[t] = src[t] - v;
}

__global__ __launch_bounds__(256) void scan3(const unsigned* __restrict__ hist,
                                             const unsigned* __restrict__ bsum,
                                             unsigned* __restrict__ cursor)
{
    const int i = blockIdx.x * 256 + threadIdx.x;
    cursor[i] = hist[i] + bsum[i >> 10];
}

// ---------------- sort: scatter points into bins ----------------
__global__ __launch_bounds__(256) void scatter_pts(const float* __restrict__ coords,
                                                   const float* __restrict__ dirs,
                                                   unsigned* __restrict__ cursor,
                                                   float4* __restrict__ cS,
                                                   float4* __restrict__ dS, int N)
{
    const int i = blockIdx.x * 256 + threadIdx.x;
    if (i >= N) return;
    const float x = coords[3*i+0], y = coords[3*i+1], z = coords[3*i+2];
    const unsigned key = morton_key(x, y, z);
    const unsigned slot = atomicAdd(&cursor[key], 1u);
    cS[slot] = make_float4(x, y, z, __uint_as_float((unsigned)i));
    dS[slot] = make_float4(dirs[3*i+0], dirs[3*i+1], dirs[3*i+2], __uint_as_float((unsigned)i));
}

// ---------------- encode kernel (pair tables; relaxed VGPR bound) ----------------
__global__ __launch_bounds__(EBLK, 4) void ngp_encode(
    const float4* __restrict__ cS,
    const unsigned* __restrict__ PD,
    const unsigned short* __restrict__ MT,
    const unsigned* __restrict__ PH,
    uint4* __restrict__ emb_out, int N)
{
    // bijective XCD-contiguous remap of blockIdx (8 XCDs)
    const unsigned nwg = gridDim.x;
    const unsigned bid = blockIdx.x;
    const unsigned qn = nwg >> 3, rn = nwg & 7;
    const unsigned xc = bid & 7, ib = bid >> 3;
    const unsigned nb = (xc < rn ? xc * (qn + 1) : rn * (qn + 1) + (xc - rn) * qn) + ib;

    const int gi = (int)(nb * EBLK + threadIdx.x);
    if (gi >= N) return;

    const float4 cp = cS[gi];
    const float x = cp.x, y = cp.y, z = cp.z;

    float emb[32];

    // ---- dense levels 0-7: one u32 pair-load per (dy,dz) corner-row ----
    {
        constexpr int RES[8] = {32,38,46,55,67,80,97,116};
        constexpr int OFF[8] = {0,35937,95256,199079,374695,689127,1220568,2161760};
        #pragma unroll
        for (int lv = 0; lv < 8; ++lv) {
            const int res = RES[lv];
            const float xl = x * (float)res, yl = y * (float)res, zl = z * (float)res;
            int cx = (int)floorf(xl); cx = cx < 0 ? 0 : (cx > res-1 ? res-1 : cx);
            int cy = (int)floorf(yl); cy = cy < 0 ? 0 : (cy > res-1 ? res-1 : cy);
            int cz = (int)floorf(zl); cz = cz < 0 ? 0 : (cz > res-1 ? res-1 : cz);
            const float wx = xl - (float)cx, wy = yl - (float)cy, wz = zl - (float)cz;
            const int res1 = res + 1;
            unsigned qv[8];
            #pragma unroll
            for (int p = 0; p < 4; ++p) {           // p = (dy<<1)|dz
                const int dy = (p >> 1) & 1, dz = p & 1;
                const unsigned w = PD[OFF[lv] + cx + (cy+dy)*res1 + (cz+dz)*res1*res1];
                qv[p] = w & 0xFFFFu; qv[p + 4] = w >> 16;
            }
            float e0 = 0.f, e1 = 0.f;
            #pragma unroll
            for (int c = 0; c < 8; ++c) {
                const int dx = (c >> 2) & 1, dy = (c >> 1) & 1, dz = c & 1;
                const float w = (dx ? wx : 1.f-wx)*(dy ? wy : 1.f-wy)*(dz ? wz : 1.f-wz);
                const f32x2 vf = __builtin_amdgcn_cvt_pk_f32_fp8((int)qv[c], false);
                e0 = fmaf(vf.x, w, e0); e1 = fmaf(vf.y, w, e1);
            }
            emb[2*lv+0] = e0 * Q_DESCALE; emb[2*lv+1] = e1 * Q_DESCALE;
        }
    }

    // ---- Morton-block dense levels 8-11 ----
    {
        constexpr int RESM[4] = {140,168,203,244};
        constexpr int CNTM[4] = {3,3,4,4};
        constexpr unsigned MOFF[4] = {0u, 7077888u, 14155776u, 30932992u};
        #pragma unroll
        for (int j = 0; j < 4; ++j) {
            const int res = RESM[j];
            const int cnt = CNTM[j];
            const float xl = x * (float)res, yl = y * (float)res, zl = z * (float)res;
            int cx = (int)floorf(xl); cx = cx < 0 ? 0 : (cx > res-1 ? res-1 : cx);
            int cy = (int)floorf(yl); cy = cy < 0 ? 0 : (cy > res-1 ? res-1 : cy);
            int cz = (int)floorf(zl); cz = cz < 0 ? 0 : (cz > res-1 ? res-1 : cz);
            const float wx = xl - (float)cx, wy = yl - (float)cy, wz = zl - (float)cz;

            const int bx0 = cx >> 6, bx1 = (cx+1) >> 6;
            const int by0 = cy >> 6, by1 = (cy+1) >> 6;
            const int bz0 = cz >> 6, bz1 = (cz+1) >> 6;
            const unsigned mx0 = mexp(cx & 63),      mx1 = mexp((cx+1) & 63);
            const unsigned my0 = mexp(cy & 63) << 1, my1 = mexp((cy+1) & 63) << 1;
            const unsigned mz0 = mexp(cz & 63) << 2, mz1 = mexp((cz+1) & 63) << 2;

            unsigned qv[8];
            #pragma unroll
            for (int c = 0; c < 8; ++c) {
                const int dx = (c >> 2) & 1, dy = (c >> 1) & 1, dz = c & 1;
                const int bx = dx ? bx1 : bx0, by = dy ? by1 : by0, bz = dz ? bz1 : bz0;
                const unsigned mm = (dx ? mx1 : mx0) | (dy ? my1 : my0) | (dz ? mz1 : mz0);
                const unsigned blk = (unsigned)((bz * cnt + by) * cnt + bx);
                qv[c] = MT[(size_t)MOFF[j] + ((blk << 18) | mm)];
            }
            float e0 = 0.f, e1 = 0.f;
            #pragma unroll
            for (int c = 0; c < 8; ++c) {
                const int dx = (c >> 2) & 1, dy = (c >> 1) & 1, dz = c & 1;
                const float w = (dx ? wx : 1.f-wx)*(dy ? wy : 1.f-wy)*(dz ? wz : 1.f-wz);
                const f32x2 vf = __builtin_amdgcn_cvt_pk_f32_fp8((int)qv[c], false);
                e0 = fmaf(vf.x, w, e0); e1 = fmaf(vf.y, w, e1);
            }
            emb[16+2*j+0] = e0 * Q_DESCALE; emb[16+2*j+1] = e1 * Q_DESCALE;
        }
    }

    // ---- hashed levels 12-15: pair u32, extra load only for odd cx ----
    {
        constexpr int RESH[4] = {294,353,425,512};
        constexpr unsigned NMASK = (1u << 19) - 1u;
        #pragma unroll
        for (int j = 0; j < 4; ++j) {
            const int res = RESH[j];
            const float xl = x * (float)res, yl = y * (float)res, zl = z * (float)res;
            int cx = (int)floorf(xl); cx = cx < 0 ? 0 : (cx > res-1 ? res-1 : cx);
            int cy = (int)floorf(yl); cy = cy < 0 ? 0 : (cy > res-1 ? res-1 : cy);
            int cz = (int)floorf(zl); cz = cz < 0 ? 0 : (cz > res-1 ? res-1 : cz);
            const float wx = xl - (float)cx, wy = yl - (float)cy, wz = zl - (float)cz;
            const unsigned lvbase = (unsigned)j << 19;
            const bool xodd = (cx & 1) != 0;
            unsigned qv[8];
            #pragma unroll
            for (int p = 0; p < 4; ++p) {
                const int dy = (p >> 1) & 1, dz = p & 1;
                const unsigned hyz = ((unsigned)(cy+dy) * 2654435761u)
                                   ^ ((unsigned)(cz+dz) * 805459861u);
                const unsigned h0 = ((unsigned)cx ^ hyz) & NMASK;
                const unsigned w0 = PH[lvbase + h0];
                unsigned q0 = w0 & 0xFFFFu;
                unsigned q1 = w0 >> 16;                 // = q[h0^1] (valid when cx even)
                if (xodd) {
                    const unsigned h1 = (((unsigned)cx + 1u) ^ hyz) & NMASK;
                    q1 = PH[lvbase + h1] & 0xFFFFu;
                }
                qv[p] = q0; qv[p + 4] = q1;
            }
            float e0 = 0.f, e1 = 0.f;
            #pragma unroll
            for (int c = 0; c < 8; ++c) {
                const int dx = (c >> 2) & 1, dy = (c >> 1) & 1, dz = c & 1;
                const float w = (dx ? wx : 1.f-wx)*(dy ? wy : 1.f-wy)*(dz ? wz : 1.f-wz);
                const f32x2 vf = __builtin_amdgcn_cvt_pk_f32_fp8((int)qv[c], false);
                e0 = fmaf(vf.x, w, e0); e1 = fmaf(vf.y, w, e1);
            }
            emb[24+2*j+0] = e0 * Q_DESCALE; emb[24+2*j+1] = e1 * Q_DESCALE;
        }
    }

    unsigned packed[16];
    #pragma unroll
    for (int i = 0; i < 16; ++i) {
        const __half2 h = __floats2half2_rn(emb[2*i+0], emb[2*i+1]);
        packed[i] = *reinterpret_cast<const unsigned*>(&h);
    }
    uint4* dst = emb_out + (size_t)gi * 4;
    #pragma unroll
    for (int k = 0; k < 4; ++k)
        dst[k] = make_uint4(packed[4*k+0], packed[4*k+1], packed[4*k+2], packed[4*k+3]);
}

// ================= MFMA MLP (verbatim R7) =================
__device__ __forceinline__ half8 ldfrag(const _Float16* __restrict__ frags, int off, int l) {
    return *reinterpret_cast<const half8*>(frags + off + l * 8);
}
__device__ __forceinline__ int swz(int f, int p) {
    return ((((f >> 3) + p) & 7) << 3) | (f & 7);
}
__device__ __forceinline__ half8 loadA(const _Float16* T, int p, int kb) {
    return *reinterpret_cast<const half8*>(T + p * 64 + ((((kb >> 3) + p) & 7) << 3));
}
// paired store: acc[t][r] holds output feature 4*p16+t for point g*4+r
template<bool RELU>
__device__ __forceinline__ void storePair(_Float16* T, const f32x4 (&acc)[4], int p16, int g) {
    #pragma unroll
    for (int r = 0; r < 4; ++r) {
        const int p = g * 4 + r;
        float v0 = acc[0][r], v1 = acc[1][r], v2 = acc[2][r], v3 = acc[3][r];
        if (RELU) { v0 = fmaxf(v0,0.f); v1 = fmaxf(v1,0.f); v2 = fmaxf(v2,0.f); v3 = fmaxf(v3,0.f); }
        const __half2 h01 = __floats2half2_rn(v0, v1);
        const __half2 h23 = __floats2half2_rn(v2, v3);
        const int blkb = ((p16 >> 1) + p) & 7;
        uint2* dst = reinterpret_cast<uint2*>(T + p * 64 + blkb * 8 + 4 * (p16 & 1));
        *dst = make_uint2(*reinterpret_cast<const unsigned*>(&h01),
                          *reinterpret_cast<const unsigned*>(&h23));
    }
}
__device__ __forceinline__ void pe_fill(_Float16* T, int p16, int g, float dx, float dy, float dz) {
    float pv0, pv1, pv2, pv3;
    if (g == 0)      { pv0 = dx;             pv1 = dy;         pv2 = dz;             pv3 = __sinf(dx); }
    else if (g == 1) { pv0 = __sinf(2.f*dx); pv1 = __sinf(dy); pv2 = __sinf(2.f*dy); pv3 = __sinf(dz); }
    else if (g == 2) { pv0 = __sinf(2.f*dz); pv1 = __cosf(dx); pv2 = __cosf(2.f*dx); pv3 = __cosf(dy); }
    else             { pv0 = __cosf(2.f*dy); pv1 = __cosf(dz); pv2 = __cosf(2.f*dz); pv3 = 0.f; }
    const float pv[4] = {pv0, pv1, pv2, pv3};
    #pragma unroll
    for (int j2 = 0; j2 < 4; ++j2) {
        const int f = 16 + g * 4 + j2;
        T[p16 * 64 + swz(f, p16)] = (_Float16)pv[j2];
    }
}
#define MFMA16(a, b, c) __builtin_amdgcn_mfma_f32_16x16x32_f16((a), (b), (c), 0, 0, 0)

__global__ __launch_bounds__(256) void ngp_mlp_mfma(
    const _Float16* __restrict__ embws,      // [N][32] f16
    const float4* __restrict__ dS,
    const _Float16* __restrict__ frags,
    const float* __restrict__ fb1, const float* __restrict__ fb2, const float* __restrict__ fb3,
    const float* __restrict__ rb1, const float* __restrict__ rb2, const float* __restrict__ rb3,
    const float* __restrict__ rb4,
    float* __restrict__ out, int N)
{
    __shared__ _Float16 tbuf[4][2][16 * 64];
    __shared__ float obuf[4][2][64];
    const int tid = threadIdx.x;
    const int wv = tid >> 6, l = tid & 63;
    const int p16 = l & 15, g = l >> 4;
    const int wbase = (blockIdx.x * 4 + wv) * 32;
    _Float16* T0 = tbuf[wv][0];
    _Float16* T1 = tbuf[wv][1];
    float* O0 = obuf[wv][0];
    float* O1 = obuf[wv][1];

    int pi0 = wbase + p16;      if (pi0 >= N) pi0 = N - 1;
    int pi1 = wbase + 16 + p16; if (pi1 >= N) pi1 = N - 1;
    const float4 d0 = dS[pi0];
    const float4 d1 = dS[pi1];

    f32x4 ac0[4], ac1[4];
    half8 x00, x01, x10, x11;

    // ---- L1 (K=32): A straight from packed emb ----
    {
        const half8 a0 = *reinterpret_cast<const half8*>(embws + (size_t)pi0 * 32 + g * 8);
        const half8 a1 = *reinterpret_cast<const half8*>(embws + (size_t)pi1 * 32 + g * 8);
        __builtin_amdgcn_s_setprio(1);
        #pragma unroll
        for (int t = 0; t < 4; ++t) {
            const float b = fb1[(p16 << 2) + t];
            const half8 w = ldfrag(frags, FO_L1 + t * 512, l);
            f32x4 c = {b, b, b, b};
            ac0[t] = MFMA16(a0, w, c);
            ac1[t] = MFMA16(a1, w, c);
        }
        __builtin_amdgcn_s_setprio(0);
    }
    storePair<true>(T0, ac0, p16, g);
    storePair<true>(T1, ac1, p16, g);
    x00 = loadA(T0, p16, g*8); x01 = loadA(T0, p16, 32 + g*8);
    x10 = loadA(T1, p16, g*8); x11 = loadA(T1, p16, 32 + g*8);

    // ---- L2 (K=64) ----
    __builtin_amdgcn_s_setprio(1);
    #pragma unroll
    for (int t = 0; t < 4; ++t) {
        const float b = fb2[(p16 << 2) + t];
        const half8 w0 = ldfrag(frags, FO_L2 + (2*t+0) * 512, l);
        const half8 w1 = ldfrag(frags, FO_L2 + (2*t+1) * 512, l);
        f32x4 c0 = {b, b, b, b}, c1 = {b, b, b, b};
        c0 = MFMA16(x00, w0, c0); ac0[t] = MFMA16(x01, w1, c0);
        c1 = MFMA16(x10, w0, c1); ac1[t] = MFMA16(x11, w1, c1);
    }
    __builtin_amdgcn_s_setprio(0);
    storePair<true>(T0, ac0, p16, g);
    storePair<true>(T1, ac1, p16, g);
    x00 = loadA(T0, p16, g*8); x01 = loadA(T0, p16, 32 + g*8);
    x10 = loadA(T1, p16, g*8); x11 = loadA(T1, p16, 32 + g*8);

    // ---- L3 (feat, 16 cols, natural mapping) ----
    {
        const float b = fb3[p16];
        const half8 wa = ldfrag(frags, FO_L3 + 0, l);
        const half8 wb = ldfrag(frags, FO_L3 + 512, l);
        f32x4 c0 = {b, b, b, b}, c1 = {b, b, b, b};
        __builtin_amdgcn_s_setprio(1);
        c0 = MFMA16(x00, wa, c0); c0 = MFMA16(x01, wb, c0);
        c1 = MFMA16(x10, wa, c1); c1 = MFMA16(x11, wb, c1);
        __builtin_amdgcn_s_setprio(0);
        if (p16 == 0) {
            #pragma unroll
            for (int rr = 0; rr < 4; ++rr) {
                O0[(g*4+rr)*4 + 3] = __expf(c0[rr]);
                O1[(g*4+rr)*4 + 3] = __expf(c1[rr]);
            }
        }
        #pragma unroll
        for (int rr = 0; rr < 4; ++rr) {
            const int p = g*4 + rr;
            T0[p*64 + swz(p16, p)] = (_Float16)c0[rr];
            T1[p*64 + swz(p16, p)] = (_Float16)c1[rr];
        }
    }

    // ---- PE fill: features 16..31 ----
    pe_fill(T0, p16, g, d0.x, d0.y, d0.z);
    pe_fill(T1, p16, g, d1.x, d1.y, d1.z);
    const half8 ar0 = loadA(T0, p16, g*8);
    const half8 ar1 = loadA(T1, p16, g*8);

    // ---- R1 (K=32) ----
    __builtin_amdgcn_s_setprio(1);
    #pragma unroll
    for (int t = 0; t < 4; ++t) {
        const float b = rb1[(p16 << 2) + t];
        const half8 w = ldfrag(frags, FO_R1 + t * 512, l);
        f32x4 c = {b, b, b, b};
        ac0[t] = MFMA16(ar0, w, c);
        ac1[t] = MFMA16(ar1, w, c);
    }
    __builtin_amdgcn_s_setprio(0);
    storePair<true>(T0, ac0, p16, g);
    storePair<true>(T1, ac1, p16, g);
    x00 = loadA(T0, p16, g*8); x01 = loadA(T0, p16, 32 + g*8);
    x10 = loadA(T1, p16, g*8); x11 = loadA(T1, p16, 32 + g*8);

    // ---- R2 (K=64) ----
    __builtin_amdgcn_s_setprio(1);
    #pragma unroll
    for (int t = 0; t < 4; ++t) {
        const float b = rb2[(p16 << 2) + t];
        const half8 w0 = ldfrag(frags, FO_R2 + (2*t+0) * 512, l);
        const half8 w1 = ldfrag(frags, FO_R2 + (2*t+1) * 512, l);
        f32x4 c0 = {b, b, b, b}, c1 = {b, b, b, b};
        c0 = MFMA16(x00, w0, c0); ac0[t] = MFMA16(x01, w1, c0);
        c1 = MFMA16(x10, w0, c1); ac1[t] = MFMA16(x11, w1, c1);
    }
    __builtin_amdgcn_s_setprio(0);
    storePair<true>(T0, ac0, p16, g);
    storePair<true>(T1, ac1, p16, g);
    x00 = loadA(T0, p16, g*8); x01 = loadA(T0, p16, 32 + g*8);
    x10 = loadA(T1, p16, g*8); x11 = loadA(T1, p16, 32 + g*8);

    // ---- R3 (K=64) ----
    __builtin_amdgcn_s_setprio(1);
    #pragma unroll
    for (int t = 0; t < 4; ++t) {
        const float b = rb3[(p16 << 2) + t];
        const half8 w0 = ldfrag(frags, FO_R3 + (2*t+0) * 512, l);
        const half8 w1 = ldfrag(frags, FO_R3 + (2*t+1) * 512, l);
        f32x4 c0 = {b, b, b, b}, c1 = {b, b, b, b};
        c0 = MFMA16(x00, w0, c0); ac0[t] = MFMA16(x01, w1, c0);
        c1 = MFMA16(x10, w0, c1); ac1[t] = MFMA16(x11, w1, c1);
    }
    __builtin_amdgcn_s_setprio(0);
    storePair<true>(T0, ac0, p16, g);
    storePair<true>(T1, ac1, p16, g);
    x00 = loadA(T0, p16, g*8); x01 = loadA(T0, p16, 32 + g*8);
    x10 = loadA(T1, p16, g*8); x11 = loadA(T1, p16, 32 + g*8);

    // ---- R4 (rgb, 3 cols, natural mapping) ----
    {
        const float b = (p16 < 3) ? rb4[p16] : 0.f;
        const half8 wa = ldfrag(frags, FO_R4 + 0, l);
        const half8 wb = ldfrag(frags, FO_R4 + 512, l);
        f32x4 c0 = {b, b, b, b}, c1 = {b, b, b, b};
        __builtin_amdgcn_s_setprio(1);
        c0 = MFMA16(x00, wa, c0); c0 = MFMA16(x01, wb, c0);
        c1 = MFMA16(x10, wa, c1); c1 = MFMA16(x11, wb, c1);
        __builtin_amdgcn_s_setprio(0);
        if (p16 < 3) {
            #pragma unroll
            for (int rr = 0; rr < 4; ++rr) {
                O0[(g*4+rr)*4 + p16] = 1.f / (1.f + __expf(-c0[rr]));
                O1[(g*4+rr)*4 + p16] = 1.f / (1.f + __expf(-c1[rr]));
            }
        }
    }

    // ---- scatter out ----
    if (wbase + p16 < N) {
        const unsigned orig = __float_as_uint(d0.w);
        out[(size_t)orig * 4 + g] = O0[p16 * 4 + g];
    }
    if (wbase + 16 + p16 < N) {
        const unsigned orig = __float_as_uint(d1.w);
        out[(size_t)orig * 4 + g] = O1[p16 * 4 + g];
    }
}

// ---------------- fused fallback (small ws, f32 table) ----------------
template<int NIN, int NOUT, bool RELU>
__device__ __forceinline__ void dense_l(const float* __restrict__ W, const float* __restrict__ Bias,
                                        const float* __restrict__ col, float (&out)[NOUT])
{
    #pragma unroll
    for (int j = 0; j < NOUT; ++j) out[j] = Bias[j];
    #pragma unroll 4
    for (int i = 0; i < NIN; ++i) {
        const float a = col[i * BLK];
        const float* Wr = W + i * NOUT;
        #pragma unroll
        for (int j = 0; j < NOUT; ++j) out[j] = fmaf(a, Wr[j], out[j]);
    }
    if (RELU) {
        #pragma unroll
        for (int j = 0; j < NOUT; ++j) out[j] = fmaxf(out[j], 0.f);
    }
}

__device__ __forceinline__ void encode_point_f(float x, float y, float z,
                                               const float* __restrict__ tableF,
                                               float (&emb)[32])
{
    constexpr int RES[16] = {32,38,46,55,67,80,97,116,140,168,203,244,294,353,425,512};
    constexpr int DN [16] = {1,1,1,1,1,1,1,1,1,1,1,1,0,0,0,0};
    constexpr int OFF[16] = {0,35937,95256,199079,374695,689127,1220568,2161760,
                             3763373,6566594,11393403,19883067,34589192,35113480,
                             35637768,36162056};
    constexpr unsigned NMASK = (1u << 19) - 1u;
    #pragma unroll
    for (int l = 0; l < 16; ++l) {
        const int res = RES[l];
        const float xl = x * (float)res, yl = y * (float)res, zl = z * (float)res;
        int cx = (int)floorf(xl); cx = cx < 0 ? 0 : (cx > res-1 ? res-1 : cx);
        int cy = (int)floorf(yl); cy = cy < 0 ? 0 : (cy > res-1 ? res-1 : cy);
        int cz = (int)floorf(zl); cz = cz < 0 ? 0 : (cz > res-1 ? res-1 : cz);
        const float wx = xl - (float)cx, wy = yl - (float)cy, wz = zl - (float)cz;
        float e0 = 0.f, e1 = 0.f;
        #pragma unroll
        for (int c = 0; c < 8; ++c) {
            const int dx = (c >> 2) & 1, dy = (c >> 1) & 1, dz = c & 1;
            int idx;
            if (DN[l]) {
                idx = (cx+dx) + (cy+dy)*(res+1) + (cz+dz)*(res+1)*(res+1);
            } else {
                const unsigned hh = (unsigned)(cx+dx) ^ ((unsigned)(cy+dy)*2654435761u)
                                  ^ ((unsigned)(cz+dz)*805459861u);
                idx = (int)(hh & NMASK);
            }
            const float w = (dx ? wx : 1.f-wx)*(dy ? wy : 1.f-wy)*(dz ? wz : 1.f-wz);
            const float2 v = *reinterpret_cast<const float2*>(tableF + (size_t)2*(size_t)(OFF[l]+idx));
            e0 = fmaf(v.x, w, e0); e1 = fmaf(v.y, w, e1);
        }
        emb[2*l+0] = e0; emb[2*l+1] = e1;
    }
}

__device__ __forceinline__ float4 mlp_lds(float* col, float dx0, float dy0, float dz0,
    const float* __restrict__ fw1, const float* __restrict__ fb1,
    const float* __restrict__ fw2, const float* __restrict__ fb2,
    const float* __restrict__ fw3, const float* __restrict__ fb3,
    const float* __restrict__ rw1, const float* __restrict__ rb1,
    const float* __restrict__ rw2, const float* __restrict__ rb2,
    const float* __restrict__ rw3, const float* __restrict__ rb3,
    const float* __restrict__ rw4, const float* __restrict__ rb4)
{
    float h[64];
    dense_l<32, 64, true>(fw1, fb1, col, h);
    #pragma unroll
    for (int j = 0; j < 64; ++j) col[j * BLK] = h[j];
    dense_l<64, 64, true>(fw2, fb2, col, h);
    #pragma unroll
    for (int j = 0; j < 64; ++j) col[j * BLK] = h[j];
    float feat16[16];
    dense_l<64, 16, false>(fw3, fb3, col, feat16);
    const float sigma = expf(feat16[0]);
    #pragma unroll
    for (int j = 0; j < 16; ++j) col[j * BLK] = feat16[j];
    col[16 * BLK] = dx0; col[17 * BLK] = dy0; col[18 * BLK] = dz0;
    {
        float s, c;
        sincosf(dx0,     &s, &c); col[19 * BLK] = s; col[25 * BLK] = c;
        sincosf(2.f*dx0, &s, &c); col[20 * BLK] = s; col[26 * BLK] = c;
        sincosf(dy0,     &s, &c); col[21 * BLK] = s; col[27 * BLK] = c;
        sincosf(2.f*dy0, &s, &c); col[22 * BLK] = s; col[28 * BLK] = c;
        sincosf(dz0,     &s, &c); col[23 * BLK] = s; col[29 * BLK] = c;
        sincosf(2.f*dz0, &s, &c); col[24 * BLK] = s; col[30 * BLK] = c;
    }
    dense_l<31, 64, true>(rw1, rb1, col, h);
    #pragma unroll
    for (int j = 0; j < 64; ++j) col[j * BLK] = h[j];
    dense_l<64, 64, true>(rw2, rb2, col, h);
    #pragma unroll
    for (int j = 0; j < 64; ++j) col[j * BLK] = h[j];
    dense_l<64, 64, true>(rw3, rb3, col, h);
    #pragma unroll
    for (int j = 0; j < 64; ++j) col[j * BLK] = h[j];
    float o0 = rb4[0], o1 = rb4[1], o2 = rb4[2];
    #pragma unroll 4
    for (int i = 0; i < 64; ++i) {
        const float a = col[i * BLK];
        o0 = fmaf(a, rw4[i*3 + 0], o0);
        o1 = fmaf(a, rw4[i*3 + 1], o1);
        o2 = fmaf(a, rw4[i*3 + 2], o2);
    }
    o0 = 1.f / (1.f + expf(-o0));
    o1 = 1.f / (1.f + expf(-o1));
    o2 = 1.f / (1.f + expf(-o2));
    return make_float4(o0, o1, o2, sigma);
}

__global__ __launch_bounds__(BLK) void ngp_fused_f32(
    const float* __restrict__ coords,
    const float* __restrict__ dirs,
    const float* __restrict__ tableF,
    const float* __restrict__ fw1, const float* __restrict__ fb1,
    const float* __restrict__ fw2, const float* __restrict__ fb2,
    const float* __restrict__ fw3, const float* __restrict__ fb3,
    const float* __restrict__ rw1, const float* __restrict__ rb1,
    const float* __restrict__ rw2, const float* __restrict__ rb2,
    const float* __restrict__ rw3, const float* __restrict__ rb3,
    const float* __restrict__ rw4, const float* __restrict__ rb4,
    float* __restrict__ out, int N)
{
    __shared__ float sbuf[64 * BLK];
    const int tid = threadIdx.x;
    const int gi  = blockIdx.x * BLK + tid;
    if (gi >= N) return;

    float emb[32];
    encode_point_f(coords[3*gi+0], coords[3*gi+1], coords[3*gi+2], tableF, emb);
    float* col = sbuf + tid;
    #pragma unroll
    for (int j = 0; j < 32; ++j) col[j * BLK] = emb[j];

    const float4 ov = mlp_lds(col, dirs[3*gi+0], dirs[3*gi+1], dirs[3*gi+2],
                              fw1, fb1, fw2, fb2, fw3, fb3,
                              rw1, rb1, rw2, rb2, rw3, rb3, rw4, rb4);
    reinterpret_cast<float4*>(out)[gi] = ov;
}

extern "C" void kernel_launch(void* const* d_in, const int* in_sizes, int n_in,
                              void* d_out, int out_size, void* d_ws, size_t ws_size,
                              hipStream_t stream)
{
    const float* coords = (const float*)d_in[0];
    const float* dirs   = (const float*)d_in[1];
    const float* table  = (const float*)d_in[2];
    const float* fw1 = (const float*)d_in[3];
    const float* fb1 = (const float*)d_in[4];
    const float* fw2 = (const float*)d_in[5];
    const float* fb2 = (const float*)d_in[6];
    const float* fw3 = (const float*)d_in[7];
    const float* fb3 = (const float*)d_in[8];
    const float* rw1 = (const float*)d_in[9];
    const float* rb1 = (const float*)d_in[10];
    const float* rw2 = (const float*)d_in[11];
    const float* rb2 = (const float*)d_in[12];
    const float* rw3 = (const float*)d_in[13];
    const float* rb3 = (const float*)d_in[14];
    const float* rw4 = (const float*)d_in[15];
    const float* rb4 = (const float*)d_in[16];

    const int N = in_sizes[0] / 3;

    // ws layout
    size_t pos = 0;
    auto take = [&](size_t bytes) { size_t p = pos; pos = (pos + bytes + 255) & ~(size_t)255; return p; };
    const size_t o_pd     = take((size_t)PD_ENTRIES * 4);
    const size_t o_mt     = take((size_t)MTOT * 2);
    const size_t o_ph     = take((size_t)PH_ENTRIES * 4);
    const size_t o_emb    = take((size_t)N * 64);
    const size_t o_cS     = take((size_t)N * 16);
    const size_t o_dS     = take((size_t)N * 16);
    const size_t o_hist   = take((size_t)NBINS * 4);
    const size_t o_cursor = take((size_t)NBINS * 4);
    const size_t o_bsum   = take(256 * 4);
    const size_t o_frag   = take((size_t)FRAG_TOTAL * 2);
    const size_t need_full = pos;

    char* ws = (char*)d_ws;

    if (ws_size >= need_full) {
        unsigned*       PD     = (unsigned*)(ws + o_pd);
        unsigned short* MT     = (unsigned short*)(ws + o_mt);
        unsigned*       PH     = (unsigned*)(ws + o_ph);
        uint4*     embws  = (uint4*)(ws + o_emb);
        float4*    cS     = (float4*)(ws + o_cS);
        float4*    dS     = (float4*)(ws + o_dS);
        unsigned*  hist   = (unsigned*)(ws + o_hist);
        unsigned*  cursor = (unsigned*)(ws + o_cursor);
        unsigned*  bsum   = (unsigned*)(ws + o_bsum);
        _Float16*  frag   = (_Float16*)(ws + o_frag);

        hipLaunchKernelGGL(cvt_pd, dim3((PD_ENTRIES + 255) / 256), dim3(256), 0, stream,
                           table, PD);
        hipLaunchKernelGGL(cvt_ph, dim3(PH_ENTRIES / 256), dim3(256), 0, stream,
                           table, PH);
        hipLaunchKernelGGL(cvt_mt, dim3(MTOT / 256), dim3(256), 0, stream,
                           table, MT);
        hipLaunchKernelGGL(prep_frags, dim3(FRAG_TOTAL / 256), dim3(256), 0, stream,
                           fw1, fw2, fw3, rw1, rw2, rw3, rw4, frag);
        hipMemsetAsync(hist, 0, (size_t)NBINS * 4, stream);
        hipLaunchKernelGGL(hist_build, dim3((N + 255) / 256), dim3(256), 0, stream,
                           coords, hist, N);
        hipLaunchKernelGGL(scan1, dim3(NBINS / 1024), dim3(256), 0, stream, hist, bsum);
        hipLaunchKernelGGL(scan2, dim3(1), dim3(256), 0, stream, bsum);
        hipLaunchKernelGGL(scan3, dim3(NBINS / 256), dim3(256), 0, stream, hist, bsum, cursor);
        hipLaunchKernelGGL(scatter_pts, dim3((N + 255) / 256), dim3(256), 0, stream,
                           coords, dirs, cursor, cS, dS, N);
        hipLaunchKernelGGL(ngp_encode, dim3((N + EBLK - 1) / EBLK), dim3(EBLK), 0, stream,
                           cS, PD, MT, PH, embws, N);
        hipLaunchKernelGGL(ngp_mlp_mfma, dim3((N + 127) / 128), dim3(256), 0, stream,
                           (const _Float16*)embws, dS, frag,
                           fb1, fb2, fb3, rb1, rb2, rb3, rb4,
                           (float*)d_out, N);
    } else {
        hipLaunchKernelGGL(ngp_fused_f32, dim3((N + BLK - 1) / BLK), dim3(BLK), 0, stream,
                           coords, dirs, table,
                           fw1, fb1, fw2, fb2, fw3, fb3,
                           rw1, rb1, rw2, rb2, rw3, rb3, rw4, rb4,
                           (float*)d_out, N);
    }
}

// Round 12
// 900.146 us; speedup vs baseline: 3.1445x; 1.3122x over previous
//
#include <hip/hip_runtime.h>
#include <hip/hip_fp16.h>
#include <math.h>

#define BLK 128          // fused-fallback block
#define EBLK 256         // encode / utility block
#define NBINS (1 << 18)  // 6 bits per axis, Morton sort bins
#define Q_SCALE 65536.0f
#define Q_DESCALE 0x1p-16f

typedef __attribute__((ext_vector_type(8))) _Float16 half8;
typedef __attribute__((ext_vector_type(4))) float f32x4;
typedef __attribute__((ext_vector_type(2))) float f32x2;

// frag offsets in f16 elements: L1,L2,L3,R1,R2,R3,R4
#define FO_L1 0
#define FO_L2 2048
#define FO_L3 6144
#define FO_R1 7168
#define FO_R2 9216
#define FO_R3 13312
#define FO_R4 17408
#define FRAG_TOTAL 18432

// ---- fp8 table layout ----
#define HOFF0 3764224
#define MOFF0 5861376
#define MOFF1 12939264
#define MOFF2 20017152
#define MOFF3 36794368
#define TABQ_ENTRIES 53571584
#define PAIR_LO 1881687
#define PAIR_H  1048576
#define MTOT 47710208

// ---------------- Morton helpers ----------------
__device__ __forceinline__ unsigned mexp(unsigned v) {
    v &= 0x3FF;
    v = (v | (v << 16)) & 0x030000FF;
    v = (v | (v << 8))  & 0x0300F00F;
    v = (v | (v << 4))  & 0x030C30C3;
    v = (v | (v << 2))  & 0x09249249;
    return v;
}
__device__ __forceinline__ unsigned mcomp(unsigned v) {
    v &= 0x09249249u;
    v = (v | (v >> 2)) & 0x030C30C3u;
    v = (v | (v >> 4)) & 0x0300F00Fu;
    v = (v | (v >> 8)) & 0x030000FFu;
    v = (v | (v >> 16)) & 0x3FFu;
    return v;
}
__device__ __forceinline__ unsigned morton_key(float x, float y, float z) {
    int bx = (int)(x * 64.f); bx = bx < 0 ? 0 : (bx > 63 ? 63 : bx);
    int by = (int)(y * 64.f); by = by < 0 ? 0 : (by > 63 ? 63 : by);
    int bz = (int)(z * 64.f); bz = bz < 0 ? 0 : (bz > 63 ? 63 : bz);
    return (mexp((unsigned)bx) << 2) | (mexp((unsigned)by) << 1) | mexp((unsigned)bz);
}

// ---------------- table conversion kernels ----------------
__device__ __forceinline__ unsigned pk_fp8(float a, float b) {
    const int lo = __builtin_amdgcn_cvt_pk_fp8_f32(a * Q_SCALE, b * Q_SCALE, 0, false);
    return (unsigned)lo & 0xFFFFu;
}

__global__ __launch_bounds__(256) void cvt_lo(const float4* __restrict__ src,
                                              unsigned* __restrict__ dst)
{
    const int i = blockIdx.x * 256 + threadIdx.x;
    if (i >= PAIR_LO) return;
    const float4 v = src[i];
    dst[i] = pk_fp8(v.x, v.y) | (pk_fp8(v.z, v.w) << 16);
}

__global__ __launch_bounds__(256) void cvt_hash(const float4* __restrict__ src,
                                                unsigned* __restrict__ dst)
{
    const int i = blockIdx.x * 256 + threadIdx.x;
    if (i >= PAIR_H) return;
    const float4 v = src[17294596 + i];            // OFF[12]/2 + i
    dst[HOFF0 / 2 + i] = pk_fp8(v.x, v.y) | (pk_fp8(v.z, v.w) << 16);
}

__global__ __launch_bounds__(256) void cvt_morton(const float* __restrict__ srcF,
                                                  unsigned short* __restrict__ dstQ)
{
    const unsigned e = blockIdx.x * 256 + threadIdx.x;
    if (e >= MTOT) return;
    int j, cnt; unsigned base, moff;
    if (e < 14155776u) {
        cnt = 3;
        if (e < 7077888u) { j = 0; base = 0u;        moff = MOFF0; }
        else              { j = 1; base = 7077888u;  moff = MOFF1; }
    } else {
        cnt = 4;
        if (e < 30932992u){ j = 2; base = 14155776u; moff = MOFF2; }
        else              { j = 3; base = 30932992u; moff = MOFF3; }
    }
    const unsigned within = e - base;
    const unsigned blk = within >> 18, lo = within & 0x3FFFFu;
    unsigned bx, by, bz;
    if (cnt == 3) { bx = blk % 3u; const unsigned t = blk / 3u; by = t % 3u; bz = t / 3u; }
    else          { bx = blk & 3u; by = (blk >> 2) & 3u; bz = blk >> 4; }
    const unsigned x = bx * 64u + mcomp(lo);
    const unsigned y = by * 64u + mcomp(lo >> 1);
    const unsigned z = bz * 64u + mcomp(lo >> 2);

    constexpr unsigned RES1[4] = {141u, 169u, 204u, 245u};
    constexpr unsigned SOFF[4] = {3763373u, 6566594u, 11393403u, 19883067u};
    const unsigned r1 = RES1[j];
    unsigned q = 0;
    if (x < r1 && y < r1 && z < r1) {
        const size_t se = (size_t)SOFF[j] + x + (size_t)y * r1 + (size_t)z * r1 * r1;
        const float2 v = *reinterpret_cast<const float2*>(srcF + 2 * se);
        q = pk_fp8(v.x, v.y);
    }
    dstQ[(size_t)moff + within] = (unsigned short)q;
}

// ---------------- weight fragment packing ----------------
__global__ __launch_bounds__(256) void prep_frags(
    const float* __restrict__ fw1, const float* __restrict__ fw2, const float* __restrict__ fw3,
    const float* __restrict__ rw1, const float* __restrict__ rw2, const float* __restrict__ rw3,
    const float* __restrict__ rw4, _Float16* __restrict__ frag)
{
    const int gid = blockIdx.x * 256 + threadIdx.x;
    if (gid >= FRAG_TOTAL) return;
    constexpr int offs[8] = {FO_L1, FO_L2, FO_L3, FO_R1, FO_R2, FO_R3, FO_R4, FRAG_TOTAL};
    constexpr int Ks[7]   = {32, 64, 64, 31, 64, 64, 64};
    constexpr int NO[7]   = {64, 64, 16, 64, 64, 64, 3};
    constexpr int NKs[7]  = {1, 2, 2, 1, 2, 2, 2};
    int layer = 0;
    #pragma unroll
    for (int i = 1; i < 7; ++i) if (gid >= offs[i]) layer = i;
    const float* W = fw1;
    if (layer == 1) W = fw2; else if (layer == 2) W = fw3;
    else if (layer == 3) W = rw1; else if (layer == 4) W = rw2;
    else if (layer == 5) W = rw3; else if (layer == 6) W = rw4;

    const int e = gid - offs[layer];
    const int nk = NKs[layer];
    const int blk = e >> 9, within = e & 511;
    const int t = blk / nk, ks = blk - t * nk;
    const int lane = within >> 3, i = within & 7;
    const int k = ks * 32 + (lane >> 4) * 8 + i;
    // 64-wide layers: col c of tile t holds output feature 4*c + t (paired-store remap)
    const int col = (NO[layer] == 64) ? ((lane & 15) * 4 + t) : (t * 16 + (lane & 15));
    float v = 0.f;
    if (k < Ks[layer] && col < NO[layer]) v = W[k * NO[layer] + col];
    frag[gid] = (_Float16)v;
}

// ---------------- sort: histogram ----------------
__global__ __launch_bounds__(256) void hist_build(const float* __restrict__ coords,
                                                  unsigned* __restrict__ hist, int N)
{
    const int i = blockIdx.x * 256 + threadIdx.x;
    if (i >= N) return;
    const unsigned key = morton_key(coords[3*i+0], coords[3*i+1], coords[3*i+2]);
    atomicAdd(&hist[key], 1u);
}

// ---------------- sort: hierarchical exclusive scan ----------------
__global__ __launch_bounds__(256) void scan1(unsigned* __restrict__ hist, unsigned* __restrict__ bsum)
{
    __shared__ unsigned sa[256], sb[256];
    const int t = threadIdx.x;
    const unsigned base = blockIdx.x * 1024u + (unsigned)t * 4u;
    const unsigned v0 = hist[base+0], v1 = hist[base+1], v2 = hist[base+2], v3 = hist[base+3];
    const unsigned sum = v0 + v1 + v2 + v3;
    sa[t] = sum; __syncthreads();
    unsigned* src = sa; unsigned* dst = sb;
    for (int off = 1; off < 256; off <<= 1) {
        dst[t] = src[t] + (t >= off ? src[t - off] : 0u);
        __syncthreads();
        unsigned* tmp = src; src = dst; dst = tmp;
    }
    const unsigned incl = src[t];
    unsigned run = incl - sum;
    hist[base+0] = run; run += v0;
    hist[base+1] = run; run += v1;
    hist[base+2] = run; run += v2;
    hist[base+3] = run;
    if (t == 255) bsum[blockIdx.x] = incl;
}

__global__ __launch_bounds__(256) void scan2(unsigned* __restrict__ bsum)
{
    __shared__ unsigned sa[256], sb[256];
    const int t = threadIdx.x;
    const unsigned v = bsum[t];
    sa[t] = v; __syncthreads();
    unsigned* src = sa; unsigned* dst = sb;
    for (int off = 1; off < 256; off <<= 1) {
        dst[t] = src[t] + (t >= off ? src[t - off] : 0u);
        __syncthreads();
        unsigned* tmp = src; src = dst; dst = tmp;
    }
    bsum[t] = src[t] - v;
}

__global__ __launch_bounds__(256) void scan3(const unsigned* __restrict__ hist,
                                             const unsigned* __restrict__ bsum,
                                             unsigned* __restrict__ cursor)
{
    const int i = blockIdx.x * 256 + threadIdx.x;
    cursor[i] = hist[i] + bsum[i >> 10];
}

// ---------------- sort: scatter points into bins ----------------
__global__ __launch_bounds__(256) void scatter_pts(const float* __restrict__ coords,
                                                   const float* __restrict__ dirs,
                                                   unsigned* __restrict__ cursor,
                                                   float4* __restrict__ cS,
                                                   float4* __restrict__ dS, int N)
{
    const int i = blockIdx.x * 256 + threadIdx.x;
    if (i >= N) return;
    const float x = coords[3*i+0], y = coords[3*i+1], z = coords[3*i+2];
    const unsigned key = morton_key(x, y, z);
    const unsigned slot = atomicAdd(&cursor[key], 1u);
    cS[slot] = make_float4(x, y, z, __uint_as_float((unsigned)i));
    dS[slot] = make_float4(dirs[3*i+0], dirs[3*i+1], dirs[3*i+2], __uint_as_float((unsigned)i));
}

// ---------------- encode kernel ----------------
__global__ __launch_bounds__(EBLK, 8) void ngp_encode(
    const float4* __restrict__ cS,
    const unsigned short* __restrict__ tableQ,
    uint4* __restrict__ emb_out, int N)
{
    // bijective XCD-contiguous remap of blockIdx (8 XCDs)
    const unsigned nwg = gridDim.x;
    const unsigned bid = blockIdx.x;
    const unsigned qn = nwg >> 3, rn = nwg & 7;
    const unsigned xc = bid & 7, ib = bid >> 3;
    const unsigned nb = (xc < rn ? xc * (qn + 1) : rn * (qn + 1) + (xc - rn) * qn) + ib;

    const int gi = (int)(nb * EBLK + threadIdx.x);
    if (gi >= N) return;

    const float4 cp = cS[gi];
    const float x = cp.x, y = cp.y, z = cp.z;

    float emb[32];

    // ---- dense row-major levels 0-7 ----
    {
        constexpr int RES[8] = {32,38,46,55,67,80,97,116};
        constexpr int OFF[8] = {0,35937,95256,199079,374695,689127,1220568,2161760};
        #pragma unroll
        for (int l = 0; l < 8; ++l) {
            const int res = RES[l];
            const float xl = x * (float)res, yl = y * (float)res, zl = z * (float)res;
            int cx = (int)floorf(xl); cx = cx < 0 ? 0 : (cx > res-1 ? res-1 : cx);
            int cy = (int)floorf(yl); cy = cy < 0 ? 0 : (cy > res-1 ? res-1 : cy);
            int cz = (int)floorf(zl); cz = cz < 0 ? 0 : (cz > res-1 ? res-1 : cz);
            const float wx = xl - (float)cx, wy = yl - (float)cy, wz = zl - (float)cz;
            unsigned qv[8];
            #pragma unroll
            for (int c = 0; c < 8; ++c) {
                const int dx = (c >> 2) & 1, dy = (c >> 1) & 1, dz = c & 1;
                const int idx = (cx+dx) + (cy+dy)*(res+1) + (cz+dz)*(res+1)*(res+1);
                qv[c] = tableQ[OFF[l] + idx];
            }
            float e0 = 0.f, e1 = 0.f;
            #pragma unroll
            for (int c = 0; c < 8; ++c) {
                const int dx = (c >> 2) & 1, dy = (c >> 1) & 1, dz = c & 1;
                const float w = (dx ? wx : 1.f-wx)*(dy ? wy : 1.f-wy)*(dz ? wz : 1.f-wz);
                const f32x2 vf = __builtin_amdgcn_cvt_pk_f32_fp8((int)qv[c], false);
                e0 = fmaf(vf.x, w, e0); e1 = fmaf(vf.y, w, e1);
            }
            emb[2*l+0] = e0 * Q_DESCALE; emb[2*l+1] = e1 * Q_DESCALE;
        }
    }

    // ---- Morton-block dense levels 8-11 ----
    {
        constexpr int RESM[4] = {140,168,203,244};
        constexpr int CNTM[4] = {3,3,4,4};
        constexpr unsigned MOFF[4] = {MOFF0, MOFF1, MOFF2, MOFF3};
        #pragma unroll
        for (int j = 0; j < 4; ++j) {
            const int res = RESM[j];
            const int cnt = CNTM[j];
            const float xl = x * (float)res, yl = y * (float)res, zl = z * (float)res;
            int cx = (int)floorf(xl); cx = cx < 0 ? 0 : (cx > res-1 ? res-1 : cx);
            int cy = (int)floorf(yl); cy = cy < 0 ? 0 : (cy > res-1 ? res-1 : cy);
            int cz = (int)floorf(zl); cz = cz < 0 ? 0 : (cz > res-1 ? res-1 : cz);
            const float wx = xl - (float)cx, wy = yl - (float)cy, wz = zl - (float)cz;

            const int bx0 = cx >> 6, bx1 = (cx+1) >> 6;
            const int by0 = cy >> 6, by1 = (cy+1) >> 6;
            const int bz0 = cz >> 6, bz1 = (cz+1) >> 6;
            const unsigned mx0 = mexp(cx & 63),      mx1 = mexp((cx+1) & 63);
            const unsigned my0 = mexp(cy & 63) << 1, my1 = mexp((cy+1) & 63) << 1;
            const unsigned mz0 = mexp(cz & 63) << 2, mz1 = mexp((cz+1) & 63) << 2;

            unsigned qv[8];
            #pragma unroll
            for (int c = 0; c < 8; ++c) {
                const int dx = (c >> 2) & 1, dy = (c >> 1) & 1, dz = c & 1;
                const int bx = dx ? bx1 : bx0, by = dy ? by1 : by0, bz = dz ? bz1 : bz0;
                const unsigned mm = (dx ? mx1 : mx0) | (dy ? my1 : my0) | (dz ? mz1 : mz0);
                const unsigned blk = (unsigned)((bz * cnt + by) * cnt + bx);
                qv[c] = tableQ[(size_t)MOFF[j] + ((blk << 18) | mm)];
            }
            float e0 = 0.f, e1 = 0.f;
            #pragma unroll
            for (int c = 0; c < 8; ++c) {
                const int dx = (c >> 2) & 1, dy = (c >> 1) & 1, dz = c & 1;
                const float w = (dx ? wx : 1.f-wx)*(dy ? wy : 1.f-wy)*(dz ? wz : 1.f-wz);
                const f32x2 vf = __builtin_amdgcn_cvt_pk_f32_fp8((int)qv[c], false);
                e0 = fmaf(vf.x, w, e0); e1 = fmaf(vf.y, w, e1);
            }
            emb[16+2*j+0] = e0 * Q_DESCALE; emb[16+2*j+1] = e1 * Q_DESCALE;
        }
    }

    // ---- hashed levels 12-15 ----
    {
        constexpr int RESH[4] = {294,353,425,512};
        constexpr unsigned HOFF[4] = {HOFF0, HOFF0+524288, HOFF0+1048576, HOFF0+1572864};
        constexpr unsigned NMASK = (1u << 19) - 1u;
        #pragma unroll
        for (int j = 0; j < 4; ++j) {
            const int res = RESH[j];
            const float xl = x * (float)res, yl = y * (float)res, zl = z * (float)res;
            int cx = (int)floorf(xl); cx = cx < 0 ? 0 : (cx > res-1 ? res-1 : cx);
            int cy = (int)floorf(yl); cy = cy < 0 ? 0 : (cy > res-1 ? res-1 : cy);
            int cz = (int)floorf(zl); cz = cz < 0 ? 0 : (cz > res-1 ? res-1 : cz);
            const float wx = xl - (float)cx, wy = yl - (float)cy, wz = zl - (float)cz;
            unsigned qv[8];
            #pragma unroll
            for (int c = 0; c < 8; ++c) {
                const int dx = (c >> 2) & 1, dy = (c >> 1) & 1, dz = c & 1;
                const unsigned hh = (unsigned)(cx+dx) ^ ((unsigned)(cy+dy) * 2654435761u)
                                  ^ ((unsigned)(cz+dz) * 805459861u);
                qv[c] = tableQ[HOFF[j] + (hh & NMASK)];
            }
            float e0 = 0.f, e1 = 0.f;
            #pragma unroll
            for (int c = 0; c < 8; ++c) {
                const int dx = (c >> 2) & 1, dy = (c >> 1) & 1, dz = c & 1;
                const float w = (dx ? wx : 1.f-wx)*(dy ? wy : 1.f-wy)*(dz ? wz : 1.f-wz);
                const f32x2 vf = __builtin_amdgcn_cvt_pk_f32_fp8((int)qv[c], false);
                e0 = fmaf(vf.x, w, e0); e1 = fmaf(vf.y, w, e1);
            }
            emb[24+2*j+0] = e0 * Q_DESCALE; emb[24+2*j+1] = e1 * Q_DESCALE;
        }
    }

    unsigned packed[16];
    #pragma unroll
    for (int i = 0; i < 16; ++i) {
        const __half2 h = __floats2half2_rn(emb[2*i+0], emb[2*i+1]);
        packed[i] = *reinterpret_cast<const unsigned*>(&h);
    }
    uint4* dst = emb_out + (size_t)gi * 4;
    #pragma unroll
    for (int k = 0; k < 4; ++k)
        dst[k] = make_uint4(packed[4*k+0], packed[4*k+1], packed[4*k+2], packed[4*k+3]);
}

// ================= MFMA MLP =================
__device__ __forceinline__ half8 ldfrag(const _Float16* __restrict__ frags, int off, int l) {
    return *reinterpret_cast<const half8*>(frags + off + l * 8);
}
__device__ __forceinline__ int swz(int f, int p) {
    return ((((f >> 3) + p) & 7) << 3) | (f & 7);
}
__device__ __forceinline__ half8 loadA(const _Float16* T, int p, int kb) {
    return *reinterpret_cast<const half8*>(T + p * 64 + ((((kb >> 3) + p) & 7) << 3));
}
// paired store: acc[t][r] holds output feature 4*p16+t for point g*4+r
template<bool RELU>
__device__ __forceinline__ void storePair(_Float16* T, const f32x4 (&acc)[4], int p16, int g) {
    #pragma unroll
    for (int r = 0; r < 4; ++r) {
        const int p = g * 4 + r;
        float v0 = acc[0][r], v1 = acc[1][r], v2 = acc[2][r], v3 = acc[3][r];
        if (RELU) { v0 = fmaxf(v0,0.f); v1 = fmaxf(v1,0.f); v2 = fmaxf(v2,0.f); v3 = fmaxf(v3,0.f); }
        const __half2 h01 = __floats2half2_rn(v0, v1);
        const __half2 h23 = __floats2half2_rn(v2, v3);
        const int blkb = ((p16 >> 1) + p) & 7;
        uint2* dst = reinterpret_cast<uint2*>(T + p * 64 + blkb * 8 + 4 * (p16 & 1));
        *dst = make_uint2(*reinterpret_cast<const unsigned*>(&h01),
                          *reinterpret_cast<const unsigned*>(&h23));
    }
}
__device__ __forceinline__ void pe_fill(_Float16* T, int p16, int g, float dx, float dy, float dz) {
    float pv0, pv1, pv2, pv3;
    if (g == 0)      { pv0 = dx;             pv1 = dy;         pv2 = dz;             pv3 = __sinf(dx); }
    else if (g == 1) { pv0 = __sinf(2.f*dx); pv1 = __sinf(dy); pv2 = __sinf(2.f*dy); pv3 = __sinf(dz); }
    else if (g == 2) { pv0 = __sinf(2.f*dz); pv1 = __cosf(dx); pv2 = __cosf(2.f*dx); pv3 = __cosf(dy); }
    else             { pv0 = __cosf(2.f*dy); pv1 = __cosf(dz); pv2 = __cosf(2.f*dz); pv3 = 0.f; }
    const float pv[4] = {pv0, pv1, pv2, pv3};
    #pragma unroll
    for (int j2 = 0; j2 < 4; ++j2) {
        const int f = 16 + g * 4 + j2;
        T[p16 * 64 + swz(f, p16)] = (_Float16)pv[j2];
    }
}
#define MFMA16(a, b, c) __builtin_amdgcn_mfma_f32_16x16x32_f16((a), (b), (c), 0, 0, 0)

__global__ __launch_bounds__(256) void ngp_mlp_mfma(
    const _Float16* __restrict__ embws,      // [N][32] f16
    const float4* __restrict__ dS,
    const _Float16* __restrict__ frags,
    const float* __restrict__ fb1, const float* __restrict__ fb2, const float* __restrict__ fb3,
    const float* __restrict__ rb1, const float* __restrict__ rb2, const float* __restrict__ rb3,
    const float* __restrict__ rb4,
    float* __restrict__ out, int N)
{
    __shared__ _Float16 tbuf[4][2][16 * 64];
    __shared__ float obuf[4][2][64];
    const int tid = threadIdx.x;
    const int wv = tid >> 6, l = tid & 63;
    const int p16 = l & 15, g = l >> 4;
    const int wbase = (blockIdx.x * 4 + wv) * 32;
    _Float16* T0 = tbuf[wv][0];
    _Float16* T1 = tbuf[wv][1];
    float* O0 = obuf[wv][0];
    float* O1 = obuf[wv][1];

    int pi0 = wbase + p16;      if (pi0 >= N) pi0 = N - 1;
    int pi1 = wbase + 16 + p16; if (pi1 >= N) pi1 = N - 1;
    const float4 d0 = dS[pi0];
    const float4 d1 = dS[pi1];

    f32x4 ac0[4], ac1[4];
    half8 x00, x01, x10, x11;

    // ---- L1 (K=32): A straight from packed emb ----
    {
        const half8 a0 = *reinterpret_cast<const half8*>(embws + (size_t)pi0 * 32 + g * 8);
        const half8 a1 = *reinterpret_cast<const half8*>(embws + (size_t)pi1 * 32 + g * 8);
        __builtin_amdgcn_s_setprio(1);
        #pragma unroll
        for (int t = 0; t < 4; ++t) {
            const float b = fb1[(p16 << 2) + t];
            const half8 w = ldfrag(frags, FO_L1 + t * 512, l);
            f32x4 c = {b, b, b, b};
            ac0[t] = MFMA16(a0, w, c);
            ac1[t] = MFMA16(a1, w, c);
        }
        __builtin_amdgcn_s_setprio(0);
    }
    storePair<true>(T0, ac0, p16, g);
    storePair<true>(T1, ac1, p16, g);
    x00 = loadA(T0, p16, g*8); x01 = loadA(T0, p16, 32 + g*8);
    x10 = loadA(T1, p16, g*8); x11 = loadA(T1, p16, 32 + g*8);

    // ---- L2 (K=64) ----
    __builtin_amdgcn_s_setprio(1);
    #pragma unroll
    for (int t = 0; t < 4; ++t) {
        const float b = fb2[(p16 << 2) + t];
        const half8 w0 = ldfrag(frags, FO_L2 + (2*t+0) * 512, l);
        const half8 w1 = ldfrag(frags, FO_L2 + (2*t+1) * 512, l);
        f32x4 c0 = {b, b, b, b}, c1 = {b, b, b, b};
        c0 = MFMA16(x00, w0, c0); ac0[t] = MFMA16(x01, w1, c0);
        c1 = MFMA16(x10, w0, c1); ac1[t] = MFMA16(x11, w1, c1);
    }
    __builtin_amdgcn_s_setprio(0);
    storePair<true>(T0, ac0, p16, g);
    storePair<true>(T1, ac1, p16, g);
    x00 = loadA(T0, p16, g*8); x01 = loadA(T0, p16, 32 + g*8);
    x10 = loadA(T1, p16, g*8); x11 = loadA(T1, p16, 32 + g*8);

    // ---- L3 (feat, 16 cols, natural mapping) ----
    {
        const float b = fb3[p16];
        const half8 wa = ldfrag(frags, FO_L3 + 0, l);
        const half8 wb = ldfrag(frags, FO_L3 + 512, l);
        f32x4 c0 = {b, b, b, b}, c1 = {b, b, b, b};
        __builtin_amdgcn_s_setprio(1);
        c0 = MFMA16(x00, wa, c0); c0 = MFMA16(x01, wb, c0);
        c1 = MFMA16(x10, wa, c1); c1 = MFMA16(x11, wb, c1);
        __builtin_amdgcn_s_setprio(0);
        if (p16 == 0) {
            #pragma unroll
            for (int rr = 0; rr < 4; ++rr) {
                O0[(g*4+rr)*4 + 3] = __expf(c0[rr]);
                O1[(g*4+rr)*4 + 3] = __expf(c1[rr]);
            }
        }
        #pragma unroll
        for (int rr = 0; rr < 4; ++rr) {
            const int p = g*4 + rr;
            T0[p*64 + swz(p16, p)] = (_Float16)c0[rr];
            T1[p*64 + swz(p16, p)] = (_Float16)c1[rr];
        }
    }

    // ---- PE fill: features 16..31 ----
    pe_fill(T0, p16, g, d0.x, d0.y, d0.z);
    pe_fill(T1, p16, g, d1.x, d1.y, d1.z);
    const half8 ar0 = loadA(T0, p16, g*8);
    const half8 ar1 = loadA(T1, p16, g*8);

    // ---- R1 (K=32) ----
    __builtin_amdgcn_s_setprio(1);
    #pragma unroll
    for (int t = 0; t < 4; ++t) {
        const float b = rb1[(p16 << 2) + t];
        const half8 w = ldfrag(frags, FO_R1 + t * 512, l);
        f32x4 c = {b, b, b, b};
        ac0[t] = MFMA16(ar0, w, c);
        ac1[t] = MFMA16(ar1, w, c);
    }
    __builtin_amdgcn_s_setprio(0);
    storePair<true>(T0, ac0, p16, g);
    storePair<true>(T1, ac1, p16, g);
    x00 = loadA(T0, p16, g*8); x01 = loadA(T0, p16, 32 + g*8);
    x10 = loadA(T1, p16, g*8); x11 = loadA(T1, p16, 32 + g*8);

    // ---- R2 (K=64) ----
    __builtin_amdgcn_s_setprio(1);
    #pragma unroll
    for (int t = 0; t < 4; ++t) {
        const float b = rb2[(p16 << 2) + t];
        const half8 w0 = ldfrag(frags, FO_R2 + (2*t+0) * 512, l);
        const half8 w1 = ldfrag(frags, FO_R2 + (2*t+1) * 512, l);
        f32x4 c0 = {b, b, b, b}, c1 = {b, b, b, b};
        c0 = MFMA16(x00, w0, c0); ac0[t] = MFMA16(x01, w1, c0);
        c1 = MFMA16(x10, w0, c1); ac1[t] = MFMA16(x11, w1, c1);
    }
    __builtin_amdgcn_s_setprio(0);
    storePair<true>(T0, ac0, p16, g);
    storePair<true>(T1, ac1, p16, g);
    x00 = loadA(T0, p16, g*8); x01 = loadA(T0, p16, 32 + g*8);
    x10 = loadA(T1, p16, g*8); x11 = loadA(T1, p16, 32 + g*8);

    // ---- R3 (K=64) ----
    __builtin_amdgcn_s_setprio(1);
    #pragma unroll
    for (int t = 0; t < 4; ++t) {
        const float b = rb3[(p16 << 2) + t];
        const half8 w0 = ldfrag(frags, FO_R3 + (2*t+0) * 512, l);
        const half8 w1 = ldfrag(frags, FO_R3 + (2*t+1) * 512, l);
        f32x4 c0 = {b, b, b, b}, c1 = {b, b, b, b};
        c0 = MFMA16(x00, w0, c0); ac0[t] = MFMA16(x01, w1, c0);
        c1 = MFMA16(x10, w0, c1); ac1[t] = MFMA16(x11, w1, c1);
    }
    __builtin_amdgcn_s_setprio(0);
    storePair<true>(T0, ac0, p16, g);
    storePair<true>(T1, ac1, p16, g);
    x00 = loadA(T0, p16, g*8); x01 = loadA(T0, p16, 32 + g*8);
    x10 = loadA(T1, p16, g*8); x11 = loadA(T1, p16, 32 + g*8);

    // ---- R4 (rgb, 3 cols, natural mapping) ----
    {
        const float b = (p16 < 3) ? rb4[p16] : 0.f;
        const half8 wa = ldfrag(frags, FO_R4 + 0, l);
        const half8 wb = ldfrag(frags, FO_R4 + 512, l);
        f32x4 c0 = {b, b, b, b}, c1 = {b, b, b, b};
        __builtin_amdgcn_s_setprio(1);
        c0 = MFMA16(x00, wa, c0); c0 = MFMA16(x01, wb, c0);
        c1 = MFMA16(x10, wa, c1); c1 = MFMA16(x11, wb, c1);
        __builtin_amdgcn_s_setprio(0);
        if (p16 < 3) {
            #pragma unroll
            for (int rr = 0; rr < 4; ++rr) {
                O0[(g*4+rr)*4 + p16] = 1.f / (1.f + __expf(-c0[rr]));
                O1[(g*4+rr)*4 + p16] = 1.f / (1.f + __expf(-c1[rr]));
            }
        }
    }

    // ---- scatter out ----
    if (wbase + p16 < N) {
        const unsigned orig = __float_as_uint(d0.w);
        out[(size_t)orig * 4 + g] = O0[p16 * 4 + g];
    }
    if (wbase + 16 + p16 < N) {
        const unsigned orig = __float_as_uint(d1.w);
        out[(size_t)orig * 4 + g] = O1[p16 * 4 + g];
    }
}

// ---------------- fused fallback (small ws, f32 table) ----------------
template<int NIN, int NOUT, bool RELU>
__device__ __forceinline__ void dense_l(const float* __restrict__ W, const float* __restrict__ Bias,
                                        const float* __restrict__ col, float (&out)[NOUT])
{
    #pragma unroll
    for (int j = 0; j < NOUT; ++j) out[j] = Bias[j];
    #pragma unroll 4
    for (int i = 0; i < NIN; ++i) {
        const float a = col[i * BLK];
        const float* Wr = W + i * NOUT;
        #pragma unroll
        for (int j = 0; j < NOUT; ++j) out[j] = fmaf(a, Wr[j], out[j]);
    }
    if (RELU) {
        #pragma unroll
        for (int j = 0; j < NOUT; ++j) out[j] = fmaxf(out[j], 0.f);
    }
}

__device__ __forceinline__ void encode_point_f(float x, float y, float z,
                                               const float* __restrict__ tableF,
                                               float (&emb)[32])
{
    constexpr int RES[16] = {32,38,46,55,67,80,97,116,140,168,203,244,294,353,425,512};
    constexpr int DN [16] = {1,1,1,1,1,1,1,1,1,1,1,1,0,0,0,0};
    constexpr int OFF[16] = {0,35937,95256,199079,374695,689127,1220568,2161760,
                             3763373,6566594,11393403,19883067,34589192,35113480,
                             35637768,36162056};
    constexpr unsigned NMASK = (1u << 19) - 1u;
    #pragma unroll
    for (int l = 0; l < 16; ++l) {
        const int res = RES[l];
        const float xl = x * (float)res, yl = y * (float)res, zl = z * (float)res;
        int cx = (int)floorf(xl); cx = cx < 0 ? 0 : (cx > res-1 ? res-1 : cx);
        int cy = (int)floorf(yl); cy = cy < 0 ? 0 : (cy > res-1 ? res-1 : cy);
        int cz = (int)floorf(zl); cz = cz < 0 ? 0 : (cz > res-1 ? res-1 : cz);
        const float wx = xl - (float)cx, wy = yl - (float)cy, wz = zl - (float)cz;
        float e0 = 0.f, e1 = 0.f;
        #pragma unroll
        for (int c = 0; c < 8; ++c) {
            const int dx = (c >> 2) & 1, dy = (c >> 1) & 1, dz = c & 1;
            int idx;
            if (DN[l]) {
                idx = (cx+dx) + (cy+dy)*(res+1) + (cz+dz)*(res+1)*(res+1);
            } else {
                const unsigned hh = (unsigned)(cx+dx) ^ ((unsigned)(cy+dy)*2654435761u)
                                  ^ ((unsigned)(cz+dz)*805459861u);
                idx = (int)(hh & NMASK);
            }
            const float w = (dx ? wx : 1.f-wx)*(dy ? wy : 1.f-wy)*(dz ? wz : 1.f-wz);
            const float2 v = *reinterpret_cast<const float2*>(tableF + (size_t)2*(size_t)(OFF[l]+idx));
            e0 = fmaf(v.x, w, e0); e1 = fmaf(v.y, w, e1);
        }
        emb[2*l+0] = e0; emb[2*l+1] = e1;
    }
}

__device__ __forceinline__ float4 mlp_lds(float* col, float dx0, float dy0, float dz0,
    const float* __restrict__ fw1, const float* __restrict__ fb1,
    const float* __restrict__ fw2, const float* __restrict__ fb2,
    const float* __restrict__ fw3, const float* __restrict__ fb3,
    const float* __restrict__ rw1, const float* __restrict__ rb1,
    const float* __restrict__ rw2, const float* __restrict__ rb2,
    const float* __restrict__ rw3, const float* __restrict__ rb3,
    const float* __restrict__ rw4, const float* __restrict__ rb4)
{
    float h[64];
    dense_l<32, 64, true>(fw1, fb1, col, h);
    #pragma unroll
    for (int j = 0; j < 64; ++j) col[j * BLK] = h[j];
    dense_l<64, 64, true>(fw2, fb2, col, h);
    #pragma unroll
    for (int j = 0; j < 64; ++j) col[j * BLK] = h[j];
    float feat16[16];
    dense_l<64, 16, false>(fw3, fb3, col, feat16);
    const float sigma = expf(feat16[0]);
    #pragma unroll
    for (int j = 0; j < 16; ++j) col[j * BLK] = feat16[j];
    col[16 * BLK] = dx0; col[17 * BLK] = dy0; col[18 * BLK] = dz0;
    {
        float s, c;
        sincosf(dx0,     &s, &c); col[19 * BLK] = s; col[25 * BLK] = c;
        sincosf(2.f*dx0, &s, &c); col[20 * BLK] = s; col[26 * BLK] = c;
        sincosf(dy0,     &s, &c); col[21 * BLK] = s; col[27 * BLK] = c;
        sincosf(2.f*dy0, &s, &c); col[22 * BLK] = s; col[28 * BLK] = c;
        sincosf(dz0,     &s, &c); col[23 * BLK] = s; col[29 * BLK] = c;
        sincosf(2.f*dz0, &s, &c); col[24 * BLK] = s; col[30 * BLK] = c;
    }
    dense_l<31, 64, true>(rw1, rb1, col, h);
    #pragma unroll
    for (int j = 0; j < 64; ++j) col[j * BLK] = h[j];
    dense_l<64, 64, true>(rw2, rb2, col, h);
    #pragma unroll
    for (int j = 0; j < 64; ++j) col[j * BLK] = h[j];
    dense_l<64, 64, true>(rw3, rb3, col, h);
    #pragma unroll
    for (int j = 0; j < 64; ++j) col[j * BLK] = h[j];
    float o0 = rb4[0], o1 = rb4[1], o2 = rb4[2];
    #pragma unroll 4
    for (int i = 0; i < 64; ++i) {
        const float a = col[i * BLK];
        o0 = fmaf(a, rw4[i*3 + 0], o0);
        o1 = fmaf(a, rw4[i*3 + 1], o1);
        o2 = fmaf(a, rw4[i*3 + 2], o2);
    }
    o0 = 1.f / (1.f + expf(-o0));
    o1 = 1.f / (1.f + expf(-o1));
    o2 = 1.f / (1.f + expf(-o2));
    return make_float4(o0, o1, o2, sigma);
}

__global__ __launch_bounds__(BLK) void ngp_fused_f32(
    const float* __restrict__ coords,
    const float* __restrict__ dirs,
    const float* __restrict__ tableF,
    const float* __restrict__ fw1, const float* __restrict__ fb1,
    const float* __restrict__ fw2, const float* __restrict__ fb2,
    const float* __restrict__ fw3, const float* __restrict__ fb3,
    const float* __restrict__ rw1, const float* __restrict__ rb1,
    const float* __restrict__ rw2, const float* __restrict__ rb2,
    const float* __restrict__ rw3, const float* __restrict__ rb3,
    const float* __restrict__ rw4, const float* __restrict__ rb4,
    float* __restrict__ out, int N)
{
    __shared__ float sbuf[64 * BLK];
    const int tid = threadIdx.x;
    const int gi  = blockIdx.x * BLK + tid;
    if (gi >= N) return;

    float emb[32];
    encode_point_f(coords[3*gi+0], coords[3*gi+1], coords[3*gi+2], tableF, emb);
    float* col = sbuf + tid;
    #pragma unroll
    for (int j = 0; j < 32; ++j) col[j * BLK] = emb[j];

    const float4 ov = mlp_lds(col, dirs[3*gi+0], dirs[3*gi+1], dirs[3*gi+2],
                              fw1, fb1, fw2, fb2, fw3, fb3,
                              rw1, rb1, rw2, rb2, rw3, rb3, rw4, rb4);
    reinterpret_cast<float4*>(out)[gi] = ov;
}

extern "C" void kernel_launch(void* const* d_in, const int* in_sizes, int n_in,
                              void* d_out, int out_size, void* d_ws, size_t ws_size,
                              hipStream_t stream)
{
    const float* coords = (const float*)d_in[0];
    const float* dirs   = (const float*)d_in[1];
    const float* table  = (const float*)d_in[2];
    const float* fw1 = (const float*)d_in[3];
    const float* fb1 = (const float*)d_in[4];
    const float* fw2 = (const float*)d_in[5];
    const float* fb2 = (const float*)d_in[6];
    const float* fw3 = (const float*)d_in[7];
    const float* fb3 = (const float*)d_in[8];
    const float* rw1 = (const float*)d_in[9];
    const float* rb1 = (const float*)d_in[10];
    const float* rw2 = (const float*)d_in[11];
    const float* rb2 = (const float*)d_in[12];
    const float* rw3 = (const float*)d_in[13];
    const float* rb3 = (const float*)d_in[14];
    const float* rw4 = (const float*)d_in[15];
    const float* rb4 = (const float*)d_in[16];

    const int N = in_sizes[0] / 3;

    // ws layout
    size_t pos = 0;
    auto take = [&](size_t bytes) { size_t p = pos; pos = (pos + bytes + 255) & ~(size_t)255; return p; };
    const size_t o_tableQ = take((size_t)TABQ_ENTRIES * 2);
    const size_t o_emb    = take((size_t)N * 64);
    const size_t o_cS     = take((size_t)N * 16);
    const size_t o_dS     = take((size_t)N * 16);
    const size_t o_hist   = take((size_t)NBINS * 4);
    const size_t o_cursor = take((size_t)NBINS * 4);
    const size_t o_bsum   = take(256 * 4);
    const size_t o_frag   = take((size_t)FRAG_TOTAL * 2);
    const size_t need_full = pos;

    char* ws = (char*)d_ws;

    if (ws_size >= need_full) {
        unsigned short* tableQ = (unsigned short*)(ws + o_tableQ);
        uint4*     embws  = (uint4*)(ws + o_emb);
        float4*    cS     = (float4*)(ws + o_cS);
        float4*    dS     = (float4*)(ws + o_dS);
        unsigned*  hist   = (unsigned*)(ws + o_hist);
        unsigned*  cursor = (unsigned*)(ws + o_cursor);
        unsigned*  bsum   = (unsigned*)(ws + o_bsum);
        _Float16*  frag   = (_Float16*)(ws + o_frag);

        hipLaunchKernelGGL(cvt_lo, dim3((PAIR_LO + 255) / 256), dim3(256), 0, stream,
                           (const float4*)table, (unsigned*)tableQ);
        hipLaunchKernelGGL(cvt_hash, dim3(PAIR_H / 256), dim3(256), 0, stream,
                           (const float4*)table, (unsigned*)tableQ);
        hipLaunchKernelGGL(cvt_morton, dim3(MTOT / 256), dim3(256), 0, stream,
                           table, tableQ);
        hipLaunchKernelGGL(prep_frags, dim3(FRAG_TOTAL / 256), dim3(256), 0, stream,
                           fw1, fw2, fw3, rw1, rw2, rw3, rw4, frag);
        hipMemsetAsync(hist, 0, (size_t)NBINS * 4, stream);
        hipLaunchKernelGGL(hist_build, dim3((N + 255) / 256), dim3(256), 0, stream,
                           coords, hist, N);
        hipLaunchKernelGGL(scan1, dim3(NBINS / 1024), dim3(256), 0, stream, hist, bsum);
        hipLaunchKernelGGL(scan2, dim3(1), dim3(256), 0, stream, bsum);
        hipLaunchKernelGGL(scan3, dim3(NBINS / 256), dim3(256), 0, stream, hist, bsum, cursor);
        hipLaunchKernelGGL(scatter_pts, dim3((N + 255) / 256), dim3(256), 0, stream,
                           coords, dirs, cursor, cS, dS, N);
        hipLaunchKernelGGL(ngp_encode, dim3((N + EBLK - 1) / EBLK), dim3(EBLK), 0, stream,
                           cS, tableQ, embws, N);
        hipLaunchKernelGGL(ngp_mlp_mfma, dim3((N + 127) / 128), dim3(256), 0, stream,
                           (const _Float16*)embws, dS, frag,
                           fb1, fb2, fb3, rb1, rb2, rb3, rb4,
                           (float*)d_out, N);
    } else {
        hipLaunchKernelGGL(ngp_fused_f32, dim3((N + BLK - 1) / BLK), dim3(BLK), 0, stream,
                           coords, dirs, table,
                           fw1, fb1, fw2, fb2, fw3, fb3,
                           rw1, rb1, rw2, rb2, rw3, rb3, rw4, rb4,
                           (float*)d_out, N);
    }
}

// Round 13
// 894.324 us; speedup vs baseline: 3.1650x; 1.0065x over previous
//
#include <hip/hip_runtime.h>
#include <hip/hip_fp16.h>
#include <math.h>

#define BLK 128          // fused-fallback block
#define EBLK 256         // encode / utility block
#define NBINS (1 << 18)  // 6 bits per axis, Morton sort bins
#define Q_SCALE 65536.0f
#define Q_DESCALE 0x1p-16f

typedef __attribute__((ext_vector_type(8))) _Float16 half8;
typedef __attribute__((ext_vector_type(4))) float f32x4;
typedef __attribute__((ext_vector_type(2))) float f32x2;

// frag offsets in f16 elements: L1,L2,L3,R1,R2,R3,R4
#define FO_L1 0
#define FO_L2 2048
#define FO_L3 6144
#define FO_R1 7168
#define FO_R2 9216
#define FO_R3 13312
#define FO_R4 17408
#define FRAG_TOTAL 18432

// ---- fp8 table layout ----
#define HOFF0 3764224
#define MOFF0 5861376
#define MOFF1 12939264
#define MOFF2 20017152
#define MOFF3 36794368
#define TABQ_ENTRIES 53571584
#define PAIR_LO 1881687
#define PAIR_H  1048576
#define MTOT 47710208

// ---- prep_all region block counts (256 thr/block) ----
#define NB_MT 186368                 // MTOT / 256
#define NB_LO 7351                   // ceil(PAIR_LO / 256)
#define NB_H  4096                   // PAIR_H / 256
#define NB_FR 72                     // FRAG_TOTAL / 256
#define NB_Z  256                    // NBINS u32 zeroed as uint4
#define NB_PREP (NB_MT + NB_LO + NB_H + NB_FR + NB_Z)

// ---------------- Morton helpers ----------------
__device__ __forceinline__ unsigned mexp(unsigned v) {
    v &= 0x3FF;
    v = (v | (v << 16)) & 0x030000FF;
    v = (v | (v << 8))  & 0x0300F00F;
    v = (v | (v << 4))  & 0x030C30C3;
    v = (v | (v << 2))  & 0x09249249;
    return v;
}
__device__ __forceinline__ unsigned mcomp(unsigned v) {
    v &= 0x09249249u;
    v = (v | (v >> 2)) & 0x030C30C3u;
    v = (v | (v >> 4)) & 0x0300F00Fu;
    v = (v | (v >> 8)) & 0x030000FFu;
    v = (v | (v >> 16)) & 0x3FFu;
    return v;
}
__device__ __forceinline__ unsigned morton_key(float x, float y, float z) {
    int bx = (int)(x * 64.f); bx = bx < 0 ? 0 : (bx > 63 ? 63 : bx);
    int by = (int)(y * 64.f); by = by < 0 ? 0 : (by > 63 ? 63 : by);
    int bz = (int)(z * 64.f); bz = bz < 0 ? 0 : (bz > 63 ? 63 : bz);
    return (mexp((unsigned)bx) << 2) | (mexp((unsigned)by) << 1) | mexp((unsigned)bz);
}

__device__ __forceinline__ unsigned pk_fp8(float a, float b) {
    const int lo = __builtin_amdgcn_cvt_pk_fp8_f32(a * Q_SCALE, b * Q_SCALE, 0, false);
    return (unsigned)lo & 0xFFFFu;
}

// ---------------- fused prep: cvt_morton | cvt_lo | cvt_hash | prep_frags | hist-zero ----------------
__global__ __launch_bounds__(256) void prep_all(
    const float* __restrict__ srcF,
    unsigned short* __restrict__ tableQ,
    _Float16* __restrict__ frag,
    unsigned* __restrict__ hist,
    const float* __restrict__ fw1, const float* __restrict__ fw2, const float* __restrict__ fw3,
    const float* __restrict__ rw1, const float* __restrict__ rw2, const float* __restrict__ rw3,
    const float* __restrict__ rw4)
{
    const unsigned b = blockIdx.x;
    const unsigned tid = threadIdx.x;

    if (b < NB_MT) {
        // ---- cvt_morton region ----
        const unsigned e = b * 256u + tid;
        int j, cnt; unsigned base, moff;
        if (e < 14155776u) {
            cnt = 3;
            if (e < 7077888u) { j = 0; base = 0u;        moff = MOFF0; }
            else              { j = 1; base = 7077888u;  moff = MOFF1; }
        } else {
            cnt = 4;
            if (e < 30932992u){ j = 2; base = 14155776u; moff = MOFF2; }
            else              { j = 3; base = 30932992u; moff = MOFF3; }
        }
        const unsigned within = e - base;
        const unsigned blk = within >> 18, lo = within & 0x3FFFFu;
        unsigned bx, by, bz;
        if (cnt == 3) { bx = blk % 3u; const unsigned t = blk / 3u; by = t % 3u; bz = t / 3u; }
        else          { bx = blk & 3u; by = (blk >> 2) & 3u; bz = blk >> 4; }
        const unsigned x = bx * 64u + mcomp(lo);
        const unsigned y = by * 64u + mcomp(lo >> 1);
        const unsigned z = bz * 64u + mcomp(lo >> 2);

        constexpr unsigned RES1[4] = {141u, 169u, 204u, 245u};
        constexpr unsigned SOFF[4] = {3763373u, 6566594u, 11393403u, 19883067u};
        const unsigned r1 = RES1[j];
        unsigned q = 0;
        if (x < r1 && y < r1 && z < r1) {
            const size_t se = (size_t)SOFF[j] + x + (size_t)y * r1 + (size_t)z * r1 * r1;
            const float2 v = *reinterpret_cast<const float2*>(srcF + 2 * se);
            q = pk_fp8(v.x, v.y);
        }
        tableQ[(size_t)moff + within] = (unsigned short)q;
    } else if (b < NB_MT + NB_LO) {
        // ---- cvt_lo region: dense levels 0-7 ----
        const unsigned i = (b - NB_MT) * 256u + tid;
        if (i >= PAIR_LO) return;
        const float4 v = reinterpret_cast<const float4*>(srcF)[i];
        reinterpret_cast<unsigned*>(tableQ)[i] = pk_fp8(v.x, v.y) | (pk_fp8(v.z, v.w) << 16);
    } else if (b < NB_MT + NB_LO + NB_H) {
        // ---- cvt_hash region: hashed levels 12-15 ----
        const unsigned i = (b - NB_MT - NB_LO) * 256u + tid;
        const float4 v = reinterpret_cast<const float4*>(srcF)[17294596u + i];  // OFF[12]/2 + i
        reinterpret_cast<unsigned*>(tableQ)[HOFF0 / 2 + i] = pk_fp8(v.x, v.y) | (pk_fp8(v.z, v.w) << 16);
    } else if (b < NB_MT + NB_LO + NB_H + NB_FR) {
        // ---- prep_frags region ----
        const int gid = (int)((b - NB_MT - NB_LO - NB_H) * 256u + tid);
        constexpr int offs[8] = {FO_L1, FO_L2, FO_L3, FO_R1, FO_R2, FO_R3, FO_R4, FRAG_TOTAL};
        constexpr int Ks[7]   = {32, 64, 64, 31, 64, 64, 64};
        constexpr int NO[7]   = {64, 64, 16, 64, 64, 64, 3};
        constexpr int NKs[7]  = {1, 2, 2, 1, 2, 2, 2};
        int layer = 0;
        #pragma unroll
        for (int i = 1; i < 7; ++i) if (gid >= offs[i]) layer = i;
        const float* W = fw1;
        if (layer == 1) W = fw2; else if (layer == 2) W = fw3;
        else if (layer == 3) W = rw1; else if (layer == 4) W = rw2;
        else if (layer == 5) W = rw3; else if (layer == 6) W = rw4;

        const int e = gid - offs[layer];
        const int nk = NKs[layer];
        const int blk2 = e >> 9, within = e & 511;
        const int t = blk2 / nk, ks = blk2 - t * nk;
        const int lane = within >> 3, i = within & 7;
        const int k = ks * 32 + (lane >> 4) * 8 + i;
        const int col = (NO[layer] == 64) ? ((lane & 15) * 4 + t) : (t * 16 + (lane & 15));
        float v = 0.f;
        if (k < Ks[layer] && col < NO[layer]) v = W[k * NO[layer] + col];
        frag[gid] = (_Float16)v;
    } else {
        // ---- hist-zero region ----
        const unsigned i = (b - NB_MT - NB_LO - NB_H - NB_FR) * 256u + tid;
        reinterpret_cast<uint4*>(hist)[i] = make_uint4(0, 0, 0, 0);
    }
}

// ---------------- sort: histogram ----------------
__global__ __launch_bounds__(256) void hist_build(const float* __restrict__ coords,
                                                  unsigned* __restrict__ hist, int N)
{
    const int i = blockIdx.x * 256 + threadIdx.x;
    if (i >= N) return;
    const unsigned key = morton_key(coords[3*i+0], coords[3*i+1], coords[3*i+2]);
    atomicAdd(&hist[key], 1u);
}

// ---------------- sort: hierarchical exclusive scan ----------------
__global__ __launch_bounds__(256) void scan1(unsigned* __restrict__ hist, unsigned* __restrict__ bsum)
{
    __shared__ unsigned sa[256], sb[256];
    const int t = threadIdx.x;
    const unsigned base = blockIdx.x * 1024u + (unsigned)t * 4u;
    const unsigned v0 = hist[base+0], v1 = hist[base+1], v2 = hist[base+2], v3 = hist[base+3];
    const unsigned sum = v0 + v1 + v2 + v3;
    sa[t] = sum; __syncthreads();
    unsigned* src = sa; unsigned* dst = sb;
    for (int off = 1; off < 256; off <<= 1) {
        dst[t] = src[t] + (t >= off ? src[t - off] : 0u);
        __syncthreads();
        unsigned* tmp = src; src = dst; dst = tmp;
    }
    const unsigned incl = src[t];
    unsigned run = incl - sum;
    hist[base+0] = run; run += v0;
    hist[base+1] = run; run += v1;
    hist[base+2] = run; run += v2;
    hist[base+3] = run;
    if (t == 255) bsum[blockIdx.x] = incl;
}

__global__ __launch_bounds__(256) void scan2(unsigned* __restrict__ bsum)
{
    __shared__ unsigned sa[256], sb[256];
    const int t = threadIdx.x;
    const unsigned v = bsum[t];
    sa[t] = v; __syncthreads();
    unsigned* src = sa; unsigned* dst = sb;
    for (int off = 1; off < 256; off <<= 1) {
        dst[t] = src[t] + (t >= off ? src[t - off] : 0u);
        __syncthreads();
        unsigned* tmp = src; src = dst; dst = tmp;
    }
    bsum[t] = src[t] - v;
}

__global__ __launch_bounds__(256) void scan3(const unsigned* __restrict__ hist,
                                             const unsigned* __restrict__ bsum,
                                             unsigned* __restrict__ cursor)
{
    const int i = blockIdx.x * 256 + threadIdx.x;
    cursor[i] = hist[i] + bsum[i >> 10];
}

// ---------------- sort: scatter points into bins ----------------
__global__ __launch_bounds__(256) void scatter_pts(const float* __restrict__ coords,
                                                   const float* __restrict__ dirs,
                                                   unsigned* __restrict__ cursor,
                                                   float4* __restrict__ cS,
                                                   float4* __restrict__ dS, int N)
{
    const int i = blockIdx.x * 256 + threadIdx.x;
    if (i >= N) return;
    const float x = coords[3*i+0], y = coords[3*i+1], z = coords[3*i+2];
    const unsigned key = morton_key(x, y, z);
    const unsigned slot = atomicAdd(&cursor[key], 1u);
    cS[slot] = make_float4(x, y, z, __uint_as_float((unsigned)i));
    dS[slot] = make_float4(dirs[3*i+0], dirs[3*i+1], dirs[3*i+2], __uint_as_float((unsigned)i));
}

// ---------------- encode kernel ----------------
__global__ __launch_bounds__(EBLK, 8) void ngp_encode(
    const float4* __restrict__ cS,
    const unsigned short* __restrict__ tableQ,
    uint4* __restrict__ emb_out, int N)
{
    // bijective XCD-contiguous remap of blockIdx (8 XCDs)
    const unsigned nwg = gridDim.x;
    const unsigned bid = blockIdx.x;
    const unsigned qn = nwg >> 3, rn = nwg & 7;
    const unsigned xc = bid & 7, ib = bid >> 3;
    const unsigned nb = (xc < rn ? xc * (qn + 1) : rn * (qn + 1) + (xc - rn) * qn) + ib;

    const int gi = (int)(nb * EBLK + threadIdx.x);
    if (gi >= N) return;

    const float4 cp = cS[gi];
    const float x = cp.x, y = cp.y, z = cp.z;

    float emb[32];

    // ---- dense row-major levels 0-7 ----
    {
        constexpr int RES[8] = {32,38,46,55,67,80,97,116};
        constexpr int OFF[8] = {0,35937,95256,199079,374695,689127,1220568,2161760};
        #pragma unroll
        for (int l = 0; l < 8; ++l) {
            const int res = RES[l];
            const float xl = x * (float)res, yl = y * (float)res, zl = z * (float)res;
            int cx = (int)floorf(xl); cx = cx < 0 ? 0 : (cx > res-1 ? res-1 : cx);
            int cy = (int)floorf(yl); cy = cy < 0 ? 0 : (cy > res-1 ? res-1 : cy);
            int cz = (int)floorf(zl); cz = cz < 0 ? 0 : (cz > res-1 ? res-1 : cz);
            const float wx = xl - (float)cx, wy = yl - (float)cy, wz = zl - (float)cz;
            unsigned qv[8];
            #pragma unroll
            for (int c = 0; c < 8; ++c) {
                const int dx = (c >> 2) & 1, dy = (c >> 1) & 1, dz = c & 1;
                const int idx = (cx+dx) + (cy+dy)*(res+1) + (cz+dz)*(res+1)*(res+1);
                qv[c] = tableQ[OFF[l] + idx];
            }
            float e0 = 0.f, e1 = 0.f;
            #pragma unroll
            for (int c = 0; c < 8; ++c) {
                const int dx = (c >> 2) & 1, dy = (c >> 1) & 1, dz = c & 1;
                const float w = (dx ? wx : 1.f-wx)*(dy ? wy : 1.f-wy)*(dz ? wz : 1.f-wz);
                const f32x2 vf = __builtin_amdgcn_cvt_pk_f32_fp8((int)qv[c], false);
                e0 = fmaf(vf.x, w, e0); e1 = fmaf(vf.y, w, e1);
            }
            emb[2*l+0] = e0 * Q_DESCALE; emb[2*l+1] = e1 * Q_DESCALE;
        }
    }

    // ---- Morton-block dense levels 8-11 ----
    {
        constexpr int RESM[4] = {140,168,203,244};
        constexpr int CNTM[4] = {3,3,4,4};
        constexpr unsigned MOFF[4] = {MOFF0, MOFF1, MOFF2, MOFF3};
        #pragma unroll
        for (int j = 0; j < 4; ++j) {
            const int res = RESM[j];
            const int cnt = CNTM[j];
            const float xl = x * (float)res, yl = y * (float)res, zl = z * (float)res;
            int cx = (int)floorf(xl); cx = cx < 0 ? 0 : (cx > res-1 ? res-1 : cx);
            int cy = (int)floorf(yl); cy = cy < 0 ? 0 : (cy > res-1 ? res-1 : cy);
            int cz = (int)floorf(zl); cz = cz < 0 ? 0 : (cz > res-1 ? res-1 : cz);
            const float wx = xl - (float)cx, wy = yl - (float)cy, wz = zl - (float)cz;

            const int bx0 = cx >> 6, bx1 = (cx+1) >> 6;
            const int by0 = cy >> 6, by1 = (cy+1) >> 6;
            const int bz0 = cz >> 6, bz1 = (cz+1) >> 6;
            const unsigned mx0 = mexp(cx & 63),      mx1 = mexp((cx+1) & 63);
            const unsigned my0 = mexp(cy & 63) << 1, my1 = mexp((cy+1) & 63) << 1;
            const unsigned mz0 = mexp(cz & 63) << 2, mz1 = mexp((cz+1) & 63) << 2;

            unsigned qv[8];
            #pragma unroll
            for (int c = 0; c < 8; ++c) {
                const int dx = (c >> 2) & 1, dy = (c >> 1) & 1, dz = c & 1;
                const int bx = dx ? bx1 : bx0, by = dy ? by1 : by0, bz = dz ? bz1 : bz0;
                const unsigned mm = (dx ? mx1 : mx0) | (dy ? my1 : my0) | (dz ? mz1 : mz0);
                const unsigned blk = (unsigned)((bz * cnt + by) * cnt + bx);
                qv[c] = tableQ[(size_t)MOFF[j] + ((blk << 18) | mm)];
            }
            float e0 = 0.f, e1 = 0.f;
            #pragma unroll
            for (int c = 0; c < 8; ++c) {
                const int dx = (c >> 2) & 1, dy = (c >> 1) & 1, dz = c & 1;
                const float w = (dx ? wx : 1.f-wx)*(dy ? wy : 1.f-wy)*(dz ? wz : 1.f-wz);
                const f32x2 vf = __builtin_amdgcn_cvt_pk_f32_fp8((int)qv[c], false);
                e0 = fmaf(vf.x, w, e0); e1 = fmaf(vf.y, w, e1);
            }
            emb[16+2*j+0] = e0 * Q_DESCALE; emb[16+2*j+1] = e1 * Q_DESCALE;
        }
    }

    // ---- hashed levels 12-15 ----
    {
        constexpr int RESH[4] = {294,353,425,512};
        constexpr unsigned HOFF[4] = {HOFF0, HOFF0+524288, HOFF0+1048576, HOFF0+1572864};
        constexpr unsigned NMASK = (1u << 19) - 1u;
        #pragma unroll
        for (int j = 0; j < 4; ++j) {
            const int res = RESH[j];
            const float xl = x * (float)res, yl = y * (float)res, zl = z * (float)res;
            int cx = (int)floorf(xl); cx = cx < 0 ? 0 : (cx > res-1 ? res-1 : cx);
            int cy = (int)floorf(yl); cy = cy < 0 ? 0 : (cy > res-1 ? res-1 : cy);
            int cz = (int)floorf(zl); cz = cz < 0 ? 0 : (cz > res-1 ? res-1 : cz);
            const float wx = xl - (float)cx, wy = yl - (float)cy, wz = zl - (float)cz;
            unsigned qv[8];
            #pragma unroll
            for (int c = 0; c < 8; ++c) {
                const int dx = (c >> 2) & 1, dy = (c >> 1) & 1, dz = c & 1;
                const unsigned hh = (unsigned)(cx+dx) ^ ((unsigned)(cy+dy) * 2654435761u)
                                  ^ ((unsigned)(cz+dz) * 805459861u);
                qv[c] = tableQ[HOFF[j] + (hh & NMASK)];
            }
            float e0 = 0.f, e1 = 0.f;
            #pragma unroll
            for (int c = 0; c < 8; ++c) {
                const int dx = (c >> 2) & 1, dy = (c >> 1) & 1, dz = c & 1;
                const float w = (dx ? wx : 1.f-wx)*(dy ? wy : 1.f-wy)*(dz ? wz : 1.f-wz);
                const f32x2 vf = __builtin_amdgcn_cvt_pk_f32_fp8((int)qv[c], false);
                e0 = fmaf(vf.x, w, e0); e1 = fmaf(vf.y, w, e1);
            }
            emb[24+2*j+0] = e0 * Q_DESCALE; emb[24+2*j+1] = e1 * Q_DESCALE;
        }
    }

    unsigned packed[16];
    #pragma unroll
    for (int i = 0; i < 16; ++i) {
        const __half2 h = __floats2half2_rn(emb[2*i+0], emb[2*i+1]);
        packed[i] = *reinterpret_cast<const unsigned*>(&h);
    }
    uint4* dst = emb_out + (size_t)gi * 4;
    #pragma unroll
    for (int k = 0; k < 4; ++k)
        dst[k] = make_uint4(packed[4*k+0], packed[4*k+1], packed[4*k+2], packed[4*k+3]);
}

// ================= MFMA MLP =================
__device__ __forceinline__ half8 ldfrag(const _Float16* __restrict__ frags, int off, int l) {
    return *reinterpret_cast<const half8*>(frags + off + l * 8);
}
__device__ __forceinline__ int swz(int f, int p) {
    return ((((f >> 3) + p) & 7) << 3) | (f & 7);
}
__device__ __forceinline__ half8 loadA(const _Float16* T, int p, int kb) {
    return *reinterpret_cast<const half8*>(T + p * 64 + ((((kb >> 3) + p) & 7) << 3));
}
// paired store: acc[t][r] holds output feature 4*p16+t for point g*4+r
template<bool RELU>
__device__ __forceinline__ void storePair(_Float16* T, const f32x4 (&acc)[4], int p16, int g) {
    #pragma unroll
    for (int r = 0; r < 4; ++r) {
        const int p = g * 4 + r;
        float v0 = acc[0][r], v1 = acc[1][r], v2 = acc[2][r], v3 = acc[3][r];
        if (RELU) { v0 = fmaxf(v0,0.f); v1 = fmaxf(v1,0.f); v2 = fmaxf(v2,0.f); v3 = fmaxf(v3,0.f); }
        const __half2 h01 = __floats2half2_rn(v0, v1);
        const __half2 h23 = __floats2half2_rn(v2, v3);
        const int blkb = ((p16 >> 1) + p) & 7;
        uint2* dst = reinterpret_cast<uint2*>(T + p * 64 + blkb * 8 + 4 * (p16 & 1));
        *dst = make_uint2(*reinterpret_cast<const unsigned*>(&h01),
                          *reinterpret_cast<const unsigned*>(&h23));
    }
}
__device__ __forceinline__ void pe_fill(_Float16* T, int p16, int g, float dx, float dy, float dz) {
    float pv0, pv1, pv2, pv3;
    if (g == 0)      { pv0 = dx;             pv1 = dy;         pv2 = dz;             pv3 = __sinf(dx); }
    else if (g == 1) { pv0 = __sinf(2.f*dx); pv1 = __sinf(dy); pv2 = __sinf(2.f*dy); pv3 = __sinf(dz); }
    else if (g == 2) { pv0 = __sinf(2.f*dz); pv1 = __cosf(dx); pv2 = __cosf(2.f*dx); pv3 = __cosf(dy); }
    else             { pv0 = __cosf(2.f*dy); pv1 = __cosf(dz); pv2 = __cosf(2.f*dz); pv3 = 0.f; }
    const float pv[4] = {pv0, pv1, pv2, pv3};
    #pragma unroll
    for (int j2 = 0; j2 < 4; ++j2) {
        const int f = 16 + g * 4 + j2;
        T[p16 * 64 + swz(f, p16)] = (_Float16)pv[j2];
    }
}
#define MFMA16(a, b, c) __builtin_amdgcn_mfma_f32_16x16x32_f16((a), (b), (c), 0, 0, 0)

__global__ __launch_bounds__(256) void ngp_mlp_mfma(
    const _Float16* __restrict__ embws,      // [N][32] f16
    const float4* __restrict__ dS,
    const _Float16* __restrict__ frags,
    const float* __restrict__ fb1, const float* __restrict__ fb2, const float* __restrict__ fb3,
    const float* __restrict__ rb1, const float* __restrict__ rb2, const float* __restrict__ rb3,
    const float* __restrict__ rb4,
    float* __restrict__ out, int N)
{
    __shared__ _Float16 tbuf[4][2][16 * 64];
    __shared__ float obuf[4][2][64];
    const int tid = threadIdx.x;
    const int wv = tid >> 6, l = tid & 63;
    const int p16 = l & 15, g = l >> 4;
    const int wbase = (blockIdx.x * 4 + wv) * 32;
    _Float16* T0 = tbuf[wv][0];
    _Float16* T1 = tbuf[wv][1];
    float* O0 = obuf[wv][0];
    float* O1 = obuf[wv][1];

    int pi0 = wbase + p16;      if (pi0 >= N) pi0 = N - 1;
    int pi1 = wbase + 16 + p16; if (pi1 >= N) pi1 = N - 1;
    const float4 d0 = dS[pi0];
    const float4 d1 = dS[pi1];

    f32x4 ac0[4], ac1[4];
    half8 x00, x01, x10, x11;

    // ---- L1 (K=32): A straight from packed emb ----
    {
        const half8 a0 = *reinterpret_cast<const half8*>(embws + (size_t)pi0 * 32 + g * 8);
        const half8 a1 = *reinterpret_cast<const half8*>(embws + (size_t)pi1 * 32 + g * 8);
        __builtin_amdgcn_s_setprio(1);
        #pragma unroll
        for (int t = 0; t < 4; ++t) {
            const float b = fb1[(p16 << 2) + t];
            const half8 w = ldfrag(frags, FO_L1 + t * 512, l);
            f32x4 c = {b, b, b, b};
            ac0[t] = MFMA16(a0, w, c);
            ac1[t] = MFMA16(a1, w, c);
        }
        __builtin_amdgcn_s_setprio(0);
    }
    storePair<true>(T0, ac0, p16, g);
    storePair<true>(T1, ac1, p16, g);
    x00 = loadA(T0, p16, g*8); x01 = loadA(T0, p16, 32 + g*8);
    x10 = loadA(T1, p16, g*8); x11 = loadA(T1, p16, 32 + g*8);

    // ---- L2 (K=64) ----
    __builtin_amdgcn_s_setprio(1);
    #pragma unroll
    for (int t = 0; t < 4; ++t) {
        const float b = fb2[(p16 << 2) + t];
        const half8 w0 = ldfrag(frags, FO_L2 + (2*t+0) * 512, l);
        const half8 w1 = ldfrag(frags, FO_L2 + (2*t+1) * 512, l);
        f32x4 c0 = {b, b, b, b}, c1 = {b, b, b, b};
        c0 = MFMA16(x00, w0, c0); ac0[t] = MFMA16(x01, w1, c0);
        c1 = MFMA16(x10, w0, c1); ac1[t] = MFMA16(x11, w1, c1);
    }
    __builtin_amdgcn_s_setprio(0);
    storePair<true>(T0, ac0, p16, g);
    storePair<true>(T1, ac1, p16, g);
    x00 = loadA(T0, p16, g*8); x01 = loadA(T0, p16, 32 + g*8);
    x10 = loadA(T1, p16, g*8); x11 = loadA(T1, p16, 32 + g*8);

    // ---- L3 (feat, 16 cols, natural mapping) ----
    {
        const float b = fb3[p16];
        const half8 wa = ldfrag(frags, FO_L3 + 0, l);
        const half8 wb = ldfrag(frags, FO_L3 + 512, l);
        f32x4 c0 = {b, b, b, b}, c1 = {b, b, b, b};
        __builtin_amdgcn_s_setprio(1);
        c0 = MFMA16(x00, wa, c0); c0 = MFMA16(x01, wb, c0);
        c1 = MFMA16(x10, wa, c1); c1 = MFMA16(x11, wb, c1);
        __builtin_amdgcn_s_setprio(0);
        if (p16 == 0) {
            #pragma unroll
            for (int rr = 0; rr < 4; ++rr) {
                O0[(g*4+rr)*4 + 3] = __expf(c0[rr]);
                O1[(g*4+rr)*4 + 3] = __expf(c1[rr]);
            }
        }
        #pragma unroll
        for (int rr = 0; rr < 4; ++rr) {
            const int p = g*4 + rr;
            T0[p*64 + swz(p16, p)] = (_Float16)c0[rr];
            T1[p*64 + swz(p16, p)] = (_Float16)c1[rr];
        }
    }

    // ---- PE fill: features 16..31 ----
    pe_fill(T0, p16, g, d0.x, d0.y, d0.z);
    pe_fill(T1, p16, g, d1.x, d1.y, d1.z);
    const half8 ar0 = loadA(T0, p16, g*8);
    const half8 ar1 = loadA(T1, p16, g*8);

    // ---- R1 (K=32) ----
    __builtin_amdgcn_s_setprio(1);
    #pragma unroll
    for (int t = 0; t < 4; ++t) {
        const float b = rb1[(p16 << 2) + t];
        const half8 w = ldfrag(frags, FO_R1 + t * 512, l);
        f32x4 c = {b, b, b, b};
        ac0[t] = MFMA16(ar0, w, c);
        ac1[t] = MFMA16(ar1, w, c);
    }
    __builtin_amdgcn_s_setprio(0);
    storePair<true>(T0, ac0, p16, g);
    storePair<true>(T1, ac1, p16, g);
    x00 = loadA(T0, p16, g*8); x01 = loadA(T0, p16, 32 + g*8);
    x10 = loadA(T1, p16, g*8); x11 = loadA(T1, p16, 32 + g*8);

    // ---- R2 (K=64) ----
    __builtin_amdgcn_s_setprio(1);
    #pragma unroll
    for (int t = 0; t < 4; ++t) {
        const float b = rb2[(p16 << 2) + t];
        const half8 w0 = ldfrag(frags, FO_R2 + (2*t+0) * 512, l);
        const half8 w1 = ldfrag(frags, FO_R2 + (2*t+1) * 512, l);
        f32x4 c0 = {b, b, b, b}, c1 = {b, b, b, b};
        c0 = MFMA16(x00, w0, c0); ac0[t] = MFMA16(x01, w1, c0);
        c1 = MFMA16(x10, w0, c1); ac1[t] = MFMA16(x11, w1, c1);
    }
    __builtin_amdgcn_s_setprio(0);
    storePair<true>(T0, ac0, p16, g);
    storePair<true>(T1, ac1, p16, g);
    x00 = loadA(T0, p16, g*8); x01 = loadA(T0, p16, 32 + g*8);
    x10 = loadA(T1, p16, g*8); x11 = loadA(T1, p16, 32 + g*8);

    // ---- R3 (K=64) ----
    __builtin_amdgcn_s_setprio(1);
    #pragma unroll
    for (int t = 0; t < 4; ++t) {
        const float b = rb3[(p16 << 2) + t];
        const half8 w0 = ldfrag(frags, FO_R3 + (2*t+0) * 512, l);
        const half8 w1 = ldfrag(frags, FO_R3 + (2*t+1) * 512, l);
        f32x4 c0 = {b, b, b, b}, c1 = {b, b, b, b};
        c0 = MFMA16(x00, w0, c0); ac0[t] = MFMA16(x01, w1, c0);
        c1 = MFMA16(x10, w0, c1); ac1[t] = MFMA16(x11, w1, c1);
    }
    __builtin_amdgcn_s_setprio(0);
    storePair<true>(T0, ac0, p16, g);
    storePair<true>(T1, ac1, p16, g);
    x00 = loadA(T0, p16, g*8); x01 = loadA(T0, p16, 32 + g*8);
    x10 = loadA(T1, p16, g*8); x11 = loadA(T1, p16, 32 + g*8);

    // ---- R4 (rgb, 3 cols, natural mapping) ----
    {
        const float b = (p16 < 3) ? rb4[p16] : 0.f;
        const half8 wa = ldfrag(frags, FO_R4 + 0, l);
        const half8 wb = ldfrag(frags, FO_R4 + 512, l);
        f32x4 c0 = {b, b, b, b}, c1 = {b, b, b, b};
        __builtin_amdgcn_s_setprio(1);
        c0 = MFMA16(x00, wa, c0); c0 = MFMA16(x01, wb, c0);
        c1 = MFMA16(x10, wa, c1); c1 = MFMA16(x11, wb, c1);
        __builtin_amdgcn_s_setprio(0);
        if (p16 < 3) {
            #pragma unroll
            for (int rr = 0; rr < 4; ++rr) {
                O0[(g*4+rr)*4 + p16] = 1.f / (1.f + __expf(-c0[rr]));
                O1[(g*4+rr)*4 + p16] = 1.f / (1.f + __expf(-c1[rr]));
            }
        }
    }

    // ---- scatter out ----
    if (wbase + p16 < N) {
        const unsigned orig = __float_as_uint(d0.w);
        out[(size_t)orig * 4 + g] = O0[p16 * 4 + g];
    }
    if (wbase + 16 + p16 < N) {
        const unsigned orig = __float_as_uint(d1.w);
        out[(size_t)orig * 4 + g] = O1[p16 * 4 + g];
    }
}

// ---------------- fused fallback (small ws, f32 table) ----------------
template<int NIN, int NOUT, bool RELU>
__device__ __forceinline__ void dense_l(const float* __restrict__ W, const float* __restrict__ Bias,
                                        const float* __restrict__ col, float (&out)[NOUT])
{
    #pragma unroll
    for (int j = 0; j < NOUT; ++j) out[j] = Bias[j];
    #pragma unroll 4
    for (int i = 0; i < NIN; ++i) {
        const float a = col[i * BLK];
        const float* Wr = W + i * NOUT;
        #pragma unroll
        for (int j = 0; j < NOUT; ++j) out[j] = fmaf(a, Wr[j], out[j]);
    }
    if (RELU) {
        #pragma unroll
        for (int j = 0; j < NOUT; ++j) out[j] = fmaxf(out[j], 0.f);
    }
}

__device__ __forceinline__ void encode_point_f(float x, float y, float z,
                                               const float* __restrict__ tableF,
                                               float (&emb)[32])
{
    constexpr int RES[16] = {32,38,46,55,67,80,97,116,140,168,203,244,294,353,425,512};
    constexpr int DN [16] = {1,1,1,1,1,1,1,1,1,1,1,1,0,0,0,0};
    constexpr int OFF[16] = {0,35937,95256,199079,374695,689127,1220568,2161760,
                             3763373,6566594,11393403,19883067,34589192,35113480,
                             35637768,36162056};
    constexpr unsigned NMASK = (1u << 19) - 1u;
    #pragma unroll
    for (int l = 0; l < 16; ++l) {
        const int res = RES[l];
        const float xl = x * (float)res, yl = y * (float)res, zl = z * (float)res;
        int cx = (int)floorf(xl); cx = cx < 0 ? 0 : (cx > res-1 ? res-1 : cx);
        int cy = (int)floorf(yl); cy = cy < 0 ? 0 : (cy > res-1 ? res-1 : cy);
        int cz = (int)floorf(zl); cz = cz < 0 ? 0 : (cz > res-1 ? res-1 : cz);
        const float wx = xl - (float)cx, wy = yl - (float)cy, wz = zl - (float)cz;
        float e0 = 0.f, e1 = 0.f;
        #pragma unroll
        for (int c = 0; c < 8; ++c) {
            const int dx = (c >> 2) & 1, dy = (c >> 1) & 1, dz = c & 1;
            int idx;
            if (DN[l]) {
                idx = (cx+dx) + (cy+dy)*(res+1) + (cz+dz)*(res+1)*(res+1);
            } else {
                const unsigned hh = (unsigned)(cx+dx) ^ ((unsigned)(cy+dy)*2654435761u)
                                  ^ ((unsigned)(cz+dz)*805459861u);
                idx = (int)(hh & NMASK);
            }
            const float w = (dx ? wx : 1.f-wx)*(dy ? wy : 1.f-wy)*(dz ? wz : 1.f-wz);
            const float2 v = *reinterpret_cast<const float2*>(tableF + (size_t)2*(size_t)(OFF[l]+idx));
            e0 = fmaf(v.x, w, e0); e1 = fmaf(v.y, w, e1);
        }
        emb[2*l+0] = e0; emb[2*l+1] = e1;
    }
}

__device__ __forceinline__ float4 mlp_lds(float* col, float dx0, float dy0, float dz0,
    const float* __restrict__ fw1, const float* __restrict__ fb1,
    const float* __restrict__ fw2, const float* __restrict__ fb2,
    const float* __restrict__ fw3, const float* __restrict__ fb3,
    const float* __restrict__ rw1, const float* __restrict__ rb1,
    const float* __restrict__ rw2, const float* __restrict__ rb2,
    const float* __restrict__ rw3, const float* __restrict__ rb3,
    const float* __restrict__ rw4, const float* __restrict__ rb4)
{
    float h[64];
    dense_l<32, 64, true>(fw1, fb1, col, h);
    #pragma unroll
    for (int j = 0; j < 64; ++j) col[j * BLK] = h[j];
    dense_l<64, 64, true>(fw2, fb2, col, h);
    #pragma unroll
    for (int j = 0; j < 64; ++j) col[j * BLK] = h[j];
    float feat16[16];
    dense_l<64, 16, false>(fw3, fb3, col, feat16);
    const float sigma = expf(feat16[0]);
    #pragma unroll
    for (int j = 0; j < 16; ++j) col[j * BLK] = feat16[j];
    col[16 * BLK] = dx0; col[17 * BLK] = dy0; col[18 * BLK] = dz0;
    {
        float s, c;
        sincosf(dx0,     &s, &c); col[19 * BLK] = s; col[25 * BLK] = c;
        sincosf(2.f*dx0, &s, &c); col[20 * BLK] = s; col[26 * BLK] = c;
        sincosf(dy0,     &s, &c); col[21 * BLK] = s; col[27 * BLK] = c;
        sincosf(2.f*dy0, &s, &c); col[22 * BLK] = s; col[28 * BLK] = c;
        sincosf(dz0,     &s, &c); col[23 * BLK] = s; col[29 * BLK] = c;
        sincosf(2.f*dz0, &s, &c); col[24 * BLK] = s; col[30 * BLK] = c;
    }
    dense_l<31, 64, true>(rw1, rb1, col, h);
    #pragma unroll
    for (int j = 0; j < 64; ++j) col[j * BLK] = h[j];
    dense_l<64, 64, true>(rw2, rb2, col, h);
    #pragma unroll
    for (int j = 0; j < 64; ++j) col[j * BLK] = h[j];
    dense_l<64, 64, true>(rw3, rb3, col, h);
    #pragma unroll
    for (int j = 0; j < 64; ++j) col[j * BLK] = h[j];
    float o0 = rb4[0], o1 = rb4[1], o2 = rb4[2];
    #pragma unroll 4
    for (int i = 0; i < 64; ++i) {
        const float a = col[i * BLK];
        o0 = fmaf(a, rw4[i*3 + 0], o0);
        o1 = fmaf(a, rw4[i*3 + 1], o1);
        o2 = fmaf(a, rw4[i*3 + 2], o2);
    }
    o0 = 1.f / (1.f + expf(-o0));
    o1 = 1.f / (1.f + expf(-o1));
    o2 = 1.f / (1.f + expf(-o2));
    return make_float4(o0, o1, o2, sigma);
}

__global__ __launch_bounds__(BLK) void ngp_fused_f32(
    const float* __restrict__ coords,
    const float* __restrict__ dirs,
    const float* __restrict__ tableF,
    const float* __restrict__ fw1, const float* __restrict__ fb1,
    const float* __restrict__ fw2, const float* __restrict__ fb2,
    const float* __restrict__ fw3, const float* __restrict__ fb3,
    const float* __restrict__ rw1, const float* __restrict__ rb1,
    const float* __restrict__ rw2, const float* __restrict__ rb2,
    const float* __restrict__ rw3, const float* __restrict__ rb3,
    const float* __restrict__ rw4, const float* __restrict__ rb4,
    float* __restrict__ out, int N)
{
    __shared__ float sbuf[64 * BLK];
    const int tid = threadIdx.x;
    const int gi  = blockIdx.x * BLK + tid;
    if (gi >= N) return;

    float emb[32];
    encode_point_f(coords[3*gi+0], coords[3*gi+1], coords[3*gi+2], tableF, emb);
    float* col = sbuf + tid;
    #pragma unroll
    for (int j = 0; j < 32; ++j) col[j * BLK] = emb[j];

    const float4 ov = mlp_lds(col, dirs[3*gi+0], dirs[3*gi+1], dirs[3*gi+2],
                              fw1, fb1, fw2, fb2, fw3, fb3,
                              rw1, rb1, rw2, rb2, rw3, rb3, rw4, rb4);
    reinterpret_cast<float4*>(out)[gi] = ov;
}

extern "C" void kernel_launch(void* const* d_in, const int* in_sizes, int n_in,
                              void* d_out, int out_size, void* d_ws, size_t ws_size,
                              hipStream_t stream)
{
    const float* coords = (const float*)d_in[0];
    const float* dirs   = (const float*)d_in[1];
    const float* table  = (const float*)d_in[2];
    const float* fw1 = (const float*)d_in[3];
    const float* fb1 = (const float*)d_in[4];
    const float* fw2 = (const float*)d_in[5];
    const float* fb2 = (const float*)d_in[6];
    const float* fw3 = (const float*)d_in[7];
    const float* fb3 = (const float*)d_in[8];
    const float* rw1 = (const float*)d_in[9];
    const float* rb1 = (const float*)d_in[10];
    const float* rw2 = (const float*)d_in[11];
    const float* rb2 = (const float*)d_in[12];
    const float* rw3 = (const float*)d_in[13];
    const float* rb3 = (const float*)d_in[14];
    const float* rw4 = (const float*)d_in[15];
    const float* rb4 = (const float*)d_in[16];

    const int N = in_sizes[0] / 3;

    // ws layout
    size_t pos = 0;
    auto take = [&](size_t bytes) { size_t p = pos; pos = (pos + bytes + 255) & ~(size_t)255; return p; };
    const size_t o_tableQ = take((size_t)TABQ_ENTRIES * 2);
    const size_t o_emb    = take((size_t)N * 64);
    const size_t o_cS     = take((size_t)N * 16);
    const size_t o_dS     = take((size_t)N * 16);
    const size_t o_hist   = take((size_t)NBINS * 4);
    const size_t o_cursor = take((size_t)NBINS * 4);
    const size_t o_bsum   = take(256 * 4);
    const size_t o_frag   = take((size_t)FRAG_TOTAL * 2);
    const size_t need_full = pos;

    char* ws = (char*)d_ws;

    if (ws_size >= need_full) {
        unsigned short* tableQ = (unsigned short*)(ws + o_tableQ);
        uint4*     embws  = (uint4*)(ws + o_emb);
        float4*    cS     = (float4*)(ws + o_cS);
        float4*    dS     = (float4*)(ws + o_dS);
        unsigned*  hist   = (unsigned*)(ws + o_hist);
        unsigned*  cursor = (unsigned*)(ws + o_cursor);
        unsigned*  bsum   = (unsigned*)(ws + o_bsum);
        _Float16*  frag   = (_Float16*)(ws + o_frag);

        hipLaunchKernelGGL(prep_all, dim3(NB_PREP), dim3(256), 0, stream,
                           table, tableQ, frag, hist,
                           fw1, fw2, fw3, rw1, rw2, rw3, rw4);
        hipLaunchKernelGGL(hist_build, dim3((N + 255) / 256), dim3(256), 0, stream,
                           coords, hist, N);
        hipLaunchKernelGGL(scan1, dim3(NBINS / 1024), dim3(256), 0, stream, hist, bsum);
        hipLaunchKernelGGL(scan2, dim3(1), dim3(256), 0, stream, bsum);
        hipLaunchKernelGGL(scan3, dim3(NBINS / 256), dim3(256), 0, stream, hist, bsum, cursor);
        hipLaunchKernelGGL(scatter_pts, dim3((N + 255) / 256), dim3(256), 0, stream,
                           coords, dirs, cursor, cS, dS, N);
        hipLaunchKernelGGL(ngp_encode, dim3((N + EBLK - 1) / EBLK), dim3(EBLK), 0, stream,
                           cS, tableQ, embws, N);
        hipLaunchKernelGGL(ngp_mlp_mfma, dim3((N + 127) / 128), dim3(256), 0, stream,
                           (const _Float16*)embws, dS, frag,
                           fb1, fb2, fb3, rb1, rb2, rb3, rb4,
                           (float*)d_out, N);
    } else {
        hipLaunchKernelGGL(ngp_fused_f32, dim3((N + BLK - 1) / BLK), dim3(BLK), 0, stream,
                           coords, dirs, table,
                           fw1, fb1, fw2, fb2, fw3, fb3,
                           rw1, rb1, rw2, rb2, rw3, rb3, rw4, rb4,
                           (float*)d_out, N);
    }
}

// Round 14
// 889.130 us; speedup vs baseline: 3.1835x; 1.0058x over previous
//
#include <hip/hip_runtime.h>
#include <hip/hip_fp16.h>
#include <math.h>

#define BLK 128          // fused-fallback block
#define EBLK 256         // encode / utility block
#define NBINS (1 << 18)  // 6 bits per axis, Morton sort bins
#define Q_SCALE 65536.0f
#define Q_DESCALE 0x1p-16f

typedef __attribute__((ext_vector_type(8))) _Float16 half8;
typedef __attribute__((ext_vector_type(4))) float f32x4;
typedef __attribute__((ext_vector_type(2))) float f32x2;

// frag offsets in f16 elements: L1,L2,L3,R1,R2,R3,R4
#define FO_L1 0
#define FO_L2 2048
#define FO_L3 6144
#define FO_R1 7168
#define FO_R2 9216
#define FO_R3 13312
#define FO_R4 17408
#define FRAG_TOTAL 18432

// ---- fp8 table layout ----
#define HOFF0 3764224
#define MOFF0 5861376
#define MOFF1 12939264
#define MOFF2 20017152
#define MOFF3 36794368
#define TABQ_ENTRIES 53571584
#define PAIR_LO 1881687
#define PAIR_H  1048576
#define MTOT 47710208

// ---- prep_all region block counts (256 thr/block) ----
#define NB_MT 186368                 // MTOT / 256
#define NB_LO 7351                   // ceil(PAIR_LO / 256)
#define NB_H  4096                   // PAIR_H / 256
#define NB_FR 72                     // FRAG_TOTAL / 256
#define NB_FIX (NB_MT + NB_LO + NB_H + NB_FR)

// ---------------- Morton helpers ----------------
__device__ __forceinline__ unsigned mexp(unsigned v) {
    v &= 0x3FF;
    v = (v | (v << 16)) & 0x030000FF;
    v = (v | (v << 8))  & 0x0300F00F;
    v = (v | (v << 4))  & 0x030C30C3;
    v = (v | (v << 2))  & 0x09249249;
    return v;
}
__device__ __forceinline__ unsigned mcomp(unsigned v) {
    v &= 0x09249249u;
    v = (v | (v >> 2)) & 0x030C30C3u;
    v = (v | (v >> 4)) & 0x0300F00Fu;
    v = (v | (v >> 8)) & 0x030000FFu;
    v = (v | (v >> 16)) & 0x3FFu;
    return v;
}
__device__ __forceinline__ unsigned morton_key(float x, float y, float z) {
    int bx = (int)(x * 64.f); bx = bx < 0 ? 0 : (bx > 63 ? 63 : bx);
    int by = (int)(y * 64.f); by = by < 0 ? 0 : (by > 63 ? 63 : by);
    int bz = (int)(z * 64.f); bz = bz < 0 ? 0 : (bz > 63 ? 63 : bz);
    return (mexp((unsigned)bx) << 2) | (mexp((unsigned)by) << 1) | mexp((unsigned)bz);
}

__device__ __forceinline__ unsigned pk_fp8(float a, float b) {
    const int lo = __builtin_amdgcn_cvt_pk_fp8_f32(a * Q_SCALE, b * Q_SCALE, 0, false);
    return (unsigned)lo & 0xFFFFu;
}

// ---------------- fused prep: cvt_morton | cvt_lo | cvt_hash | prep_frags | hist_build ----------------
__global__ __launch_bounds__(256) void prep_all(
    const float* __restrict__ srcF,
    unsigned short* __restrict__ tableQ,
    _Float16* __restrict__ frag,
    unsigned* __restrict__ hist,          // pre-zeroed by memsetAsync
    const float* __restrict__ coords, int N,
    const float* __restrict__ fw1, const float* __restrict__ fw2, const float* __restrict__ fw3,
    const float* __restrict__ rw1, const float* __restrict__ rw2, const float* __restrict__ rw3,
    const float* __restrict__ rw4)
{
    const unsigned b = blockIdx.x;
    const unsigned tid = threadIdx.x;

    if (b < NB_MT) {
        // ---- cvt_morton region ----
        const unsigned e = b * 256u + tid;
        int j, cnt; unsigned base, moff;
        if (e < 14155776u) {
            cnt = 3;
            if (e < 7077888u) { j = 0; base = 0u;        moff = MOFF0; }
            else              { j = 1; base = 7077888u;  moff = MOFF1; }
        } else {
            cnt = 4;
            if (e < 30932992u){ j = 2; base = 14155776u; moff = MOFF2; }
            else              { j = 3; base = 30932992u; moff = MOFF3; }
        }
        const unsigned within = e - base;
        const unsigned blk = within >> 18, lo = within & 0x3FFFFu;
        unsigned bx, by, bz;
        if (cnt == 3) { bx = blk % 3u; const unsigned t = blk / 3u; by = t % 3u; bz = t / 3u; }
        else          { bx = blk & 3u; by = (blk >> 2) & 3u; bz = blk >> 4; }
        const unsigned x = bx * 64u + mcomp(lo);
        const unsigned y = by * 64u + mcomp(lo >> 1);
        const unsigned z = bz * 64u + mcomp(lo >> 2);

        constexpr unsigned RES1[4] = {141u, 169u, 204u, 245u};
        constexpr unsigned SOFF[4] = {3763373u, 6566594u, 11393403u, 19883067u};
        const unsigned r1 = RES1[j];
        unsigned q = 0;
        if (x < r1 && y < r1 && z < r1) {
            const size_t se = (size_t)SOFF[j] + x + (size_t)y * r1 + (size_t)z * r1 * r1;
            const float2 v = *reinterpret_cast<const float2*>(srcF + 2 * se);
            q = pk_fp8(v.x, v.y);
        }
        tableQ[(size_t)moff + within] = (unsigned short)q;
    } else if (b < NB_MT + NB_LO) {
        // ---- cvt_lo region: dense levels 0-7 ----
        const unsigned i = (b - NB_MT) * 256u + tid;
        if (i >= PAIR_LO) return;
        const float4 v = reinterpret_cast<const float4*>(srcF)[i];
        reinterpret_cast<unsigned*>(tableQ)[i] = pk_fp8(v.x, v.y) | (pk_fp8(v.z, v.w) << 16);
    } else if (b < NB_MT + NB_LO + NB_H) {
        // ---- cvt_hash region: hashed levels 12-15 ----
        const unsigned i = (b - NB_MT - NB_LO) * 256u + tid;
        const float4 v = reinterpret_cast<const float4*>(srcF)[17294596u + i];  // OFF[12]/2 + i
        reinterpret_cast<unsigned*>(tableQ)[HOFF0 / 2 + i] = pk_fp8(v.x, v.y) | (pk_fp8(v.z, v.w) << 16);
    } else if (b < NB_FIX) {
        // ---- prep_frags region ----
        const int gid = (int)((b - NB_MT - NB_LO - NB_H) * 256u + tid);
        constexpr int offs[8] = {FO_L1, FO_L2, FO_L3, FO_R1, FO_R2, FO_R3, FO_R4, FRAG_TOTAL};
        constexpr int Ks[7]   = {32, 64, 64, 31, 64, 64, 64};
        constexpr int NO[7]   = {64, 64, 16, 64, 64, 64, 3};
        constexpr int NKs[7]  = {1, 2, 2, 1, 2, 2, 2};
        int layer = 0;
        #pragma unroll
        for (int i = 1; i < 7; ++i) if (gid >= offs[i]) layer = i;
        const float* W = fw1;
        if (layer == 1) W = fw2; else if (layer == 2) W = fw3;
        else if (layer == 3) W = rw1; else if (layer == 4) W = rw2;
        else if (layer == 5) W = rw3; else if (layer == 6) W = rw4;

        const int e = gid - offs[layer];
        const int nk = NKs[layer];
        const int blk2 = e >> 9, within = e & 511;
        const int t = blk2 / nk, ks = blk2 - t * nk;
        const int lane = within >> 3, i = within & 7;
        const int k = ks * 32 + (lane >> 4) * 8 + i;
        const int col = (NO[layer] == 64) ? ((lane & 15) * 4 + t) : (t * 16 + (lane & 15));
        float v = 0.f;
        if (k < Ks[layer] && col < NO[layer]) v = W[k * NO[layer] + col];
        frag[gid] = (_Float16)v;
    } else {
        // ---- hist_build region (hist pre-zeroed) ----
        const int i = (int)((b - NB_FIX) * 256u + tid);
        if (i >= N) return;
        const unsigned key = morton_key(coords[3*i+0], coords[3*i+1], coords[3*i+2]);
        atomicAdd(&hist[key], 1u);
    }
}

// ---------------- sort: hierarchical exclusive scan ----------------
__global__ __launch_bounds__(256) void scan1(unsigned* __restrict__ hist, unsigned* __restrict__ bsum)
{
    __shared__ unsigned sa[256], sb[256];
    const int t = threadIdx.x;
    const unsigned base = blockIdx.x * 1024u + (unsigned)t * 4u;
    const unsigned v0 = hist[base+0], v1 = hist[base+1], v2 = hist[base+2], v3 = hist[base+3];
    const unsigned sum = v0 + v1 + v2 + v3;
    sa[t] = sum; __syncthreads();
    unsigned* src = sa; unsigned* dst = sb;
    for (int off = 1; off < 256; off <<= 1) {
        dst[t] = src[t] + (t >= off ? src[t - off] : 0u);
        __syncthreads();
        unsigned* tmp = src; src = dst; dst = tmp;
    }
    const unsigned incl = src[t];
    unsigned run = incl - sum;
    hist[base+0] = run; run += v0;
    hist[base+1] = run; run += v1;
    hist[base+2] = run; run += v2;
    hist[base+3] = run;
    if (t == 255) bsum[blockIdx.x] = incl;
}

// merged scan2+scan3: each block redundantly scans bsum[256] in LDS and
// adds its block-level exclusive prefix; cursor[i] = hist[i] + excl_bsum[i>>10]
__global__ __launch_bounds__(256) void scan23(const unsigned* __restrict__ hist,
                                              const unsigned* __restrict__ bsum,
                                              unsigned* __restrict__ cursor)
{
    __shared__ unsigned orig[256];
    __shared__ unsigned sa[256], sb[256];
    const int t = threadIdx.x;
    const unsigned v = bsum[t];
    orig[t] = v; sa[t] = v; __syncthreads();
    unsigned* src = sa; unsigned* dst = sb;
    for (int off = 1; off < 256; off <<= 1) {
        dst[t] = src[t] + (t >= off ? src[t - off] : 0u);
        __syncthreads();
        unsigned* tmp = src; src = dst; dst = tmp;
    }
    const int k = (int)(blockIdx.x >> 2);                 // (b*256+tid)>>10 is constant per block
    const unsigned excl = src[k] - orig[k];
    const int i = (int)(blockIdx.x * 256u + t);
    cursor[i] = hist[i] + excl;
}

// ---------------- sort: scatter points into bins ----------------
__global__ __launch_bounds__(256) void scatter_pts(const float* __restrict__ coords,
                                                   const float* __restrict__ dirs,
                                                   unsigned* __restrict__ cursor,
                                                   float4* __restrict__ cS,
                                                   float4* __restrict__ dS, int N)
{
    const int i = blockIdx.x * 256 + threadIdx.x;
    if (i >= N) return;
    const float x = coords[3*i+0], y = coords[3*i+1], z = coords[3*i+2];
    const unsigned key = morton_key(x, y, z);
    const unsigned slot = atomicAdd(&cursor[key], 1u);
    cS[slot] = make_float4(x, y, z, __uint_as_float((unsigned)i));
    dS[slot] = make_float4(dirs[3*i+0], dirs[3*i+1], dirs[3*i+2], __uint_as_float((unsigned)i));
}

// ---------------- encode kernel ----------------
__global__ __launch_bounds__(EBLK, 8) void ngp_encode(
    const float4* __restrict__ cS,
    const unsigned short* __restrict__ tableQ,
    uint4* __restrict__ emb_out, int N)
{
    // bijective XCD-contiguous remap of blockIdx (8 XCDs)
    const unsigned nwg = gridDim.x;
    const unsigned bid = blockIdx.x;
    const unsigned qn = nwg >> 3, rn = nwg & 7;
    const unsigned xc = bid & 7, ib = bid >> 3;
    const unsigned nb = (xc < rn ? xc * (qn + 1) : rn * (qn + 1) + (xc - rn) * qn) + ib;

    const int gi = (int)(nb * EBLK + threadIdx.x);
    if (gi >= N) return;

    const float4 cp = cS[gi];
    const float x = cp.x, y = cp.y, z = cp.z;

    float emb[32];

    // ---- dense row-major levels 0-7 ----
    {
        constexpr int RES[8] = {32,38,46,55,67,80,97,116};
        constexpr int OFF[8] = {0,35937,95256,199079,374695,689127,1220568,2161760};
        #pragma unroll
        for (int l = 0; l < 8; ++l) {
            const int res = RES[l];
            const float xl = x * (float)res, yl = y * (float)res, zl = z * (float)res;
            int cx = (int)floorf(xl); cx = cx < 0 ? 0 : (cx > res-1 ? res-1 : cx);
            int cy = (int)floorf(yl); cy = cy < 0 ? 0 : (cy > res-1 ? res-1 : cy);
            int cz = (int)floorf(zl); cz = cz < 0 ? 0 : (cz > res-1 ? res-1 : cz);
            const float wx = xl - (float)cx, wy = yl - (float)cy, wz = zl - (float)cz;
            unsigned qv[8];
            #pragma unroll
            for (int c = 0; c < 8; ++c) {
                const int dx = (c >> 2) & 1, dy = (c >> 1) & 1, dz = c & 1;
                const int idx = (cx+dx) + (cy+dy)*(res+1) + (cz+dz)*(res+1)*(res+1);
                qv[c] = tableQ[OFF[l] + idx];
            }
            float e0 = 0.f, e1 = 0.f;
            #pragma unroll
            for (int c = 0; c < 8; ++c) {
                const int dx = (c >> 2) & 1, dy = (c >> 1) & 1, dz = c & 1;
                const float w = (dx ? wx : 1.f-wx)*(dy ? wy : 1.f-wy)*(dz ? wz : 1.f-wz);
                const f32x2 vf = __builtin_amdgcn_cvt_pk_f32_fp8((int)qv[c], false);
                e0 = fmaf(vf.x, w, e0); e1 = fmaf(vf.y, w, e1);
            }
            emb[2*l+0] = e0 * Q_DESCALE; emb[2*l+1] = e1 * Q_DESCALE;
        }
    }

    // ---- Morton-block dense levels 8-11 ----
    {
        constexpr int RESM[4] = {140,168,203,244};
        constexpr int CNTM[4] = {3,3,4,4};
        constexpr unsigned MOFF[4] = {MOFF0, MOFF1, MOFF2, MOFF3};
        #pragma unroll
        for (int j = 0; j < 4; ++j) {
            const int res = RESM[j];
            const int cnt = CNTM[j];
            const float xl = x * (float)res, yl = y * (float)res, zl = z * (float)res;
            int cx = (int)floorf(xl); cx = cx < 0 ? 0 : (cx > res-1 ? res-1 : cx);
            int cy = (int)floorf(yl); cy = cy < 0 ? 0 : (cy > res-1 ? res-1 : cy);
            int cz = (int)floorf(zl); cz = cz < 0 ? 0 : (cz > res-1 ? res-1 : cz);
            const float wx = xl - (float)cx, wy = yl - (float)cy, wz = zl - (float)cz;

            const int bx0 = cx >> 6, bx1 = (cx+1) >> 6;
            const int by0 = cy >> 6, by1 = (cy+1) >> 6;
            const int bz0 = cz >> 6, bz1 = (cz+1) >> 6;
            const unsigned mx0 = mexp(cx & 63),      mx1 = mexp((cx+1) & 63);
            const unsigned my0 = mexp(cy & 63) << 1, my1 = mexp((cy+1) & 63) << 1;
            const unsigned mz0 = mexp(cz & 63) << 2, mz1 = mexp((cz+1) & 63) << 2;

            unsigned qv[8];
            #pragma unroll
            for (int c = 0; c < 8; ++c) {
                const int dx = (c >> 2) & 1, dy = (c >> 1) & 1, dz = c & 1;
                const int bx = dx ? bx1 : bx0, by = dy ? by1 : by0, bz = dz ? bz1 : bz0;
                const unsigned mm = (dx ? mx1 : mx0) | (dy ? my1 : my0) | (dz ? mz1 : mz0);
                const unsigned blk = (unsigned)((bz * cnt + by) * cnt + bx);
                qv[c] = tableQ[(size_t)MOFF[j] + ((blk << 18) | mm)];
            }
            float e0 = 0.f, e1 = 0.f;
            #pragma unroll
            for (int c = 0; c < 8; ++c) {
                const int dx = (c >> 2) & 1, dy = (c >> 1) & 1, dz = c & 1;
                const float w = (dx ? wx : 1.f-wx)*(dy ? wy : 1.f-wy)*(dz ? wz : 1.f-wz);
                const f32x2 vf = __builtin_amdgcn_cvt_pk_f32_fp8((int)qv[c], false);
                e0 = fmaf(vf.x, w, e0); e1 = fmaf(vf.y, w, e1);
            }
            emb[16+2*j+0] = e0 * Q_DESCALE; emb[16+2*j+1] = e1 * Q_DESCALE;
        }
    }

    // ---- hashed levels 12-15 ----
    {
        constexpr int RESH[4] = {294,353,425,512};
        constexpr unsigned HOFF[4] = {HOFF0, HOFF0+524288, HOFF0+1048576, HOFF0+1572864};
        constexpr unsigned NMASK = (1u << 19) - 1u;
        #pragma unroll
        for (int j = 0; j < 4; ++j) {
            const int res = RESH[j];
            const float xl = x * (float)res, yl = y * (float)res, zl = z * (float)res;
            int cx = (int)floorf(xl); cx = cx < 0 ? 0 : (cx > res-1 ? res-1 : cx);
            int cy = (int)floorf(yl); cy = cy < 0 ? 0 : (cy > res-1 ? res-1 : cy);
            int cz = (int)floorf(zl); cz = cz < 0 ? 0 : (cz > res-1 ? res-1 : cz);
            const float wx = xl - (float)cx, wy = yl - (float)cy, wz = zl - (float)cz;
            unsigned qv[8];
            #pragma unroll
            for (int c = 0; c < 8; ++c) {
                const int dx = (c >> 2) & 1, dy = (c >> 1) & 1, dz = c & 1;
                const unsigned hh = (unsigned)(cx+dx) ^ ((unsigned)(cy+dy) * 2654435761u)
                                  ^ ((unsigned)(cz+dz) * 805459861u);
                qv[c] = tableQ[HOFF[j] + (hh & NMASK)];
            }
            float e0 = 0.f, e1 = 0.f;
            #pragma unroll
            for (int c = 0; c < 8; ++c) {
                const int dx = (c >> 2) & 1, dy = (c >> 1) & 1, dz = c & 1;
                const float w = (dx ? wx : 1.f-wx)*(dy ? wy : 1.f-wy)*(dz ? wz : 1.f-wz);
                const f32x2 vf = __builtin_amdgcn_cvt_pk_f32_fp8((int)qv[c], false);
                e0 = fmaf(vf.x, w, e0); e1 = fmaf(vf.y, w, e1);
            }
            emb[24+2*j+0] = e0 * Q_DESCALE; emb[24+2*j+1] = e1 * Q_DESCALE;
        }
    }

    unsigned packed[16];
    #pragma unroll
    for (int i = 0; i < 16; ++i) {
        const __half2 h = __floats2half2_rn(emb[2*i+0], emb[2*i+1]);
        packed[i] = *reinterpret_cast<const unsigned*>(&h);
    }
    uint4* dst = emb_out + (size_t)gi * 4;
    #pragma unroll
    for (int k = 0; k < 4; ++k)
        dst[k] = make_uint4(packed[4*k+0], packed[4*k+1], packed[4*k+2], packed[4*k+3]);
}

// ================= MFMA MLP =================
__device__ __forceinline__ half8 ldfrag(const _Float16* __restrict__ frags, int off, int l) {
    return *reinterpret_cast<const half8*>(frags + off + l * 8);
}
__device__ __forceinline__ int swz(int f, int p) {
    return ((((f >> 3) + p) & 7) << 3) | (f & 7);
}
__device__ __forceinline__ half8 loadA(const _Float16* T, int p, int kb) {
    return *reinterpret_cast<const half8*>(T + p * 64 + ((((kb >> 3) + p) & 7) << 3));
}
// paired store: acc[t][r] holds output feature 4*p16+t for point g*4+r
template<bool RELU>
__device__ __forceinline__ void storePair(_Float16* T, const f32x4 (&acc)[4], int p16, int g) {
    #pragma unroll
    for (int r = 0; r < 4; ++r) {
        const int p = g * 4 + r;
        float v0 = acc[0][r], v1 = acc[1][r], v2 = acc[2][r], v3 = acc[3][r];
        if (RELU) { v0 = fmaxf(v0,0.f); v1 = fmaxf(v1,0.f); v2 = fmaxf(v2,0.f); v3 = fmaxf(v3,0.f); }
        const __half2 h01 = __floats2half2_rn(v0, v1);
        const __half2 h23 = __floats2half2_rn(v2, v3);
        const int blkb = ((p16 >> 1) + p) & 7;
        uint2* dst = reinterpret_cast<uint2*>(T + p * 64 + blkb * 8 + 4 * (p16 & 1));
        *dst = make_uint2(*reinterpret_cast<const unsigned*>(&h01),
                          *reinterpret_cast<const unsigned*>(&h23));
    }
}
__device__ __forceinline__ void pe_fill(_Float16* T, int p16, int g, float dx, float dy, float dz) {
    float pv0, pv1, pv2, pv3;
    if (g == 0)      { pv0 = dx;             pv1 = dy;         pv2 = dz;             pv3 = __sinf(dx); }
    else if (g == 1) { pv0 = __sinf(2.f*dx); pv1 = __sinf(dy); pv2 = __sinf(2.f*dy); pv3 = __sinf(dz); }
    else if (g == 2) { pv0 = __sinf(2.f*dz); pv1 = __cosf(dx); pv2 = __cosf(2.f*dx); pv3 = __cosf(dy); }
    else             { pv0 = __cosf(2.f*dy); pv1 = __cosf(dz); pv2 = __cosf(2.f*dz); pv3 = 0.f; }
    const float pv[4] = {pv0, pv1, pv2, pv3};
    #pragma unroll
    for (int j2 = 0; j2 < 4; ++j2) {
        const int f = 16 + g * 4 + j2;
        T[p16 * 64 + swz(f, p16)] = (_Float16)pv[j2];
    }
}
#define MFMA16(a, b, c) __builtin_amdgcn_mfma_f32_16x16x32_f16((a), (b), (c), 0, 0, 0)

__global__ __launch_bounds__(256) void ngp_mlp_mfma(
    const _Float16* __restrict__ embws,      // [N][32] f16
    const float4* __restrict__ dS,
    const _Float16* __restrict__ frags,
    const float* __restrict__ fb1, const float* __restrict__ fb2, const float* __restrict__ fb3,
    const float* __restrict__ rb1, const float* __restrict__ rb2, const float* __restrict__ rb3,
    const float* __restrict__ rb4,
    float* __restrict__ out, int N)
{
    __shared__ _Float16 tbuf[4][2][16 * 64];
    __shared__ float obuf[4][2][64];
    const int tid = threadIdx.x;
    const int wv = tid >> 6, l = tid & 63;
    const int p16 = l & 15, g = l >> 4;
    const int wbase = (blockIdx.x * 4 + wv) * 32;
    _Float16* T0 = tbuf[wv][0];
    _Float16* T1 = tbuf[wv][1];
    float* O0 = obuf[wv][0];
    float* O1 = obuf[wv][1];

    int pi0 = wbase + p16;      if (pi0 >= N) pi0 = N - 1;
    int pi1 = wbase + 16 + p16; if (pi1 >= N) pi1 = N - 1;
    const float4 d0 = dS[pi0];
    const float4 d1 = dS[pi1];

    f32x4 ac0[4], ac1[4];
    half8 x00, x01, x10, x11;

    // ---- L1 (K=32): A straight from packed emb ----
    {
        const half8 a0 = *reinterpret_cast<const half8*>(embws + (size_t)pi0 * 32 + g * 8);
        const half8 a1 = *reinterpret_cast<const half8*>(embws + (size_t)pi1 * 32 + g * 8);
        __builtin_amdgcn_s_setprio(1);
        #pragma unroll
        for (int t = 0; t < 4; ++t) {
            const float b = fb1[(p16 << 2) + t];
            const half8 w = ldfrag(frags, FO_L1 + t * 512, l);
            f32x4 c = {b, b, b, b};
            ac0[t] = MFMA16(a0, w, c);
            ac1[t] = MFMA16(a1, w, c);
        }
        __builtin_amdgcn_s_setprio(0);
    }
    storePair<true>(T0, ac0, p16, g);
    storePair<true>(T1, ac1, p16, g);
    x00 = loadA(T0, p16, g*8); x01 = loadA(T0, p16, 32 + g*8);
    x10 = loadA(T1, p16, g*8); x11 = loadA(T1, p16, 32 + g*8);

    // ---- L2 (K=64) ----
    __builtin_amdgcn_s_setprio(1);
    #pragma unroll
    for (int t = 0; t < 4; ++t) {
        const float b = fb2[(p16 << 2) + t];
        const half8 w0 = ldfrag(frags, FO_L2 + (2*t+0) * 512, l);
        const half8 w1 = ldfrag(frags, FO_L2 + (2*t+1) * 512, l);
        f32x4 c0 = {b, b, b, b}, c1 = {b, b, b, b};
        c0 = MFMA16(x00, w0, c0); ac0[t] = MFMA16(x01, w1, c0);
        c1 = MFMA16(x10, w0, c1); ac1[t] = MFMA16(x11, w1, c1);
    }
    __builtin_amdgcn_s_setprio(0);
    storePair<true>(T0, ac0, p16, g);
    storePair<true>(T1, ac1, p16, g);
    x00 = loadA(T0, p16, g*8); x01 = loadA(T0, p16, 32 + g*8);
    x10 = loadA(T1, p16, g*8); x11 = loadA(T1, p16, 32 + g*8);

    // ---- L3 (feat, 16 cols, natural mapping) ----
    {
        const float b = fb3[p16];
        const half8 wa = ldfrag(frags, FO_L3 + 0, l);
        const half8 wb = ldfrag(frags, FO_L3 + 512, l);
        f32x4 c0 = {b, b, b, b}, c1 = {b, b, b, b};
        __builtin_amdgcn_s_setprio(1);
        c0 = MFMA16(x00, wa, c0); c0 = MFMA16(x01, wb, c0);
        c1 = MFMA16(x10, wa, c1); c1 = MFMA16(x11, wb, c1);
        __builtin_amdgcn_s_setprio(0);
        if (p16 == 0) {
            #pragma unroll
            for (int rr = 0; rr < 4; ++rr) {
                O0[(g*4+rr)*4 + 3] = __expf(c0[rr]);
                O1[(g*4+rr)*4 + 3] = __expf(c1[rr]);
            }
        }
        #pragma unroll
        for (int rr = 0; rr < 4; ++rr) {
            const int p = g*4 + rr;
            T0[p*64 + swz(p16, p)] = (_Float16)c0[rr];
            T1[p*64 + swz(p16, p)] = (_Float16)c1[rr];
        }
    }

    // ---- PE fill: features 16..31 ----
    pe_fill(T0, p16, g, d0.x, d0.y, d0.z);
    pe_fill(T1, p16, g, d1.x, d1.y, d1.z);
    const half8 ar0 = loadA(T0, p16, g*8);
    const half8 ar1 = loadA(T1, p16, g*8);

    // ---- R1 (K=32) ----
    __builtin_amdgcn_s_setprio(1);
    #pragma unroll
    for (int t = 0; t < 4; ++t) {
        const float b = rb1[(p16 << 2) + t];
        const half8 w = ldfrag(frags, FO_R1 + t * 512, l);
        f32x4 c = {b, b, b, b};
        ac0[t] = MFMA16(ar0, w, c);
        ac1[t] = MFMA16(ar1, w, c);
    }
    __builtin_amdgcn_s_setprio(0);
    storePair<true>(T0, ac0, p16, g);
    storePair<true>(T1, ac1, p16, g);
    x00 = loadA(T0, p16, g*8); x01 = loadA(T0, p16, 32 + g*8);
    x10 = loadA(T1, p16, g*8); x11 = loadA(T1, p16, 32 + g*8);

    // ---- R2 (K=64) ----
    __builtin_amdgcn_s_setprio(1);
    #pragma unroll
    for (int t = 0; t < 4; ++t) {
        const float b = rb2[(p16 << 2) + t];
        const half8 w0 = ldfrag(frags, FO_R2 + (2*t+0) * 512, l);
        const half8 w1 = ldfrag(frags, FO_R2 + (2*t+1) * 512, l);
        f32x4 c0 = {b, b, b, b}, c1 = {b, b, b, b};
        c0 = MFMA16(x00, w0, c0); ac0[t] = MFMA16(x01, w1, c0);
        c1 = MFMA16(x10, w0, c1); ac1[t] = MFMA16(x11, w1, c1);
    }
    __builtin_amdgcn_s_setprio(0);
    storePair<true>(T0, ac0, p16, g);
    storePair<true>(T1, ac1, p16, g);
    x00 = loadA(T0, p16, g*8); x01 = loadA(T0, p16, 32 + g*8);
    x10 = loadA(T1, p16, g*8); x11 = loadA(T1, p16, 32 + g*8);

    // ---- R3 (K=64) ----
    __builtin_amdgcn_s_setprio(1);
    #pragma unroll
    for (int t = 0; t < 4; ++t) {
        const float b = rb3[(p16 << 2) + t];
        const half8 w0 = ldfrag(frags, FO_R3 + (2*t+0) * 512, l);
        const half8 w1 = ldfrag(frags, FO_R3 + (2*t+1) * 512, l);
        f32x4 c0 = {b, b, b, b}, c1 = {b, b, b, b};
        c0 = MFMA16(x00, w0, c0); ac0[t] = MFMA16(x01, w1, c0);
        c1 = MFMA16(x10, w0, c1); ac1[t] = MFMA16(x11, w1, c1);
    }
    __builtin_amdgcn_s_setprio(0);
    storePair<true>(T0, ac0, p16, g);
    storePair<true>(T1, ac1, p16, g);
    x00 = loadA(T0, p16, g*8); x01 = loadA(T0, p16, 32 + g*8);
    x10 = loadA(T1, p16, g*8); x11 = loadA(T1, p16, 32 + g*8);

    // ---- R4 (rgb, 3 cols, natural mapping) ----
    {
        const float b = (p16 < 3) ? rb4[p16] : 0.f;
        const half8 wa = ldfrag(frags, FO_R4 + 0, l);
        const half8 wb = ldfrag(frags, FO_R4 + 512, l);
        f32x4 c0 = {b, b, b, b}, c1 = {b, b, b, b};
        __builtin_amdgcn_s_setprio(1);
        c0 = MFMA16(x00, wa, c0); c0 = MFMA16(x01, wb, c0);
        c1 = MFMA16(x10, wa, c1); c1 = MFMA16(x11, wb, c1);
        __builtin_amdgcn_s_setprio(0);
        if (p16 < 3) {
            #pragma unroll
            for (int rr = 0; rr < 4; ++rr) {
                O0[(g*4+rr)*4 + p16] = 1.f / (1.f + __expf(-c0[rr]));
                O1[(g*4+rr)*4 + p16] = 1.f / (1.f + __expf(-c1[rr]));
            }
        }
    }

    // ---- scatter out ----
    if (wbase + p16 < N) {
        const unsigned orig = __float_as_uint(d0.w);
        out[(size_t)orig * 4 + g] = O0[p16 * 4 + g];
    }
    if (wbase + 16 + p16 < N) {
        const unsigned orig = __float_as_uint(d1.w);
        out[(size_t)orig * 4 + g] = O1[p16 * 4 + g];
    }
}

// ---------------- fused fallback (small ws, f32 table) ----------------
template<int NIN, int NOUT, bool RELU>
__device__ __forceinline__ void dense_l(const float* __restrict__ W, const float* __restrict__ Bias,
                                        const float* __restrict__ col, float (&out)[NOUT])
{
    #pragma unroll
    for (int j = 0; j < NOUT; ++j) out[j] = Bias[j];
    #pragma unroll 4
    for (int i = 0; i < NIN; ++i) {
        const float a = col[i * BLK];
        const float* Wr = W + i * NOUT;
        #pragma unroll
        for (int j = 0; j < NOUT; ++j) out[j] = fmaf(a, Wr[j], out[j]);
    }
    if (RELU) {
        #pragma unroll
        for (int j = 0; j < NOUT; ++j) out[j] = fmaxf(out[j], 0.f);
    }
}

__device__ __forceinline__ void encode_point_f(float x, float y, float z,
                                               const float* __restrict__ tableF,
                                               float (&emb)[32])
{
    constexpr int RES[16] = {32,38,46,55,67,80,97,116,140,168,203,244,294,353,425,512};
    constexpr int DN [16] = {1,1,1,1,1,1,1,1,1,1,1,1,0,0,0,0};
    constexpr int OFF[16] = {0,35937,95256,199079,374695,689127,1220568,2161760,
                             3763373,6566594,11393403,19883067,34589192,35113480,
                             35637768,36162056};
    constexpr unsigned NMASK = (1u << 19) - 1u;
    #pragma unroll
    for (int l = 0; l < 16; ++l) {
        const int res = RES[l];
        const float xl = x * (float)res, yl = y * (float)res, zl = z * (float)res;
        int cx = (int)floorf(xl); cx = cx < 0 ? 0 : (cx > res-1 ? res-1 : cx);
        int cy = (int)floorf(yl); cy = cy < 0 ? 0 : (cy > res-1 ? res-1 : cy);
        int cz = (int)floorf(zl); cz = cz < 0 ? 0 : (cz > res-1 ? res-1 : cz);
        const float wx = xl - (float)cx, wy = yl - (float)cy, wz = zl - (float)cz;
        float e0 = 0.f, e1 = 0.f;
        #pragma unroll
        for (int c = 0; c < 8; ++c) {
            const int dx = (c >> 2) & 1, dy = (c >> 1) & 1, dz = c & 1;
            int idx;
            if (DN[l]) {
                idx = (cx+dx) + (cy+dy)*(res+1) + (cz+dz)*(res+1)*(res+1);
            } else {
                const unsigned hh = (unsigned)(cx+dx) ^ ((unsigned)(cy+dy)*2654435761u)
                                  ^ ((unsigned)(cz+dz)*805459861u);
                idx = (int)(hh & NMASK);
            }
            const float w = (dx ? wx : 1.f-wx)*(dy ? wy : 1.f-wy)*(dz ? wz : 1.f-wz);
            const float2 v = *reinterpret_cast<const float2*>(tableF + (size_t)2*(size_t)(OFF[l]+idx));
            e0 = fmaf(v.x, w, e0); e1 = fmaf(v.y, w, e1);
        }
        emb[2*l+0] = e0; emb[2*l+1] = e1;
    }
}

__device__ __forceinline__ float4 mlp_lds(float* col, float dx0, float dy0, float dz0,
    const float* __restrict__ fw1, const float* __restrict__ fb1,
    const float* __restrict__ fw2, const float* __restrict__ fb2,
    const float* __restrict__ fw3, const float* __restrict__ fb3,
    const float* __restrict__ rw1, const float* __restrict__ rb1,
    const float* __restrict__ rw2, const float* __restrict__ rb2,
    const float* __restrict__ rw3, const float* __restrict__ rb3,
    const float* __restrict__ rw4, const float* __restrict__ rb4)
{
    float h[64];
    dense_l<32, 64, true>(fw1, fb1, col, h);
    #pragma unroll
    for (int j = 0; j < 64; ++j) col[j * BLK] = h[j];
    dense_l<64, 64, true>(fw2, fb2, col, h);
    #pragma unroll
    for (int j = 0; j < 64; ++j) col[j * BLK] = h[j];
    float feat16[16];
    dense_l<64, 16, false>(fw3, fb3, col, feat16);
    const float sigma = expf(feat16[0]);
    #pragma unroll
    for (int j = 0; j < 16; ++j) col[j * BLK] = feat16[j];
    col[16 * BLK] = dx0; col[17 * BLK] = dy0; col[18 * BLK] = dz0;
    {
        float s, c;
        sincosf(dx0,     &s, &c); col[19 * BLK] = s; col[25 * BLK] = c;
        sincosf(2.f*dx0, &s, &c); col[20 * BLK] = s; col[26 * BLK] = c;
        sincosf(dy0,     &s, &c); col[21 * BLK] = s; col[27 * BLK] = c;
        sincosf(2.f*dy0, &s, &c); col[22 * BLK] = s; col[28 * BLK] = c;
        sincosf(dz0,     &s, &c); col[23 * BLK] = s; col[29 * BLK] = c;
        sincosf(2.f*dz0, &s, &c); col[24 * BLK] = s; col[30 * BLK] = c;
    }
    dense_l<31, 64, true>(rw1, rb1, col, h);
    #pragma unroll
    for (int j = 0; j < 64; ++j) col[j * BLK] = h[j];
    dense_l<64, 64, true>(rw2, rb2, col, h);
    #pragma unroll
    for (int j = 0; j < 64; ++j) col[j * BLK] = h[j];
    dense_l<64, 64, true>(rw3, rb3, col, h);
    #pragma unroll
    for (int j = 0; j < 64; ++j) col[j * BLK] = h[j];
    float o0 = rb4[0], o1 = rb4[1], o2 = rb4[2];
    #pragma unroll 4
    for (int i = 0; i < 64; ++i) {
        const float a = col[i * BLK];
        o0 = fmaf(a, rw4[i*3 + 0], o0);
        o1 = fmaf(a, rw4[i*3 + 1], o1);
        o2 = fmaf(a, rw4[i*3 + 2], o2);
    }
    o0 = 1.f / (1.f + expf(-o0));
    o1 = 1.f / (1.f + expf(-o1));
    o2 = 1.f / (1.f + expf(-o2));
    return make_float4(o0, o1, o2, sigma);
}

__global__ __launch_bounds__(BLK) void ngp_fused_f32(
    const float* __restrict__ coords,
    const float* __restrict__ dirs,
    const float* __restrict__ tableF,
    const float* __restrict__ fw1, const float* __restrict__ fb1,
    const float* __restrict__ fw2, const float* __restrict__ fb2,
    const float* __restrict__ fw3, const float* __restrict__ fb3,
    const float* __restrict__ rw1, const float* __restrict__ rb1,
    const float* __restrict__ rw2, const float* __restrict__ rb2,
    const float* __restrict__ rw3, const float* __restrict__ rb3,
    const float* __restrict__ rw4, const float* __restrict__ rb4,
    float* __restrict__ out, int N)
{
    __shared__ float sbuf[64 * BLK];
    const int tid = threadIdx.x;
    const int gi  = blockIdx.x * BLK + tid;
    if (gi >= N) return;

    float emb[32];
    encode_point_f(coords[3*gi+0], coords[3*gi+1], coords[3*gi+2], tableF, emb);
    float* col = sbuf + tid;
    #pragma unroll
    for (int j = 0; j < 32; ++j) col[j * BLK] = emb[j];

    const float4 ov = mlp_lds(col, dirs[3*gi+0], dirs[3*gi+1], dirs[3*gi+2],
                              fw1, fb1, fw2, fb2, fw3, fb3,
                              rw1, rb1, rw2, rb2, rw3, rb3, rw4, rb4);
    reinterpret_cast<float4*>(out)[gi] = ov;
}

extern "C" void kernel_launch(void* const* d_in, const int* in_sizes, int n_in,
                              void* d_out, int out_size, void* d_ws, size_t ws_size,
                              hipStream_t stream)
{
    const float* coords = (const float*)d_in[0];
    const float* dirs   = (const float*)d_in[1];
    const float* table  = (const float*)d_in[2];
    const float* fw1 = (const float*)d_in[3];
    const float* fb1 = (const float*)d_in[4];
    const float* fw2 = (const float*)d_in[5];
    const float* fb2 = (const float*)d_in[6];
    const float* fw3 = (const float*)d_in[7];
    const float* fb3 = (const float*)d_in[8];
    const float* rw1 = (const float*)d_in[9];
    const float* rb1 = (const float*)d_in[10];
    const float* rw2 = (const float*)d_in[11];
    const float* rb2 = (const float*)d_in[12];
    const float* rw3 = (const float*)d_in[13];
    const float* rb3 = (const float*)d_in[14];
    const float* rw4 = (const float*)d_in[15];
    const float* rb4 = (const float*)d_in[16];

    const int N = in_sizes[0] / 3;

    // ws layout
    size_t pos = 0;
    auto take = [&](size_t bytes) { size_t p = pos; pos = (pos + bytes + 255) & ~(size_t)255; return p; };
    const size_t o_tableQ = take((size_t)TABQ_ENTRIES * 2);
    const size_t o_emb    = take((size_t)N * 64);
    const size_t o_cS     = take((size_t)N * 16);
    const size_t o_dS     = take((size_t)N * 16);
    const size_t o_hist   = take((size_t)NBINS * 4);
    const size_t o_cursor = take((size_t)NBINS * 4);
    const size_t o_bsum   = take(256 * 4);
    const size_t o_frag   = take((size_t)FRAG_TOTAL * 2);
    const size_t need_full = pos;

    char* ws = (char*)d_ws;

    if (ws_size >= need_full) {
        unsigned short* tableQ = (unsigned short*)(ws + o_tableQ);
        uint4*     embws  = (uint4*)(ws + o_emb);
        float4*    cS     = (float4*)(ws + o_cS);
        float4*    dS     = (float4*)(ws + o_dS);
        unsigned*  hist   = (unsigned*)(ws + o_hist);
        unsigned*  cursor = (unsigned*)(ws + o_cursor);
        unsigned*  bsum   = (unsigned*)(ws + o_bsum);
        _Float16*  frag   = (_Float16*)(ws + o_frag);

        const int nb_hb = (N + 255) / 256;
        hipMemsetAsync(hist, 0, (size_t)NBINS * 4, stream);
        hipLaunchKernelGGL(prep_all, dim3(NB_FIX + nb_hb), dim3(256), 0, stream,
                           table, tableQ, frag, hist, coords, N,
                           fw1, fw2, fw3, rw1, rw2, rw3, rw4);
        hipLaunchKernelGGL(scan1, dim3(NBINS / 1024), dim3(256), 0, stream, hist, bsum);
        hipLaunchKernelGGL(scan23, dim3(NBINS / 256), dim3(256), 0, stream, hist, bsum, cursor);
        hipLaunchKernelGGL(scatter_pts, dim3((N + 255) / 256), dim3(256), 0, stream,
                           coords, dirs, cursor, cS, dS, N);
        hipLaunchKernelGGL(ngp_encode, dim3((N + EBLK - 1) / EBLK), dim3(EBLK), 0, stream,
                           cS, tableQ, embws, N);
        hipLaunchKernelGGL(ngp_mlp_mfma, dim3((N + 127) / 128), dim3(256), 0, stream,
                           (const _Float16*)embws, dS, frag,
                           fb1, fb2, fb3, rb1, rb2, rb3, rb4,
                           (float*)d_out, N);
    } else {
        hipLaunchKernelGGL(ngp_fused_f32, dim3((N + BLK - 1) / BLK), dim3(BLK), 0, stream,
                           coords, dirs, table,
                           fw1, fb1, fw2, fb2, fw3, fb3,
                           rw1, rb1, rw2, rb2, rw3, rb3, rw4, rb4,
                           (float*)d_out, N);
    }
}